// Round 2
// baseline (1172.887 us; speedup 1.0000x reference)
//
#include <hip/hip_runtime.h>

// Problem constants (fixed by the reference)
#define N_NODES 100000
#define N_EDGES 1600000
#define HF      128
#define RESC    0.5f
#define LN_EPS  1e-5f

// dst-binning for the CSR build
#define BINW_SHIFT 7
#define BINW       128
#define NBIN       ((N_NODES + BINW - 1) >> BINW_SHIFT)   // 782
#define NSCAN_BLK  ((N_NODES + 1023) / 1024)              // 98

#define GEMM_THREADS 512
#define MT  32              // rows per GEMM block
#define RPT 2               // rows per thread

// ---------------------------------------------------------------------------
// Degree counting (int atomics, L2-resident 800KB -> fast)
// ---------------------------------------------------------------------------
__global__ __launch_bounds__(256) void count_kernel(
    const int* __restrict__ src, const int* __restrict__ dst,
    int* __restrict__ deg_out, int* __restrict__ cnt)
{
    int e = blockIdx.x * 256 + threadIdx.x;
    if (e >= N_EDGES) return;
    atomicAdd(deg_out + src[e], 1);
    atomicAdd(cnt + dst[e], 1);
}

// ---------------------------------------------------------------------------
// 3-stage exclusive prefix sum of cnt[N] -> nodeOfs[N+1]
// ---------------------------------------------------------------------------
__global__ __launch_bounds__(1024) void scan1_kernel(
    const int* __restrict__ cnt, int* __restrict__ nodeOfs, int* __restrict__ blockSum)
{
    __shared__ int wsum[16];
    int j = blockIdx.x * 1024 + threadIdx.x;
    int lane = threadIdx.x & 63, wid = threadIdx.x >> 6;
    int v = (j < N_NODES) ? cnt[j] : 0;
    int x = v;
#pragma unroll
    for (int off = 1; off < 64; off <<= 1) { int u = __shfl_up(x, off); if (lane >= off) x += u; }
    if (lane == 63) wsum[wid] = x;
    __syncthreads();
    if (wid == 0) {
        int y = (lane < 16) ? wsum[lane] : 0;
#pragma unroll
        for (int off = 1; off < 16; off <<= 1) { int u = __shfl_up(y, off); if (lane >= off) y += u; }
        if (lane < 16) wsum[lane] = y;
    }
    __syncthreads();
    int incl = x + (wid > 0 ? wsum[wid - 1] : 0);
    if (j < N_NODES) nodeOfs[j + 1] = incl;            // partial; base added in scan3
    if (threadIdx.x == 1023) blockSum[blockIdx.x] = incl;
}

__global__ __launch_bounds__(64) void scan2_kernel(
    const int* __restrict__ blockSum, int* __restrict__ blockBase)
{
    int lane = threadIdx.x;
    int carry = 0;
    for (int base = 0; base < NSCAN_BLK; base += 64) {
        int v = (base + lane < NSCAN_BLK) ? blockSum[base + lane] : 0;
        int x = v;
#pragma unroll
        for (int off = 1; off < 64; off <<= 1) { int u = __shfl_up(x, off); if (lane >= off) x += u; }
        if (base + lane < NSCAN_BLK) blockBase[base + lane] = x - v + carry;
        carry += __shfl(x, 63);
    }
}

__global__ __launch_bounds__(1024) void scan3_kernel(
    int* __restrict__ nodeOfs, const int* __restrict__ blockBase, int* __restrict__ binCursor)
{
    int j = blockIdx.x * 1024 + threadIdx.x;
    if (j >= N_NODES) return;
    int val = nodeOfs[j + 1] + blockBase[blockIdx.x];
    nodeOfs[j + 1] = val;
    if (j == 0) { nodeOfs[0] = 0; binCursor[0] = 0; }
    if (((j + 1) & (BINW - 1)) == 0 && (j + 1) < N_NODES)
        binCursor[(j + 1) >> BINW_SHIFT] = val;        // bin start cursor
}

// ---------------------------------------------------------------------------
// Bin-scatter: append (src,dst) to the dst's bin. 782 active 64B write
// frontiers -> lines fill completely while L2-hot (write amplification ~1).
// ---------------------------------------------------------------------------
__global__ __launch_bounds__(256) void binscat_kernel(
    const int* __restrict__ src, const int* __restrict__ dst,
    int* __restrict__ binCursor, int2* __restrict__ pairs)
{
    int e = blockIdx.x * 256 + threadIdx.x;
    if (e >= N_EDGES) return;
    int s = src[e], d = dst[e];
    int pos = atomicAdd(binCursor + (d >> BINW_SHIFT), 1);
    pairs[pos] = make_int2(s, d);
}

// ---------------------------------------------------------------------------
// Per-bin CSR scatter: one block per bin, per-node cursors in LDS, the bin's
// CSR window (~8KB) stays L2-hot -> dense writes.
// ---------------------------------------------------------------------------
__global__ __launch_bounds__(256) void csrscat_kernel(
    const int2* __restrict__ pairs, const int* __restrict__ nodeOfs,
    int* __restrict__ csr)
{
    __shared__ int curs[BINW];
    int nstart = blockIdx.x << BINW_SHIFT;
    int nend = min(nstart + BINW, N_NODES);
    if (threadIdx.x < nend - nstart) curs[threadIdx.x] = nodeOfs[nstart + threadIdx.x];
    __syncthreads();
    int beg = nodeOfs[nstart];
    int end = nodeOfs[nend];
    for (int e = beg + (int)threadIdx.x; e < end; e += 256) {
        int2 p = pairs[e];
        int pos = atomicAdd(&curs[p.y - nstart], 1);
        csr[pos] = p.x;
    }
}

__global__ __launch_bounds__(256) void norm_kernel(
    const int* __restrict__ deg_out, const int* __restrict__ cnt,
    float* __restrict__ ns, float* __restrict__ nd)
{
    int i = blockIdx.x * 256 + threadIdx.x;
    if (i >= N_NODES) return;
    ns[i] = rsqrtf((float)max(deg_out[i], 1));
    nd[i] = rsqrtf((float)max(cnt[i], 1));
}

// ---------------------------------------------------------------------------
// Aggregation: one 64-lane wave per node. agg[v] = nd[v] * sum_e ns[s]*hin[s].
// Each lane owns 2 features (float2) -> 512B coalesced row reads.
// ---------------------------------------------------------------------------
__global__ __launch_bounds__(256) void agg_kernel(
    const float* __restrict__ hin, const int* __restrict__ csr,
    const int* __restrict__ nodeOfs, const float* __restrict__ ns,
    const float* __restrict__ nd, float* __restrict__ agg)
{
    int node = blockIdx.x * 4 + (threadIdx.x >> 6);
    if (node >= N_NODES) return;
    int lane = threadIdx.x & 63;
    int beg = nodeOfs[node], end = nodeOfs[node + 1];

    float ax = 0.f, ay = 0.f;
    int k = beg;
    for (; k + 1 < end; k += 2) {
        int s0 = csr[k], s1 = csr[k + 1];
        float c0 = ns[s0], c1 = ns[s1];
        float2 v0 = *(const float2*)(hin + (size_t)s0 * HF + lane * 2);
        float2 v1 = *(const float2*)(hin + (size_t)s1 * HF + lane * 2);
        ax = fmaf(c0, v0.x, ax); ay = fmaf(c0, v0.y, ay);
        ax = fmaf(c1, v1.x, ax); ay = fmaf(c1, v1.y, ay);
    }
    if (k < end) {
        int s = csr[k];
        float c = ns[s];
        float2 v = *(const float2*)(hin + (size_t)s * HF + lane * 2);
        ax = fmaf(c, v.x, ax); ay = fmaf(c, v.y, ay);
    }
    float m = nd[node];
    *(float2*)(agg + (size_t)node * HF + lane * 2) = make_float2(ax * m, ay * m);
}

// ---------------------------------------------------------------------------
// Fused GEMM: t = A @ W + bias [+ RES*ori], then
//   MODE 0: store t -> out2 (=ori buffer, lives in d_out); LN/ReLU -> hout
//   MODE 1: LN/ReLU -> hout only
//   MODE 2: store t -> out2 (final output)
// ---------------------------------------------------------------------------
template <int MODE>
__global__ __launch_bounds__(GEMM_THREADS) void gemm_fused(
    const float* __restrict__ A, const float* __restrict__ Wp,
    const float* __restrict__ bias, const float* __restrict__ lng,
    const float* __restrict__ lnb, const float* __restrict__ ori,
    float* __restrict__ hout, float* __restrict__ out2)
{
    __shared__ float sW[HF * HF];   // 64 KiB
    const int tid = threadIdx.x;
    const int row0 = blockIdx.x * MT;

    const float4* W4 = (const float4*)Wp;
    float4* sW4 = (float4*)sW;
#pragma unroll
    for (int i = 0; i < (HF * HF / 4) / GEMM_THREADS; ++i)
        sW4[tid + i * GEMM_THREADS] = W4[tid + i * GEMM_THREADS];
    __syncthreads();

    const int cg = tid & 31;        // col group: cols cg*4 .. cg*4+3
    const int rg = tid >> 5;        // row group

    const float* Ar0 = A + (size_t)(row0 + rg * RPT) * HF;
    const float* Ar1 = Ar0 + HF;

    float acc[RPT][4] = {};
    for (int k = 0; k < HF; k += 4) {
        float4 a0 = *(const float4*)(Ar0 + k);
        float4 a1 = *(const float4*)(Ar1 + k);
#pragma unroll
        for (int j = 0; j < 4; ++j) {
            float4 w = *(const float4*)(sW + (k + j) * HF + cg * 4);
            float av0 = j == 0 ? a0.x : j == 1 ? a0.y : j == 2 ? a0.z : a0.w;
            float av1 = j == 0 ? a1.x : j == 1 ? a1.y : j == 2 ? a1.z : a1.w;
            acc[0][0] = fmaf(av0, w.x, acc[0][0]);
            acc[0][1] = fmaf(av0, w.y, acc[0][1]);
            acc[0][2] = fmaf(av0, w.z, acc[0][2]);
            acc[0][3] = fmaf(av0, w.w, acc[0][3]);
            acc[1][0] = fmaf(av1, w.x, acc[1][0]);
            acc[1][1] = fmaf(av1, w.y, acc[1][1]);
            acc[1][2] = fmaf(av1, w.z, acc[1][2]);
            acc[1][3] = fmaf(av1, w.w, acc[1][3]);
        }
    }

    const float4 bia = *(const float4*)(bias + cg * 4);
    float4 gg, bb;
    if constexpr (MODE != 2) {
        gg = *(const float4*)(lng + cg * 4);
        bb = *(const float4*)(lnb + cg * 4);
    }

#pragma unroll
    for (int r = 0; r < RPT; ++r) {
        const int row = row0 + rg * RPT + r;
        const size_t off = (size_t)row * HF + cg * 4;
        float t0 = acc[r][0] + bia.x, t1 = acc[r][1] + bia.y;
        float t2 = acc[r][2] + bia.z, t3 = acc[r][3] + bia.w;
        if constexpr (MODE != 0) {
            float4 o = *(const float4*)(ori + off);
            t0 = fmaf(RESC, o.x, t0); t1 = fmaf(RESC, o.y, t1);
            t2 = fmaf(RESC, o.z, t2); t3 = fmaf(RESC, o.w, t3);
        }
        if constexpr (MODE == 0)
            *(float4*)(out2 + off) = make_float4(t0, t1, t2, t3);
        if constexpr (MODE == 2) {
            *(float4*)(out2 + off) = make_float4(t0, t1, t2, t3);
        } else {
            float s  = t0 + t1 + t2 + t3;
            float ss = t0 * t0 + t1 * t1 + t2 * t2 + t3 * t3;
#pragma unroll
            for (int m = 16; m >= 1; m >>= 1) {
                s  += __shfl_xor(s, m);
                ss += __shfl_xor(ss, m);
            }
            float mu   = s * (1.0f / HF);
            float var  = ss * (1.0f / HF) - mu * mu;
            float rinv = rsqrtf(var + LN_EPS);
            float y0 = fmaxf(0.f, (t0 - mu) * rinv * gg.x + bb.x);
            float y1 = fmaxf(0.f, (t1 - mu) * rinv * gg.y + bb.y);
            float y2 = fmaxf(0.f, (t2 - mu) * rinv * gg.z + bb.z);
            float y3 = fmaxf(0.f, (t3 - mu) * rinv * gg.w + bb.w);
            *(float4*)(hout + off) = make_float4(y0, y1, y2, y3);
        }
    }
}

// ---------------------------------------------------------------------------
extern "C" void kernel_launch(void* const* d_in, const int* in_sizes, int n_in,
                              void* d_out, int out_size, void* d_ws, size_t ws_size,
                              hipStream_t stream)
{
    const float* x   = (const float*)d_in[0];
    const float* W0  = (const float*)d_in[1];
    const float* Ws  = (const float*)d_in[2];
    const float* b   = (const float*)d_in[3];
    const float* lng = (const float*)d_in[4];
    const float* lnb = (const float*)d_in[5];
    const int*   src = (const int*)d_in[6];
    const int*   dst = (const int*)d_in[7];
    float* out = (float*)d_out;

    // workspace layout (512B-aligned chunks), total ~123.6 MB
    char* ws = (char*)d_ws;
    int*   cnt       = (int*)(ws + 0);            // N ints (deg_in)
    int*   deg_out   = (int*)(ws + 400384);       // N ints
    float* ns        = (float*)(ws + 800768);     // N f32
    float* nd        = (float*)(ws + 1201152);    // N f32
    int*   nodeOfs   = (int*)(ws + 1601536);      // N+1 ints
    int*   blockSum  = (int*)(ws + 2001920);      // 98 ints
    int*   blockBase = (int*)(ws + 2002432);      // 98 ints
    int*   binCursor = (int*)(ws + 2002944);      // 782 ints (pad 3328)
    int2*  pairs     = (int2*)(ws + 2006272);     // E int2 = 12.8 MB
    int*   csr       = (int*)(ws + 14806272);     // E ints = 6.4 MB
    float* hin       = (float*)(ws + 21206272);   // N*128 f32 = 51.2 MB
    float* agg       = (float*)(ws + 72406272);   // N*128 f32 = 51.2 MB

    // zero cnt + deg_out (contiguous)
    hipMemsetAsync(cnt, 0, 800768, stream);

    count_kernel<<<(N_EDGES + 255) / 256, 256, 0, stream>>>(src, dst, deg_out, cnt);
    scan1_kernel<<<NSCAN_BLK, 1024, 0, stream>>>(cnt, nodeOfs, blockSum);
    scan2_kernel<<<1, 64, 0, stream>>>(blockSum, blockBase);
    scan3_kernel<<<NSCAN_BLK, 1024, 0, stream>>>(nodeOfs, blockBase, binCursor);
    binscat_kernel<<<(N_EDGES + 255) / 256, 256, 0, stream>>>(src, dst, binCursor, pairs);
    csrscat_kernel<<<NBIN, 256, 0, stream>>>(pairs, nodeOfs, csr);
    norm_kernel<<<(N_NODES + 255) / 256, 256, 0, stream>>>(deg_out, cnt, ns, nd);

    // layer 0: agg0 = norm-agg(x); ori(d_out) = agg0@W0+b0; hin = relu(LN1(ori))
    agg_kernel<<<N_NODES / 4, 256, 0, stream>>>(x, csr, nodeOfs, ns, nd, agg);
    gemm_fused<0><<<N_NODES / MT, GEMM_THREADS, 0, stream>>>(
        agg, W0, b, lng + HF, lnb + HF, nullptr, hin, out);

    // layer 1
    agg_kernel<<<N_NODES / 4, 256, 0, stream>>>(hin, csr, nodeOfs, ns, nd, agg);
    gemm_fused<1><<<N_NODES / MT, GEMM_THREADS, 0, stream>>>(
        agg, Ws, b + HF, lng + 2 * HF, lnb + 2 * HF, out, hin, nullptr);

    // layer 2
    agg_kernel<<<N_NODES / 4, 256, 0, stream>>>(hin, csr, nodeOfs, ns, nd, agg);
    gemm_fused<2><<<N_NODES / MT, GEMM_THREADS, 0, stream>>>(
        agg, Ws + HF * HF, b + 2 * HF, nullptr, nullptr, out, nullptr, out);
}

// Round 3
// 860.849 us; speedup vs baseline: 1.3625x; 1.3625x over previous
//
#include <hip/hip_runtime.h>

// Problem constants (fixed by the reference)
#define N_NODES 100000
#define N_EDGES 1600000
#define HF      128
#define RESC    0.5f
#define LN_EPS  1e-5f

#define NCOPY      8            // one count/cursor copy per XCD
#define NSCAN_BLK  ((N_NODES + 1023) / 1024)              // 98

#define GEMM_THREADS 512
#define MT  128             // rows per GEMM block
#define RPT 8               // rows per thread

// ---------------------------------------------------------------------------
// Degree counting, privatized 8-way so atomics stay XCD-local (bid&7 follows
// the round-robin block->XCD heuristic; correctness independent of mapping).
// ---------------------------------------------------------------------------
__global__ __launch_bounds__(256) void count_kernel(
    const int* __restrict__ src, const int* __restrict__ dst,
    int* __restrict__ deg8, int* __restrict__ cnt8)
{
    int e = blockIdx.x * 256 + threadIdx.x;
    if (e >= N_EDGES) return;
    size_t copy = (size_t)(blockIdx.x & (NCOPY - 1)) * N_NODES;
    atomicAdd(deg8 + copy + src[e], 1);
    atomicAdd(cnt8 + copy + dst[e], 1);
}

// ---------------------------------------------------------------------------
// 3-stage exclusive prefix sum of (sum over copies of cnt8)[N] -> nodeOfs[N+1]
// ---------------------------------------------------------------------------
__global__ __launch_bounds__(1024) void scan1_kernel(
    const int* __restrict__ cnt8, int* __restrict__ nodeOfs, int* __restrict__ blockSum)
{
    __shared__ int wsum[16];
    int j = blockIdx.x * 1024 + threadIdx.x;
    int lane = threadIdx.x & 63, wid = threadIdx.x >> 6;
    int v = 0;
    if (j < N_NODES) {
#pragma unroll
        for (int c = 0; c < NCOPY; ++c) v += cnt8[(size_t)c * N_NODES + j];
    }
    int x = v;
#pragma unroll
    for (int off = 1; off < 64; off <<= 1) { int u = __shfl_up(x, off); if (lane >= off) x += u; }
    if (lane == 63) wsum[wid] = x;
    __syncthreads();
    if (wid == 0) {
        int y = (lane < 16) ? wsum[lane] : 0;
#pragma unroll
        for (int off = 1; off < 16; off <<= 1) { int u = __shfl_up(y, off); if (lane >= off) y += u; }
        if (lane < 16) wsum[lane] = y;
    }
    __syncthreads();
    int incl = x + (wid > 0 ? wsum[wid - 1] : 0);
    if (j < N_NODES) nodeOfs[j + 1] = incl;            // partial; base added in scan3
    if (threadIdx.x == 1023) blockSum[blockIdx.x] = incl;
}

__global__ __launch_bounds__(64) void scan2_kernel(
    const int* __restrict__ blockSum, int* __restrict__ blockBase)
{
    int lane = threadIdx.x;
    int carry = 0;
    for (int base = 0; base < NSCAN_BLK; base += 64) {
        int v = (base + lane < NSCAN_BLK) ? blockSum[base + lane] : 0;
        int x = v;
#pragma unroll
        for (int off = 1; off < 64; off <<= 1) { int u = __shfl_up(x, off); if (lane >= off) x += u; }
        if (base + lane < NSCAN_BLK) blockBase[base + lane] = x - v + carry;
        carry += __shfl(x, 63);
    }
}

__global__ __launch_bounds__(1024) void scan3_kernel(
    int* __restrict__ nodeOfs, const int* __restrict__ blockBase)
{
    int j = blockIdx.x * 1024 + threadIdx.x;
    if (j >= N_NODES) return;
    nodeOfs[j + 1] += blockBase[blockIdx.x];
    if (j == 0) nodeOfs[0] = 0;
}

// ---------------------------------------------------------------------------
// Per-copy CSR cursors: copy c's sub-range of node j's CSR row starts at
// nodeOfs[j] + sum_{c'<c} cnt8[c'][j].
// ---------------------------------------------------------------------------
__global__ __launch_bounds__(256) void cursinit_kernel(
    const int* __restrict__ cnt8, const int* __restrict__ nodeOfs,
    int* __restrict__ curs8)
{
    int j = blockIdx.x * 256 + threadIdx.x;
    if (j >= N_NODES) return;
    int run = nodeOfs[j];
#pragma unroll
    for (int c = 0; c < NCOPY; ++c) {
        curs8[(size_t)c * N_NODES + j] = run;
        run += cnt8[(size_t)c * N_NODES + j];
    }
}

__global__ __launch_bounds__(256) void norm_kernel(
    const int* __restrict__ deg8, const int* __restrict__ nodeOfs,
    float* __restrict__ ns, float* __restrict__ nd)
{
    int i = blockIdx.x * 256 + threadIdx.x;
    if (i >= N_NODES) return;
    int dsum = 0;
#pragma unroll
    for (int c = 0; c < NCOPY; ++c) dsum += deg8[(size_t)c * N_NODES + i];
    ns[i] = rsqrtf((float)max(dsum, 1));
    int din = nodeOfs[i + 1] - nodeOfs[i];
    nd[i] = rsqrtf((float)max(din, 1));
}

// ---------------------------------------------------------------------------
// CSR scatter with XCD-local cursors.
// ---------------------------------------------------------------------------
__global__ __launch_bounds__(256) void scatter_kernel(
    const int* __restrict__ src, const int* __restrict__ dst,
    int* __restrict__ curs8, int* __restrict__ csr)
{
    int e = blockIdx.x * 256 + threadIdx.x;
    if (e >= N_EDGES) return;
    int s = src[e], d = dst[e];
    int pos = atomicAdd(curs8 + (size_t)(blockIdx.x & (NCOPY - 1)) * N_NODES + d, 1);
    csr[pos] = s;
}

// ---------------------------------------------------------------------------
// Aggregation: one 64-lane wave per node. Per 64-edge chunk: one coalesced
// csr load, then readlane-broadcast src ids -> row loads are SGPR-base
// coalesced 512B reads with no dependent per-edge scalar loads.
// NS: gather ns[src] per edge (layer 0 only; later layers consume rows
// pre-scaled by the producing GEMM's epilogue).
// ---------------------------------------------------------------------------
template <bool NS>
__global__ __launch_bounds__(256) void agg_kernel(
    const float* __restrict__ hin, const int* __restrict__ csr,
    const int* __restrict__ nodeOfs, const float* __restrict__ ns,
    const float* __restrict__ nd, float* __restrict__ agg)
{
    int node = blockIdx.x * 4 + (threadIdx.x >> 6);
    if (node >= N_NODES) return;
    int lane = threadIdx.x & 63;
    int beg = nodeOfs[node], end = nodeOfs[node + 1];

    float ax = 0.f, ay = 0.f, bx = 0.f, by = 0.f;
    for (int base = beg; base < end; base += 64) {
        int m = min(64, end - base);
        int sl = (lane < m) ? csr[base + lane] : 0;
        unsigned clu = 0;
        if (NS) { float cl = (lane < m) ? ns[sl] : 0.f; clu = __float_as_uint(cl); }
        int k = 0;
        for (; k + 1 < m; k += 2) {
            int s0 = __builtin_amdgcn_readlane(sl, k);
            int s1 = __builtin_amdgcn_readlane(sl, k + 1);
            float2 v0 = *(const float2*)(hin + (size_t)s0 * HF + lane * 2);
            float2 v1 = *(const float2*)(hin + (size_t)s1 * HF + lane * 2);
            if (NS) {
                float c0 = __uint_as_float(__builtin_amdgcn_readlane(clu, k));
                float c1 = __uint_as_float(__builtin_amdgcn_readlane(clu, k + 1));
                ax = fmaf(c0, v0.x, ax); ay = fmaf(c0, v0.y, ay);
                bx = fmaf(c1, v1.x, bx); by = fmaf(c1, v1.y, by);
            } else {
                ax += v0.x; ay += v0.y; bx += v1.x; by += v1.y;
            }
        }
        if (k < m) {
            int s0 = __builtin_amdgcn_readlane(sl, k);
            float2 v0 = *(const float2*)(hin + (size_t)s0 * HF + lane * 2);
            if (NS) {
                float c0 = __uint_as_float(__builtin_amdgcn_readlane(clu, k));
                ax = fmaf(c0, v0.x, ax); ay = fmaf(c0, v0.y, ay);
            } else {
                ax += v0.x; ay += v0.y;
            }
        }
    }
    float mm = nd[node];
    *(float2*)(agg + (size_t)node * HF + lane * 2) =
        make_float2((ax + bx) * mm, (ay + by) * mm);
}

// ---------------------------------------------------------------------------
// Fused GEMM: t = A @ W + bias [+ RES*ori], then
//   MODE 0: store t -> out2 (ori buffer = d_out); ns[row]*relu(LN(t)) -> hout
//   MODE 1: ns[row]*relu(LN(t)) -> hout only
//   MODE 2: store t -> out2 (final output, NOT scaled)
// RPT=8 rows/thread: per-thread W LDS traffic fixed at 2KB, fma scales ->
// fma-bound (~16K cy/block) instead of ds_read_b128-bound.
// ---------------------------------------------------------------------------
template <int MODE>
__global__ __launch_bounds__(GEMM_THREADS) void gemm_fused(
    const float* __restrict__ A, const float* __restrict__ Wp,
    const float* __restrict__ bias, const float* __restrict__ lng,
    const float* __restrict__ lnb, const float* __restrict__ ori,
    const float* __restrict__ ns, float* __restrict__ hout,
    float* __restrict__ out2)
{
    __shared__ float sW[HF * HF];   // 64 KiB
    const int tid = threadIdx.x;
    const int row0 = blockIdx.x * MT;

    const float4* W4 = (const float4*)Wp;
    float4* sW4 = (float4*)sW;
#pragma unroll
    for (int i = 0; i < (HF * HF / 4) / GEMM_THREADS; ++i)
        sW4[tid + i * GEMM_THREADS] = W4[tid + i * GEMM_THREADS];
    __syncthreads();

    const int cg = tid & 31;        // col group: cols cg*4 .. cg*4+3
    const int rg = tid >> 5;        // row group: rows rbase .. rbase+RPT-1
    const int rbase = row0 + rg * RPT;

    const float* Ar[RPT];
#pragma unroll
    for (int r = 0; r < RPT; ++r) {
        int row = min(rbase + r, N_NODES - 1);
        Ar[r] = A + (size_t)row * HF;
    }

    float acc[RPT][4] = {};
    for (int k = 0; k < HF; k += 4) {
        float a[RPT][4];
#pragma unroll
        for (int r = 0; r < RPT; ++r) {
            float4 t = *(const float4*)(Ar[r] + k);
            a[r][0] = t.x; a[r][1] = t.y; a[r][2] = t.z; a[r][3] = t.w;
        }
#pragma unroll
        for (int j = 0; j < 4; ++j) {
            float4 w = *(const float4*)(sW + (k + j) * HF + cg * 4);
#pragma unroll
            for (int r = 0; r < RPT; ++r) {
                acc[r][0] = fmaf(a[r][j], w.x, acc[r][0]);
                acc[r][1] = fmaf(a[r][j], w.y, acc[r][1]);
                acc[r][2] = fmaf(a[r][j], w.z, acc[r][2]);
                acc[r][3] = fmaf(a[r][j], w.w, acc[r][3]);
            }
        }
    }

    const float4 bia = *(const float4*)(bias + cg * 4);
    float4 gg, bb;
    if constexpr (MODE != 2) {
        gg = *(const float4*)(lng + cg * 4);
        bb = *(const float4*)(lnb + cg * 4);
    }

#pragma unroll
    for (int r = 0; r < RPT; ++r) {
        const int row = rbase + r;
        const bool ok = row < N_NODES;
        const int rowc = ok ? row : N_NODES - 1;
        const size_t off = (size_t)rowc * HF + cg * 4;
        float t0 = acc[r][0] + bia.x, t1 = acc[r][1] + bia.y;
        float t2 = acc[r][2] + bia.z, t3 = acc[r][3] + bia.w;
        if constexpr (MODE != 0) {
            float4 o = *(const float4*)(ori + off);
            t0 = fmaf(RESC, o.x, t0); t1 = fmaf(RESC, o.y, t1);
            t2 = fmaf(RESC, o.z, t2); t3 = fmaf(RESC, o.w, t3);
        }
        if constexpr (MODE == 2) {
            if (ok) *(float4*)(out2 + off) = make_float4(t0, t1, t2, t3);
        } else {
            if constexpr (MODE == 0)
                if (ok) *(float4*)(out2 + off) = make_float4(t0, t1, t2, t3);
            float s  = t0 + t1 + t2 + t3;
            float ss = t0 * t0 + t1 * t1 + t2 * t2 + t3 * t3;
#pragma unroll
            for (int m = 16; m >= 1; m >>= 1) {
                s  += __shfl_xor(s, m);
                ss += __shfl_xor(ss, m);
            }
            float mu   = s * (1.0f / HF);
            float var  = ss * (1.0f / HF) - mu * mu;
            float rinv = rsqrtf(var + LN_EPS);
            float nsr  = ns[rowc];   // pre-scale for next layer's aggregation
            float y0 = nsr * fmaxf(0.f, (t0 - mu) * rinv * gg.x + bb.x);
            float y1 = nsr * fmaxf(0.f, (t1 - mu) * rinv * gg.y + bb.y);
            float y2 = nsr * fmaxf(0.f, (t2 - mu) * rinv * gg.z + bb.z);
            float y3 = nsr * fmaxf(0.f, (t3 - mu) * rinv * gg.w + bb.w);
            if (ok) *(float4*)(hout + off) = make_float4(y0, y1, y2, y3);
        }
    }
}

// ---------------------------------------------------------------------------
extern "C" void kernel_launch(void* const* d_in, const int* in_sizes, int n_in,
                              void* d_out, int out_size, void* d_ws, size_t ws_size,
                              hipStream_t stream)
{
    const float* x   = (const float*)d_in[0];
    const float* W0  = (const float*)d_in[1];
    const float* Ws  = (const float*)d_in[2];
    const float* b   = (const float*)d_in[3];
    const float* lng = (const float*)d_in[4];
    const float* lnb = (const float*)d_in[5];
    const int*   src = (const int*)d_in[6];
    const int*   dst = (const int*)d_in[7];
    float* out = (float*)d_out;

    // workspace layout, total ~119.6 MB
    char* ws = (char*)d_ws;
    int*   cnt8      = (int*)(ws + 0);            // 8*N ints = 3.2 MB
    int*   deg8      = (int*)(ws + 3200000);      // 8*N ints = 3.2 MB
    int*   curs8     = (int*)(ws + 6400000);      // 8*N ints = 3.2 MB
    float* ns        = (float*)(ws + 9600000);    // N f32
    float* nd        = (float*)(ws + 10000000);   // N f32
    int*   nodeOfs   = (int*)(ws + 10400000);     // N+1 ints
    int*   blockSum  = (int*)(ws + 10800128);     // 98 ints
    int*   blockBase = (int*)(ws + 10800640);     // 98 ints
    int*   csr       = (int*)(ws + 10801152);     // E ints = 6.4 MB
    float* hin       = (float*)(ws + 17201152);   // N*128 f32 = 51.2 MB
    float* agg       = (float*)(ws + 68401152);   // N*128 f32 = 51.2 MB

    // zero cnt8 + deg8 (contiguous 6.4 MB)
    hipMemsetAsync(cnt8, 0, 6400000, stream);

    count_kernel<<<(N_EDGES + 255) / 256, 256, 0, stream>>>(src, dst, deg8, cnt8);
    scan1_kernel<<<NSCAN_BLK, 1024, 0, stream>>>(cnt8, nodeOfs, blockSum);
    scan2_kernel<<<1, 64, 0, stream>>>(blockSum, blockBase);
    scan3_kernel<<<NSCAN_BLK, 1024, 0, stream>>>(nodeOfs, blockBase);
    cursinit_kernel<<<(N_NODES + 255) / 256, 256, 0, stream>>>(cnt8, nodeOfs, curs8);
    norm_kernel<<<(N_NODES + 255) / 256, 256, 0, stream>>>(deg8, nodeOfs, ns, nd);
    scatter_kernel<<<(N_EDGES + 255) / 256, 256, 0, stream>>>(src, dst, curs8, csr);

    const int gemm_grid = (N_NODES + MT - 1) / MT;   // 782

    // layer 0: agg0 = nd*sum(ns[s]*x[s]); ori(d_out) = agg0@W0+b0; hin = ns*relu(LN1(ori))
    agg_kernel<true><<<(N_NODES + 3) / 4, 256, 0, stream>>>(x, csr, nodeOfs, ns, nd, agg);
    gemm_fused<0><<<gemm_grid, GEMM_THREADS, 0, stream>>>(
        agg, W0, b, lng + HF, lnb + HF, nullptr, ns, hin, out);

    // layer 1: agg1 = nd*sum(hin[s]); h1 = agg1@Ws0+b1+0.5*ori; hin = ns*relu(LN2(h1))
    agg_kernel<false><<<(N_NODES + 3) / 4, 256, 0, stream>>>(hin, csr, nodeOfs, ns, nd, agg);
    gemm_fused<1><<<gemm_grid, GEMM_THREADS, 0, stream>>>(
        agg, Ws, b + HF, lng + 2 * HF, lnb + 2 * HF, out, ns, hin, nullptr);

    // layer 2: agg2 = nd*sum(hin[s]); out = agg2@Ws1+b2+0.5*ori
    agg_kernel<false><<<(N_NODES + 3) / 4, 256, 0, stream>>>(hin, csr, nodeOfs, ns, nd, agg);
    gemm_fused<2><<<gemm_grid, GEMM_THREADS, 0, stream>>>(
        agg, Ws + HF * HF, b + 2 * HF, nullptr, nullptr, out, ns, nullptr, out);
}

// Round 4
// 795.242 us; speedup vs baseline: 1.4749x; 1.0825x over previous
//
#include <hip/hip_runtime.h>

// Problem constants (fixed by the reference)
#define N_NODES 100000
#define N_EDGES 1600000
#define HF      128
#define RESC    0.5f
#define LN_EPS  1e-5f

#define NCOPY      8                                      // one copy per XCD
#define BINW_SHIFT 7
#define BINW       128
#define NBIN       ((N_NODES + BINW - 1) >> BINW_SHIFT)   // 782
#define NSCAN_BLK  ((N_NODES + 1023) / 1024)              // 98

#define GEMM_THREADS 512
#define MT  128             // rows per GEMM block
#define RPT 8               // rows per thread

// bf16 helpers (round-to-nearest-even)
static __device__ __forceinline__ unsigned f2b(float f) {
    unsigned u = __float_as_uint(f);
    return (u + 0x7FFFu + ((u >> 16) & 1u)) >> 16;
}
static __device__ __forceinline__ unsigned pack2(float a, float b) {
    return f2b(a) | (f2b(b) << 16);
}
static __device__ __forceinline__ float b2f(unsigned short u) {
    return __uint_as_float(((unsigned)u) << 16);
}

// ---------------------------------------------------------------------------
// Degree + per-(copy,bin) histogram. All atomics XCD-privatized (bid&7).
// ---------------------------------------------------------------------------
__global__ __launch_bounds__(256) void count_kernel(
    const int* __restrict__ src, const int* __restrict__ dst,
    int* __restrict__ deg8, int* __restrict__ cnt8, int* __restrict__ bincnt8)
{
    int e = blockIdx.x * 256 + threadIdx.x;
    if (e >= N_EDGES) return;
    int copy = blockIdx.x & (NCOPY - 1);
    int s = src[e], d = dst[e];
    atomicAdd(deg8 + (size_t)copy * N_NODES + s, 1);
    atomicAdd(cnt8 + (size_t)copy * N_NODES + d, 1);
    atomicAdd(bincnt8 + copy * NBIN + (d >> BINW_SHIFT), 1);
}

// ---------------------------------------------------------------------------
// 3-stage exclusive prefix sum of (sum over copies of cnt8)[N] -> nodeOfs[N+1]
// ---------------------------------------------------------------------------
__global__ __launch_bounds__(1024) void scan1_kernel(
    const int* __restrict__ cnt8, int* __restrict__ nodeOfs, int* __restrict__ blockSum)
{
    __shared__ int wsum[16];
    int j = blockIdx.x * 1024 + threadIdx.x;
    int lane = threadIdx.x & 63, wid = threadIdx.x >> 6;
    int v = 0;
    if (j < N_NODES) {
#pragma unroll
        for (int c = 0; c < NCOPY; ++c) v += cnt8[(size_t)c * N_NODES + j];
    }
    int x = v;
#pragma unroll
    for (int off = 1; off < 64; off <<= 1) { int u = __shfl_up(x, off); if (lane >= off) x += u; }
    if (lane == 63) wsum[wid] = x;
    __syncthreads();
    if (wid == 0) {
        int y = (lane < 16) ? wsum[lane] : 0;
#pragma unroll
        for (int off = 1; off < 16; off <<= 1) { int u = __shfl_up(y, off); if (lane >= off) y += u; }
        if (lane < 16) wsum[lane] = y;
    }
    __syncthreads();
    int incl = x + (wid > 0 ? wsum[wid - 1] : 0);
    if (j < N_NODES) nodeOfs[j + 1] = incl;            // partial; base added in scan3
    if (threadIdx.x == 1023) blockSum[blockIdx.x] = incl;
}

__global__ __launch_bounds__(64) void scan2_kernel(
    const int* __restrict__ blockSum, int* __restrict__ blockBase)
{
    int lane = threadIdx.x;
    int carry = 0;
    for (int base = 0; base < NSCAN_BLK; base += 64) {
        int v = (base + lane < NSCAN_BLK) ? blockSum[base + lane] : 0;
        int x = v;
#pragma unroll
        for (int off = 1; off < 64; off <<= 1) { int u = __shfl_up(x, off); if (lane >= off) x += u; }
        if (base + lane < NSCAN_BLK) blockBase[base + lane] = x - v + carry;
        carry += __shfl(x, 63);
    }
}

__global__ __launch_bounds__(1024) void scan3_kernel(
    int* __restrict__ nodeOfs, const int* __restrict__ blockBase)
{
    int j = blockIdx.x * 1024 + threadIdx.x;
    if (j >= N_NODES) return;
    nodeOfs[j + 1] += blockBase[blockIdx.x];
    if (j == 0) nodeOfs[0] = 0;
}

// ---------------------------------------------------------------------------
// Per-(copy,bin) pair cursors: copy c's frontier in bin b starts at
// nodeOfs[b*BINW] + sum_{c'<c} bincnt8[c'][b].
// ---------------------------------------------------------------------------
__global__ __launch_bounds__(256) void bincurs_kernel(
    const int* __restrict__ bincnt8, const int* __restrict__ nodeOfs,
    int* __restrict__ bincurs8)
{
    int b = blockIdx.x * 256 + threadIdx.x;
    if (b >= NBIN) return;
    int run = nodeOfs[b << BINW_SHIFT];
#pragma unroll
    for (int c = 0; c < NCOPY; ++c) {
        bincurs8[c * NBIN + b] = run;
        run += bincnt8[c * NBIN + b];
    }
}

__global__ __launch_bounds__(256) void norm_kernel(
    const int* __restrict__ deg8, const int* __restrict__ nodeOfs,
    float* __restrict__ ns, float* __restrict__ nd)
{
    int i = blockIdx.x * 256 + threadIdx.x;
    if (i >= N_NODES) return;
    int dsum = 0;
#pragma unroll
    for (int c = 0; c < NCOPY; ++c) dsum += deg8[(size_t)c * N_NODES + i];
    ns[i] = rsqrtf((float)max(dsum, 1));
    int din = nodeOfs[i + 1] - nodeOfs[i];
    nd[i] = rsqrtf((float)max(din, 1));
}

// ---------------------------------------------------------------------------
// xb[i] = bf16(ns[row] * x[i]) — pre-scaled bf16 copy of x for the gather.
// ---------------------------------------------------------------------------
__global__ __launch_bounds__(256) void xconv_kernel(
    const float* __restrict__ x, const float* __restrict__ ns,
    unsigned* __restrict__ xb)   // as uint (2 bf16 each)
{
    int idx = blockIdx.x * 256 + threadIdx.x;    // 8 elements per thread
    if (idx >= N_NODES * HF / 8) return;
    int row = idx >> 4;
    float c = ns[row];
    const float4* px = (const float4*)(x + (size_t)idx * 8);
    float4 v0 = px[0], v1 = px[1];
    uint4 o;
    o.x = pack2(c * v0.x, c * v0.y);
    o.y = pack2(c * v0.z, c * v0.w);
    o.z = pack2(c * v1.x, c * v1.y);
    o.w = pack2(c * v1.z, c * v1.w);
    *(uint4*)(xb + (size_t)idx * 4) = o;
}

// ---------------------------------------------------------------------------
// Bin-scatter: append packed (s<<7 | d&127) to dst's bin via XCD-local
// cursors. ~6256 sequential write frontiers -> write amplification ~1.
// ---------------------------------------------------------------------------
__global__ __launch_bounds__(256) void binscat_kernel(
    const int* __restrict__ src, const int* __restrict__ dst,
    int* __restrict__ bincurs8, int* __restrict__ pairs)
{
    int e = blockIdx.x * 256 + threadIdx.x;
    if (e >= N_EDGES) return;
    int s = src[e], d = dst[e];
    int pos = atomicAdd(bincurs8 + (blockIdx.x & (NCOPY - 1)) * NBIN + (d >> BINW_SHIFT), 1);
    pairs[pos] = (s << BINW_SHIFT) | (d & (BINW - 1));
}

// ---------------------------------------------------------------------------
// Per-bin CSR scatter: LDS cursors; all writes land in the bin's ~8KB
// contiguous L2-hot csr window.
// ---------------------------------------------------------------------------
__global__ __launch_bounds__(256) void csrscat_kernel(
    const int* __restrict__ pairs, const int* __restrict__ nodeOfs,
    int* __restrict__ csr)
{
    __shared__ int curs[BINW];
    int nstart = blockIdx.x << BINW_SHIFT;
    int nend = min(nstart + BINW, N_NODES);
    if (threadIdx.x < nend - nstart) curs[threadIdx.x] = nodeOfs[nstart + threadIdx.x];
    __syncthreads();
    int beg = nodeOfs[nstart];
    int end = nodeOfs[nend];
    for (int e = beg + (int)threadIdx.x; e < end; e += 256) {
        int p = pairs[e];
        int pos = atomicAdd(&curs[p & (BINW - 1)], 1);
        csr[pos] = p >> BINW_SHIFT;
    }
}

// ---------------------------------------------------------------------------
// Aggregation: one wave per node, bf16 rows (256B). Lane-halves own even/odd
// edges -> one dwordx2 load covers 2 rows per iteration; f32 accumulate;
// shfl_xor(.,32) combines halves; lanes 0-31 write the f32 agg row.
// Source rows are pre-scaled by ns; nd applied here.
// ---------------------------------------------------------------------------
__global__ __launch_bounds__(256) void agg_kernel(
    const unsigned short* __restrict__ hb, const int* __restrict__ csr,
    const int* __restrict__ nodeOfs, const float* __restrict__ nd,
    float* __restrict__ agg)
{
    int node = blockIdx.x * 4 + (threadIdx.x >> 6);
    if (node >= N_NODES) return;
    int lane = threadIdx.x & 63;
    int half = lane >> 5;
    int flo = (lane & 31) * 4;                 // 4 features per lane
    int beg = nodeOfs[node], end = nodeOfs[node + 1];

    float a0 = 0.f, a1 = 0.f, a2 = 0.f, a3 = 0.f;
    for (int base = beg; base < end; base += 64) {
        int m = min(64, end - base);
        int sl = (lane < m) ? csr[base + lane] : 0;
        int k = 0;
        for (; k + 1 < m; k += 2) {
            int s0 = __builtin_amdgcn_readlane(sl, k);
            int s1 = __builtin_amdgcn_readlane(sl, k + 1);
            int sr = half ? s1 : s0;
            ushort4 v = *(const ushort4*)(hb + (size_t)sr * HF + flo);
            a0 += b2f(v.x); a1 += b2f(v.y); a2 += b2f(v.z); a3 += b2f(v.w);
        }
        if (k < m && half == 0) {
            int s0 = __builtin_amdgcn_readlane(sl, k);
            ushort4 v = *(const ushort4*)(hb + (size_t)s0 * HF + flo);
            a0 += b2f(v.x); a1 += b2f(v.y); a2 += b2f(v.z); a3 += b2f(v.w);
        }
    }
    a0 += __shfl_xor(a0, 32); a1 += __shfl_xor(a1, 32);
    a2 += __shfl_xor(a2, 32); a3 += __shfl_xor(a3, 32);
    if (half == 0) {
        float mm = nd[node];
        *(float4*)(agg + (size_t)node * HF + flo) =
            make_float4(a0 * mm, a1 * mm, a2 * mm, a3 * mm);
    }
}

// ---------------------------------------------------------------------------
// Fused GEMM: t = A @ W + bias [+ RES*ori], then
//   MODE 0: t(f32) -> out2 (=ori=d_out); bf16(ns*relu(LN(t))) -> hb
//   MODE 1: bf16(ns*relu(LN(t))) -> hb
//   MODE 2: t(f32) -> out2 (final output)
// ---------------------------------------------------------------------------
template <int MODE>
__global__ __launch_bounds__(GEMM_THREADS) void gemm_fused(
    const float* __restrict__ A, const float* __restrict__ Wp,
    const float* __restrict__ bias, const float* __restrict__ lng,
    const float* __restrict__ lnb, const float* __restrict__ ori,
    const float* __restrict__ ns, unsigned short* __restrict__ hb,
    float* __restrict__ out2)
{
    __shared__ float sW[HF * HF];   // 64 KiB
    const int tid = threadIdx.x;
    const int row0 = blockIdx.x * MT;

    const float4* W4 = (const float4*)Wp;
    float4* sW4 = (float4*)sW;
#pragma unroll
    for (int i = 0; i < (HF * HF / 4) / GEMM_THREADS; ++i)
        sW4[tid + i * GEMM_THREADS] = W4[tid + i * GEMM_THREADS];
    __syncthreads();

    const int cg = tid & 31;        // col group: cols cg*4 .. cg*4+3
    const int rg = tid >> 5;        // row group: rows rbase .. rbase+RPT-1
    const int rbase = row0 + rg * RPT;

    const float* Ar[RPT];
#pragma unroll
    for (int r = 0; r < RPT; ++r) {
        int row = min(rbase + r, N_NODES - 1);
        Ar[r] = A + (size_t)row * HF;
    }

    float acc[RPT][4] = {};
    for (int k = 0; k < HF; k += 4) {
        float a[RPT][4];
#pragma unroll
        for (int r = 0; r < RPT; ++r) {
            float4 t = *(const float4*)(Ar[r] + k);
            a[r][0] = t.x; a[r][1] = t.y; a[r][2] = t.z; a[r][3] = t.w;
        }
#pragma unroll
        for (int j = 0; j < 4; ++j) {
            float4 w = *(const float4*)(sW + (k + j) * HF + cg * 4);
#pragma unroll
            for (int r = 0; r < RPT; ++r) {
                acc[r][0] = fmaf(a[r][j], w.x, acc[r][0]);
                acc[r][1] = fmaf(a[r][j], w.y, acc[r][1]);
                acc[r][2] = fmaf(a[r][j], w.z, acc[r][2]);
                acc[r][3] = fmaf(a[r][j], w.w, acc[r][3]);
            }
        }
    }

    const float4 bia = *(const float4*)(bias + cg * 4);
    float4 gg, bb;
    if constexpr (MODE != 2) {
        gg = *(const float4*)(lng + cg * 4);
        bb = *(const float4*)(lnb + cg * 4);
    }

#pragma unroll
    for (int r = 0; r < RPT; ++r) {
        const int row = rbase + r;
        const bool ok = row < N_NODES;
        const int rowc = ok ? row : N_NODES - 1;
        const size_t off = (size_t)rowc * HF + cg * 4;
        float t0 = acc[r][0] + bia.x, t1 = acc[r][1] + bia.y;
        float t2 = acc[r][2] + bia.z, t3 = acc[r][3] + bia.w;
        if constexpr (MODE != 0) {
            float4 o = *(const float4*)(ori + off);
            t0 = fmaf(RESC, o.x, t0); t1 = fmaf(RESC, o.y, t1);
            t2 = fmaf(RESC, o.z, t2); t3 = fmaf(RESC, o.w, t3);
        }
        if constexpr (MODE == 2) {
            if (ok) *(float4*)(out2 + off) = make_float4(t0, t1, t2, t3);
        } else {
            if constexpr (MODE == 0)
                if (ok) *(float4*)(out2 + off) = make_float4(t0, t1, t2, t3);
            float s  = t0 + t1 + t2 + t3;
            float ss = t0 * t0 + t1 * t1 + t2 * t2 + t3 * t3;
#pragma unroll
            for (int m = 16; m >= 1; m >>= 1) {
                s  += __shfl_xor(s, m);
                ss += __shfl_xor(ss, m);
            }
            float mu   = s * (1.0f / HF);
            float var  = ss * (1.0f / HF) - mu * mu;
            float rinv = rsqrtf(var + LN_EPS);
            float nsr  = ns[rowc];   // pre-scale for next layer's aggregation
            float y0 = nsr * fmaxf(0.f, (t0 - mu) * rinv * gg.x + bb.x);
            float y1 = nsr * fmaxf(0.f, (t1 - mu) * rinv * gg.y + bb.y);
            float y2 = nsr * fmaxf(0.f, (t2 - mu) * rinv * gg.z + bb.z);
            float y3 = nsr * fmaxf(0.f, (t3 - mu) * rinv * gg.w + bb.w);
            if (ok) {
                uint2 w2;
                w2.x = pack2(y0, y1);
                w2.y = pack2(y2, y3);
                *(uint2*)(hb + off) = w2;
            }
        }
    }
}

// ---------------------------------------------------------------------------
extern "C" void kernel_launch(void* const* d_in, const int* in_sizes, int n_in,
                              void* d_out, int out_size, void* d_ws, size_t ws_size,
                              hipStream_t stream)
{
    const float* x   = (const float*)d_in[0];
    const float* W0  = (const float*)d_in[1];
    const float* Ws  = (const float*)d_in[2];
    const float* b   = (const float*)d_in[3];
    const float* lng = (const float*)d_in[4];
    const float* lnb = (const float*)d_in[5];
    const int*   src = (const int*)d_in[6];
    const int*   dst = (const int*)d_in[7];
    float* out = (float*)d_out;

    // workspace layout, total ~122.9 MB
    char* ws = (char*)d_ws;
    int*   cnt8      = (int*)(ws + 0);            // 8*N = 3.2 MB
    int*   deg8      = (int*)(ws + 3200000);      // 8*N = 3.2 MB
    int*   bincnt8   = (int*)(ws + 6400000);      // 8*782 ints (pad 25600)
    float* ns        = (float*)(ws + 6425600);    // N f32
    float* nd        = (float*)(ws + 6825600);    // N f32
    int*   nodeOfs   = (int*)(ws + 7225600);      // N+1 ints (pad 400384)
    int*   blockSum  = (int*)(ws + 7625984);      // 98 ints (pad 512)
    int*   blockBase = (int*)(ws + 7626496);      // 98 ints (pad 512)
    int*   bincurs8  = (int*)(ws + 7627008);      // 8*782 ints (pad 25600)
    int*   pairs     = (int*)(ws + 7652608);      // E ints = 6.4 MB
    int*   csr       = (int*)(ws + 14052608);     // E ints = 6.4 MB
    unsigned*       xb = (unsigned*)(ws + 20452608);        // N*128 bf16 = 25.6 MB
    unsigned short* hb = (unsigned short*)(ws + 46052608);  // N*128 bf16 = 25.6 MB
    float* agg       = (float*)(ws + 71652608);   // N*128 f32 = 51.2 MB

    // zero cnt8 + deg8 + bincnt8 (contiguous)
    hipMemsetAsync(cnt8, 0, 6425600, stream);

    count_kernel<<<(N_EDGES + 255) / 256, 256, 0, stream>>>(src, dst, deg8, cnt8, bincnt8);
    scan1_kernel<<<NSCAN_BLK, 1024, 0, stream>>>(cnt8, nodeOfs, blockSum);
    scan2_kernel<<<1, 64, 0, stream>>>(blockSum, blockBase);
    scan3_kernel<<<NSCAN_BLK, 1024, 0, stream>>>(nodeOfs, blockBase);
    bincurs_kernel<<<(NBIN + 255) / 256, 256, 0, stream>>>(bincnt8, nodeOfs, bincurs8);
    norm_kernel<<<(N_NODES + 255) / 256, 256, 0, stream>>>(deg8, nodeOfs, ns, nd);
    xconv_kernel<<<(N_NODES * HF / 8 + 255) / 256, 256, 0, stream>>>(x, ns, xb);
    binscat_kernel<<<(N_EDGES + 255) / 256, 256, 0, stream>>>(src, dst, bincurs8, pairs);
    csrscat_kernel<<<NBIN, 256, 0, stream>>>(pairs, nodeOfs, csr);

    const int gemm_grid = (N_NODES + MT - 1) / MT;   // 782

    // layer 0
    agg_kernel<<<(N_NODES + 3) / 4, 256, 0, stream>>>(
        (const unsigned short*)xb, csr, nodeOfs, nd, agg);
    gemm_fused<0><<<gemm_grid, GEMM_THREADS, 0, stream>>>(
        agg, W0, b, lng + HF, lnb + HF, nullptr, ns, hb, out);

    // layer 1
    agg_kernel<<<(N_NODES + 3) / 4, 256, 0, stream>>>(hb, csr, nodeOfs, nd, agg);
    gemm_fused<1><<<gemm_grid, GEMM_THREADS, 0, stream>>>(
        agg, Ws, b + HF, lng + 2 * HF, lnb + 2 * HF, out, ns, hb, nullptr);

    // layer 2
    agg_kernel<<<(N_NODES + 3) / 4, 256, 0, stream>>>(hb, csr, nodeOfs, nd, agg);
    gemm_fused<2><<<gemm_grid, GEMM_THREADS, 0, stream>>>(
        agg, Ws + HF * HF, b + 2 * HF, nullptr, nullptr, out, ns, nullptr, out);
}

// Round 6
// 733.331 us; speedup vs baseline: 1.5994x; 1.0844x over previous
//
#include <hip/hip_runtime.h>

// Problem constants (fixed by the reference)
#define N_NODES 100000
#define N_EDGES 1600000
#define HF      128
#define RESC    0.5f
#define LN_EPS  1e-5f

#define NCOPY      8                                      // one copy per XCD
#define BINW_SHIFT 7
#define BINW       128
#define NBIN       ((N_NODES + BINW - 1) >> BINW_SHIFT)   // 782
#define HCHUNK     50176                                  // multiple of 256
#define NHBLK      ((N_EDGES + HCHUNK - 1) / HCHUNK)      // 32

#define GEMM_THREADS 512
#define MT  128             // rows per GEMM block
#define RPT 8               // rows per thread

// bf16 helpers (round-to-nearest-even)
static __device__ __forceinline__ unsigned f2b(float f) {
    unsigned u = __float_as_uint(f);
    return (u + 0x7FFFu + ((u >> 16) & 1u)) >> 16;
}
static __device__ __forceinline__ unsigned pack2(float a, float b) {
    return f2b(a) | (f2b(b) << 16);
}
static __device__ __forceinline__ float b2f(unsigned short u) {
    return __uint_as_float(((unsigned)u) << 16);
}

// ---------------------------------------------------------------------------
// Bin histograms (dst and src), 8-copy LDS privatized. copy = (e>>8)&7 —
// MUST match binscat_kernel's copy mapping exactly (R5 bug: it didn't).
// Global atomics: only the dense per-block flush (~32*12512 ~ 400K).
// ---------------------------------------------------------------------------
__global__ __launch_bounds__(256) void hist_kernel(
    const int* __restrict__ src, const int* __restrict__ dst,
    int* __restrict__ bincnt8, int* __restrict__ srcbincnt8)
{
    __shared__ int hd[NCOPY * NBIN];   // 25024 B
    __shared__ int hs[NCOPY * NBIN];   // 25024 B
    for (int i = threadIdx.x; i < NCOPY * NBIN; i += 256) { hd[i] = 0; hs[i] = 0; }
    __syncthreads();
    int base = blockIdx.x * HCHUNK;
    int lim = min(base + HCHUNK, N_EDGES);
    for (int e = base + (int)threadIdx.x; e < lim; e += 256) {
        int cb = ((e >> 8) & (NCOPY - 1)) * NBIN;   // wave-uniform per sweep
        atomicAdd(&hd[cb + (dst[e] >> BINW_SHIFT)], 1);
        atomicAdd(&hs[cb + (src[e] >> BINW_SHIFT)], 1);
    }
    __syncthreads();
    for (int i = threadIdx.x; i < NCOPY * NBIN; i += 256) {
        if (hd[i]) atomicAdd(bincnt8 + i, hd[i]);
        if (hs[i]) atomicAdd(srcbincnt8 + i, hs[i]);
    }
}

// ---------------------------------------------------------------------------
// Single-block scan over bins (both sides): binOfs[b] (global prefix) and
// per-(copy,bin) cursors.
// ---------------------------------------------------------------------------
__global__ __launch_bounds__(1024) void binscan_kernel(
    const int* __restrict__ bincnt8, const int* __restrict__ srcbincnt8,
    int* __restrict__ binOfs, int* __restrict__ srcbinOfs,
    int* __restrict__ bincurs8, int* __restrict__ srcbincurs8)
{
    __shared__ int wsum[16];
    for (int side = 0; side < 2; ++side) {
        const int* cnt = side ? srcbincnt8 : bincnt8;
        int* ofs  = side ? srcbinOfs : binOfs;
        int* curs = side ? srcbincurs8 : bincurs8;
        int b = threadIdx.x;
        int tot = 0, pc[NCOPY];
        if (b < NBIN) {
#pragma unroll
            for (int c = 0; c < NCOPY; ++c) { pc[c] = tot; tot += cnt[c * NBIN + b]; }
        }
        int lane = threadIdx.x & 63, wid = threadIdx.x >> 6;
        int x = tot;
#pragma unroll
        for (int off = 1; off < 64; off <<= 1) { int u = __shfl_up(x, off); if (lane >= off) x += u; }
        if (lane == 63) wsum[wid] = x;
        __syncthreads();
        if (wid == 0) {
            int y = (lane < 16) ? wsum[lane] : 0;
#pragma unroll
            for (int off = 1; off < 16; off <<= 1) { int u = __shfl_up(y, off); if (lane >= off) y += u; }
            if (lane < 16) wsum[lane] = y;
        }
        __syncthreads();
        int incl = x + (wid > 0 ? wsum[wid - 1] : 0);
        int excl = incl - tot;
        if (b < NBIN) {
            ofs[b + 1] = incl;
            if (b == 0) ofs[0] = 0;
#pragma unroll
            for (int c = 0; c < NCOPY; ++c) curs[c * NBIN + b] = excl + pc[c];
        }
        __syncthreads();   // wsum reused next side
    }
}

// ---------------------------------------------------------------------------
// Fused bin-scatter: dst side writes packed (s<<7|dloc) pairs; src side
// writes sloc bytes. copy = blockIdx&7 == (e>>8)&7 (256-edge blocks) —
// matches hist_kernel. Cursor atomics are 8-copy, 50KB hot, XCD-local.
// ---------------------------------------------------------------------------
__global__ __launch_bounds__(256) void binscat_kernel(
    const int* __restrict__ src, const int* __restrict__ dst,
    int* __restrict__ bincurs8, int* __restrict__ srcbincurs8,
    int* __restrict__ pairs, unsigned char* __restrict__ sbytes)
{
    int e = blockIdx.x * 256 + threadIdx.x;
    if (e >= N_EDGES) return;
    int copy = blockIdx.x & (NCOPY - 1);
    int s = src[e], d = dst[e];
    int pd = atomicAdd(bincurs8 + copy * NBIN + (d >> BINW_SHIFT), 1);
    int ps = atomicAdd(srcbincurs8 + copy * NBIN + (s >> BINW_SHIFT), 1);
    pairs[pd] = (s << BINW_SHIFT) | (d & (BINW - 1));
    sbytes[ps] = (unsigned char)(s & (BINW - 1));
}

// ---------------------------------------------------------------------------
// Src side finisher: per-bin LDS histogram of sloc bytes -> ns directly.
// No global atomics.
// ---------------------------------------------------------------------------
__global__ __launch_bounds__(256) void srccount_kernel(
    const unsigned char* __restrict__ sbytes, const int* __restrict__ srcbinOfs,
    float* __restrict__ ns)
{
    __shared__ int h[BINW];
    if (threadIdx.x < BINW) h[threadIdx.x] = 0;
    __syncthreads();
    int beg = srcbinOfs[blockIdx.x], end = srcbinOfs[blockIdx.x + 1];
    for (int i = beg + (int)threadIdx.x; i < end; i += 256)
        atomicAdd(&h[sbytes[i] & (BINW - 1)], 1);
    __syncthreads();
    int node = (blockIdx.x << BINW_SHIFT) + threadIdx.x;
    if (threadIdx.x < BINW && node < N_NODES)
        ns[node] = rsqrtf((float)max(h[threadIdx.x], 1));
}

// ---------------------------------------------------------------------------
// Dst side finisher: per-bin LDS histogram -> intra-bin prefix (wave-0
// shuffle scan) -> nodeOfs + nd, then CSR scatter via LDS cursors into the
// bin's contiguous L2-hot window. No global atomics.
// ---------------------------------------------------------------------------
__global__ __launch_bounds__(256) void csrbuild_kernel(
    const int* __restrict__ pairs, const int* __restrict__ binOfs,
    float* __restrict__ nd, int* __restrict__ nodeOfs, int* __restrict__ csr)
{
    __shared__ int h[BINW];
    __shared__ int curs[BINW];
    if (threadIdx.x < BINW) h[threadIdx.x] = 0;
    __syncthreads();
    int beg = binOfs[blockIdx.x], end = binOfs[blockIdx.x + 1];
    for (int i = beg + (int)threadIdx.x; i < end; i += 256)
        atomicAdd(&h[pairs[i] & (BINW - 1)], 1);
    __syncthreads();
    if (threadIdx.x < 64) {
        int lane = threadIdx.x;
        int v0 = h[lane], v1 = h[lane + 64];
        int s0 = v0, s1 = v1;
#pragma unroll
        for (int off = 1; off < 64; off <<= 1) {
            int u0 = __shfl_up(s0, off); if (lane >= off) s0 += u0;
            int u1 = __shfl_up(s1, off); if (lane >= off) s1 += u1;
        }
        int t0 = __shfl(s0, 63);
        curs[lane]      = beg + (s0 - v0);
        curs[lane + 64] = beg + (s1 - v1) + t0;
    }
    __syncthreads();
    int node = (blockIdx.x << BINW_SHIFT) + threadIdx.x;
    if (threadIdx.x < BINW && node < N_NODES) {
        nodeOfs[node] = curs[threadIdx.x];
        nd[node] = rsqrtf((float)max(h[threadIdx.x], 1));
        if (node == N_NODES - 1) nodeOfs[N_NODES] = end;
    }
    __syncthreads();
    for (int i = beg + (int)threadIdx.x; i < end; i += 256) {
        int p = pairs[i];
        int pos = atomicAdd(&curs[p & (BINW - 1)], 1);
        csr[pos] = p >> BINW_SHIFT;
    }
}

// ---------------------------------------------------------------------------
// xb[i] = bf16(ns[row] * x[i]) — pre-scaled bf16 copy of x for the gather.
// ---------------------------------------------------------------------------
__global__ __launch_bounds__(256) void xconv_kernel(
    const float* __restrict__ x, const float* __restrict__ ns,
    unsigned* __restrict__ xb)   // as uint (2 bf16 each)
{
    int idx = blockIdx.x * 256 + threadIdx.x;    // 8 elements per thread
    if (idx >= N_NODES * HF / 8) return;
    int row = idx >> 4;
    float c = ns[row];
    const float4* px = (const float4*)(x + (size_t)idx * 8);
    float4 v0 = px[0], v1 = px[1];
    uint4 o;
    o.x = pack2(c * v0.x, c * v0.y);
    o.y = pack2(c * v0.z, c * v0.w);
    o.z = pack2(c * v1.x, c * v1.y);
    o.w = pack2(c * v1.z, c * v1.w);
    *(uint4*)(xb + (size_t)idx * 4) = o;
}

// ---------------------------------------------------------------------------
// Aggregation: one wave per node, bf16 rows (256B). Lane-halves own even/odd
// edges; f32 accumulate; shfl_xor(.,32) combine; lanes 0-31 write f32 agg.
// Source rows pre-scaled by ns; nd applied here.
// ---------------------------------------------------------------------------
__global__ __launch_bounds__(256) void agg_kernel(
    const unsigned short* __restrict__ hb, const int* __restrict__ csr,
    const int* __restrict__ nodeOfs, const float* __restrict__ nd,
    float* __restrict__ agg)
{
    int node = blockIdx.x * 4 + (threadIdx.x >> 6);
    if (node >= N_NODES) return;
    int lane = threadIdx.x & 63;
    int half = lane >> 5;
    int flo = (lane & 31) * 4;                 // 4 features per lane
    int beg = nodeOfs[node], end = nodeOfs[node + 1];

    float a0 = 0.f, a1 = 0.f, a2 = 0.f, a3 = 0.f;
    for (int base = beg; base < end; base += 64) {
        int m = min(64, end - base);
        int sl = (lane < m) ? csr[base + lane] : 0;
        int k = 0;
        for (; k + 1 < m; k += 2) {
            int s0 = __builtin_amdgcn_readlane(sl, k);
            int s1 = __builtin_amdgcn_readlane(sl, k + 1);
            int sr = half ? s1 : s0;
            ushort4 v = *(const ushort4*)(hb + (size_t)sr * HF + flo);
            a0 += b2f(v.x); a1 += b2f(v.y); a2 += b2f(v.z); a3 += b2f(v.w);
        }
        if (k < m && half == 0) {
            int s0 = __builtin_amdgcn_readlane(sl, k);
            ushort4 v = *(const ushort4*)(hb + (size_t)s0 * HF + flo);
            a0 += b2f(v.x); a1 += b2f(v.y); a2 += b2f(v.z); a3 += b2f(v.w);
        }
    }
    a0 += __shfl_xor(a0, 32); a1 += __shfl_xor(a1, 32);
    a2 += __shfl_xor(a2, 32); a3 += __shfl_xor(a3, 32);
    if (half == 0) {
        float mm = nd[node];
        *(float4*)(agg + (size_t)node * HF + flo) =
            make_float4(a0 * mm, a1 * mm, a2 * mm, a3 * mm);
    }
}

// ---------------------------------------------------------------------------
// Fused GEMM: t = A @ W + bias [+ RES*ori], then
//   MODE 0: t(f32) -> out2 (=ori=d_out); bf16(ns*relu(LN(t))) -> hb
//   MODE 1: bf16(ns*relu(LN(t))) -> hb
//   MODE 2: t(f32) -> out2 (final output)
// ---------------------------------------------------------------------------
template <int MODE>
__global__ __launch_bounds__(GEMM_THREADS) void gemm_fused(
    const float* __restrict__ A, const float* __restrict__ Wp,
    const float* __restrict__ bias, const float* __restrict__ lng,
    const float* __restrict__ lnb, const float* __restrict__ ori,
    const float* __restrict__ ns, unsigned short* __restrict__ hb,
    float* __restrict__ out2)
{
    __shared__ float sW[HF * HF];   // 64 KiB
    const int tid = threadIdx.x;
    const int row0 = blockIdx.x * MT;

    const float4* W4 = (const float4*)Wp;
    float4* sW4 = (float4*)sW;
#pragma unroll
    for (int i = 0; i < (HF * HF / 4) / GEMM_THREADS; ++i)
        sW4[tid + i * GEMM_THREADS] = W4[tid + i * GEMM_THREADS];
    __syncthreads();

    const int cg = tid & 31;        // col group: cols cg*4 .. cg*4+3
    const int rg = tid >> 5;        // row group: rows rbase .. rbase+RPT-1
    const int rbase = row0 + rg * RPT;

    const float* Ar[RPT];
#pragma unroll
    for (int r = 0; r < RPT; ++r) {
        int row = min(rbase + r, N_NODES - 1);
        Ar[r] = A + (size_t)row * HF;
    }

    float acc[RPT][4] = {};
    for (int k = 0; k < HF; k += 4) {
        float a[RPT][4];
#pragma unroll
        for (int r = 0; r < RPT; ++r) {
            float4 t = *(const float4*)(Ar[r] + k);
            a[r][0] = t.x; a[r][1] = t.y; a[r][2] = t.z; a[r][3] = t.w;
        }
#pragma unroll
        for (int j = 0; j < 4; ++j) {
            float4 w = *(const float4*)(sW + (k + j) * HF + cg * 4);
#pragma unroll
            for (int r = 0; r < RPT; ++r) {
                acc[r][0] = fmaf(a[r][j], w.x, acc[r][0]);
                acc[r][1] = fmaf(a[r][j], w.y, acc[r][1]);
                acc[r][2] = fmaf(a[r][j], w.z, acc[r][2]);
                acc[r][3] = fmaf(a[r][j], w.w, acc[r][3]);
            }
        }
    }

    const float4 bia = *(const float4*)(bias + cg * 4);
    float4 gg, bb;
    if constexpr (MODE != 2) {
        gg = *(const float4*)(lng + cg * 4);
        bb = *(const float4*)(lnb + cg * 4);
    }

#pragma unroll
    for (int r = 0; r < RPT; ++r) {
        const int row = rbase + r;
        const bool ok = row < N_NODES;
        const int rowc = ok ? row : N_NODES - 1;
        const size_t off = (size_t)rowc * HF + cg * 4;
        float t0 = acc[r][0] + bia.x, t1 = acc[r][1] + bia.y;
        float t2 = acc[r][2] + bia.z, t3 = acc[r][3] + bia.w;
        if constexpr (MODE != 0) {
            float4 o = *(const float4*)(ori + off);
            t0 = fmaf(RESC, o.x, t0); t1 = fmaf(RESC, o.y, t1);
            t2 = fmaf(RESC, o.z, t2); t3 = fmaf(RESC, o.w, t3);
        }
        if constexpr (MODE == 2) {
            if (ok) *(float4*)(out2 + off) = make_float4(t0, t1, t2, t3);
        } else {
            if constexpr (MODE == 0)
                if (ok) *(float4*)(out2 + off) = make_float4(t0, t1, t2, t3);
            float s  = t0 + t1 + t2 + t3;
            float ss = t0 * t0 + t1 * t1 + t2 * t2 + t3 * t3;
#pragma unroll
            for (int m = 16; m >= 1; m >>= 1) {
                s  += __shfl_xor(s, m);
                ss += __shfl_xor(ss, m);
            }
            float mu   = s * (1.0f / HF);
            float var  = ss * (1.0f / HF) - mu * mu;
            float rinv = rsqrtf(var + LN_EPS);
            float nsr  = ns[rowc];   // pre-scale for next layer's aggregation
            float y0 = nsr * fmaxf(0.f, (t0 - mu) * rinv * gg.x + bb.x);
            float y1 = nsr * fmaxf(0.f, (t1 - mu) * rinv * gg.y + bb.y);
            float y2 = nsr * fmaxf(0.f, (t2 - mu) * rinv * gg.z + bb.z);
            float y3 = nsr * fmaxf(0.f, (t3 - mu) * rinv * gg.w + bb.w);
            if (ok) {
                uint2 w2;
                w2.x = pack2(y0, y1);
                w2.y = pack2(y2, y3);
                *(uint2*)(hb + off) = w2;
            }
        }
    }
}

// ---------------------------------------------------------------------------
extern "C" void kernel_launch(void* const* d_in, const int* in_sizes, int n_in,
                              void* d_out, int out_size, void* d_ws, size_t ws_size,
                              hipStream_t stream)
{
    const float* x   = (const float*)d_in[0];
    const float* W0  = (const float*)d_in[1];
    const float* Ws  = (const float*)d_in[2];
    const float* b   = (const float*)d_in[3];
    const float* lng = (const float*)d_in[4];
    const float* lnb = (const float*)d_in[5];
    const int*   src = (const int*)d_in[6];
    const int*   dst = (const int*)d_in[7];
    float* out = (float*)d_out;

    // workspace layout, total ~118.1 MB
    char* ws = (char*)d_ws;
    int*   bincnt8     = (int*)(ws + 0);          // 8*782 ints (pad 25600)
    int*   srcbincnt8  = (int*)(ws + 25600);      // 8*782 ints
    int*   bincurs8    = (int*)(ws + 51200);      // 8*782 ints
    int*   srcbincurs8 = (int*)(ws + 76800);      // 8*782 ints
    int*   binOfs      = (int*)(ws + 102400);     // 783 ints (pad 3584)
    int*   srcbinOfs   = (int*)(ws + 105984);     // 783 ints
    float* ns          = (float*)(ws + 109568);   // N f32 (pad 400384)
    float* nd          = (float*)(ws + 509952);   // N f32
    int*   nodeOfs     = (int*)(ws + 910336);     // N+1 ints
    int*   pairs       = (int*)(ws + 1310720);    // E ints = 6.4 MB
    unsigned char* sbytes = (unsigned char*)(ws + 7710720);  // E bytes = 1.6 MB
    int*   csr         = (int*)(ws + 9310720);    // E ints = 6.4 MB
    unsigned*       xb = (unsigned*)(ws + 15710720);        // N*128 bf16 = 25.6 MB
    unsigned short* hb = (unsigned short*)(ws + 41310720);  // N*128 bf16 = 25.6 MB
    float* agg         = (float*)(ws + 66910720); // N*128 f32 = 51.2 MB

    // zero bin histograms (contiguous 50 KB)
    hipMemsetAsync(bincnt8, 0, 51200, stream);

    hist_kernel<<<NHBLK, 256, 0, stream>>>(src, dst, bincnt8, srcbincnt8);
    binscan_kernel<<<1, 1024, 0, stream>>>(bincnt8, srcbincnt8,
                                           binOfs, srcbinOfs, bincurs8, srcbincurs8);
    binscat_kernel<<<(N_EDGES + 255) / 256, 256, 0, stream>>>(
        src, dst, bincurs8, srcbincurs8, pairs, sbytes);
    srccount_kernel<<<NBIN, 256, 0, stream>>>(sbytes, srcbinOfs, ns);
    csrbuild_kernel<<<NBIN, 256, 0, stream>>>(pairs, binOfs, nd, nodeOfs, csr);
    xconv_kernel<<<(N_NODES * HF / 8 + 255) / 256, 256, 0, stream>>>(x, ns, xb);

    const int gemm_grid = (N_NODES + MT - 1) / MT;   // 782

    // layer 0
    agg_kernel<<<(N_NODES + 3) / 4, 256, 0, stream>>>(
        (const unsigned short*)xb, csr, nodeOfs, nd, agg);
    gemm_fused<0><<<gemm_grid, GEMM_THREADS, 0, stream>>>(
        agg, W0, b, lng + HF, lnb + HF, nullptr, ns, hb, out);

    // layer 1
    agg_kernel<<<(N_NODES + 3) / 4, 256, 0, stream>>>(hb, csr, nodeOfs, nd, agg);
    gemm_fused<1><<<gemm_grid, GEMM_THREADS, 0, stream>>>(
        agg, Ws, b + HF, lng + 2 * HF, lnb + 2 * HF, out, ns, hb, nullptr);

    // layer 2
    agg_kernel<<<(N_NODES + 3) / 4, 256, 0, stream>>>(hb, csr, nodeOfs, nd, agg);
    gemm_fused<2><<<gemm_grid, GEMM_THREADS, 0, stream>>>(
        agg, Ws + HF * HF, b + 2 * HF, nullptr, nullptr, out, ns, nullptr, out);
}

// Round 7
// 555.411 us; speedup vs baseline: 2.1117x; 1.3203x over previous
//
#include <hip/hip_runtime.h>

// Problem constants (fixed by the reference)
#define N_NODES 100000
#define N_EDGES 1600000
#define HF      128
#define RESC    0.5f
#define LN_EPS  1e-5f

#define BINW_SHIFT 7
#define BINW       128
#define NBIN       ((N_NODES + BINW - 1) >> BINW_SHIFT)   // 782
#define HCHUNK     16384
#define NCHUNK     ((N_EDGES + HCHUNK - 1) / HCHUNK)      // 98

#define GEMM_THREADS 512
#define MT  128             // rows per GEMM block
#define RPT 8               // rows per thread

// bf16 helpers (round-to-nearest-even)
static __device__ __forceinline__ unsigned f2b(float f) {
    unsigned u = __float_as_uint(f);
    return (u + 0x7FFFu + ((u >> 16) & 1u)) >> 16;
}
static __device__ __forceinline__ unsigned pack2(float a, float b) {
    return f2b(a) | (f2b(b) << 16);
}
static __device__ __forceinline__ float b2f(unsigned short u) {
    return __uint_as_float(((unsigned)u) << 16);
}

// ---------------------------------------------------------------------------
// Counting-sort pass 1: per-chunk LDS bin histograms (dst & src). The LDS
// atomic's RETURN VALUE is the edge's intra-chunk intra-bin rank -> stored.
// Zero global atomics; hist flush is a dense write to [bin][chunk].
// ---------------------------------------------------------------------------
__global__ __launch_bounds__(1024) void histrank_kernel(
    const int* __restrict__ src, const int* __restrict__ dst,
    int* __restrict__ histD, int* __restrict__ histS,
    unsigned short* __restrict__ dstrank, unsigned short* __restrict__ srcrank)
{
    __shared__ int hd[NBIN], hs[NBIN];
    for (int i = threadIdx.x; i < NBIN; i += 1024) { hd[i] = 0; hs[i] = 0; }
    __syncthreads();
    int base = blockIdx.x * HCHUNK;
    int lim = min(base + HCHUNK, N_EDGES);
    for (int e = base + (int)threadIdx.x; e < lim; e += 1024) {
        int d = dst[e], s = src[e];
        int rd = atomicAdd(&hd[d >> BINW_SHIFT], 1);
        int rs = atomicAdd(&hs[s >> BINW_SHIFT], 1);
        dstrank[e] = (unsigned short)rd;   // < HCHUNK <= 16384, fits ushort
        srcrank[e] = (unsigned short)rs;
    }
    __syncthreads();
    for (int i = threadIdx.x; i < NBIN; i += 1024) {
        histD[i * NCHUNK + blockIdx.x] = hd[i];
        histS[i * NCHUNK + blockIdx.x] = hs[i];
    }
}

// ---------------------------------------------------------------------------
// Pass 2a: exclusive scan WITHIN each bin across its 98 chunk counts
// (in-place), emitting the bin total. One wave per row; rows = 2*NBIN.
// ---------------------------------------------------------------------------
__global__ __launch_bounds__(256) void scanA_kernel(
    int* __restrict__ histD, int* __restrict__ histS,
    int* __restrict__ rowTotD, int* __restrict__ rowTotS)
{
    int row = blockIdx.x * 4 + ((int)threadIdx.x >> 6);
    int lane = threadIdx.x & 63;
    if (row >= 2 * NBIN) return;
    int* h = (row < NBIN) ? (histD + row * NCHUNK) : (histS + (row - NBIN) * NCHUNK);
    int v0 = h[lane];                                  // NCHUNK=98 > 64: always valid
    int v1 = (64 + lane < NCHUNK) ? h[64 + lane] : 0;
    int s0 = v0, s1 = v1;
#pragma unroll
    for (int off = 1; off < 64; off <<= 1) {
        int u0 = __shfl_up(s0, off); if (lane >= off) s0 += u0;
        int u1 = __shfl_up(s1, off); if (lane >= off) s1 += u1;
    }
    int c = __shfl(s0, 63);        // total of first 64 chunks
    h[lane] = s0 - v0;             // exclusive
    if (64 + lane < NCHUNK) h[64 + lane] = c + s1 - v1;
    int tot = c + __shfl(s1, 63);  // v1 zero-padded -> full total
    if (lane == 0) {
        if (row < NBIN) rowTotD[row] = tot;
        else            rowTotS[row - NBIN] = tot;
    }
}

// ---------------------------------------------------------------------------
// Pass 2b: single-block exclusive scan over the 782 bin totals (both sides)
// -> rowBase[bin] and binOfs/srcbinOfs.
// ---------------------------------------------------------------------------
__global__ __launch_bounds__(1024) void scanB_kernel(
    const int* __restrict__ rowTotD, const int* __restrict__ rowTotS,
    int* __restrict__ rowBaseD, int* __restrict__ rowBaseS,
    int* __restrict__ binOfs, int* __restrict__ srcbinOfs)
{
    __shared__ int wsum[16];
    for (int side = 0; side < 2; ++side) {
        const int* cnt = side ? rowTotS : rowTotD;
        int* base = side ? rowBaseS : rowBaseD;
        int* ofs  = side ? srcbinOfs : binOfs;
        int b = threadIdx.x;
        int tot = (b < NBIN) ? cnt[b] : 0;
        int lane = threadIdx.x & 63, wid = threadIdx.x >> 6;
        int x = tot;
#pragma unroll
        for (int off = 1; off < 64; off <<= 1) { int u = __shfl_up(x, off); if (lane >= off) x += u; }
        if (lane == 63) wsum[wid] = x;
        __syncthreads();
        if (wid == 0) {
            int y = (lane < 16) ? wsum[lane] : 0;
#pragma unroll
            for (int off = 1; off < 16; off <<= 1) { int u = __shfl_up(y, off); if (lane >= off) y += u; }
            if (lane < 16) wsum[lane] = y;
        }
        __syncthreads();
        int incl = x + (wid > 0 ? wsum[wid - 1] : 0);
        if (b < NBIN) {
            base[b] = incl - tot;
            ofs[b + 1] = incl;
            if (b == 0) ofs[0] = 0;
        }
        __syncthreads();   // wsum reused next side
    }
}

// ---------------------------------------------------------------------------
// Counting-sort pass 3: deterministic scatter, pos = rowBase[bin] +
// scannedHist[bin][chunk] + rank[e]. No atomics anywhere; per-(bin,chunk)
// runs (~21 edges) keep writes line-clustered.
// ---------------------------------------------------------------------------
__global__ __launch_bounds__(1024) void scatter_kernel(
    const int* __restrict__ src, const int* __restrict__ dst,
    const unsigned short* __restrict__ dstrank, const unsigned short* __restrict__ srcrank,
    const int* __restrict__ histD, const int* __restrict__ histS,
    const int* __restrict__ rowBaseD, const int* __restrict__ rowBaseS,
    int* __restrict__ pairs, unsigned char* __restrict__ sbytes)
{
    __shared__ int baseD[NBIN], baseS[NBIN];
    for (int i = threadIdx.x; i < NBIN; i += 1024) {
        baseD[i] = rowBaseD[i] + histD[i * NCHUNK + blockIdx.x];
        baseS[i] = rowBaseS[i] + histS[i * NCHUNK + blockIdx.x];
    }
    __syncthreads();
    int base = blockIdx.x * HCHUNK;
    int lim = min(base + HCHUNK, N_EDGES);
    for (int e = base + (int)threadIdx.x; e < lim; e += 1024) {
        int d = dst[e], s = src[e];
        pairs[baseD[d >> BINW_SHIFT] + dstrank[e]] = (s << BINW_SHIFT) | (d & (BINW - 1));
        sbytes[baseS[s >> BINW_SHIFT] + srcrank[e]] = (unsigned char)(s & (BINW - 1));
    }
}

// ---------------------------------------------------------------------------
// Src side finisher: per-bin LDS histogram of sloc bytes -> ns directly.
// ---------------------------------------------------------------------------
__global__ __launch_bounds__(256) void srccount_kernel(
    const unsigned char* __restrict__ sbytes, const int* __restrict__ srcbinOfs,
    float* __restrict__ ns)
{
    __shared__ int h[BINW];
    if (threadIdx.x < BINW) h[threadIdx.x] = 0;
    __syncthreads();
    int beg = srcbinOfs[blockIdx.x], end = srcbinOfs[blockIdx.x + 1];
    for (int i = beg + (int)threadIdx.x; i < end; i += 256)
        atomicAdd(&h[sbytes[i] & (BINW - 1)], 1);
    __syncthreads();
    int node = (blockIdx.x << BINW_SHIFT) + threadIdx.x;
    if (threadIdx.x < BINW && node < N_NODES)
        ns[node] = rsqrtf((float)max(h[threadIdx.x], 1));
}

// ---------------------------------------------------------------------------
// Dst side finisher: per-bin LDS histogram -> intra-bin prefix -> nodeOfs +
// nd, then CSR scatter via LDS cursors into the bin's L2-hot window.
// ---------------------------------------------------------------------------
__global__ __launch_bounds__(256) void csrbuild_kernel(
    const int* __restrict__ pairs, const int* __restrict__ binOfs,
    float* __restrict__ nd, int* __restrict__ nodeOfs, int* __restrict__ csr)
{
    __shared__ int h[BINW];
    __shared__ int curs[BINW];
    if (threadIdx.x < BINW) h[threadIdx.x] = 0;
    __syncthreads();
    int beg = binOfs[blockIdx.x], end = binOfs[blockIdx.x + 1];
    for (int i = beg + (int)threadIdx.x; i < end; i += 256)
        atomicAdd(&h[pairs[i] & (BINW - 1)], 1);
    __syncthreads();
    if (threadIdx.x < 64) {
        int lane = threadIdx.x;
        int v0 = h[lane], v1 = h[lane + 64];
        int s0 = v0, s1 = v1;
#pragma unroll
        for (int off = 1; off < 64; off <<= 1) {
            int u0 = __shfl_up(s0, off); if (lane >= off) s0 += u0;
            int u1 = __shfl_up(s1, off); if (lane >= off) s1 += u1;
        }
        int t0 = __shfl(s0, 63);
        curs[lane]      = beg + (s0 - v0);
        curs[lane + 64] = beg + (s1 - v1) + t0;
    }
    __syncthreads();
    int node = (blockIdx.x << BINW_SHIFT) + threadIdx.x;
    if (threadIdx.x < BINW && node < N_NODES) {
        nodeOfs[node] = curs[threadIdx.x];
        nd[node] = rsqrtf((float)max(h[threadIdx.x], 1));
        if (node == N_NODES - 1) nodeOfs[N_NODES] = end;
    }
    __syncthreads();
    for (int i = beg + (int)threadIdx.x; i < end; i += 256) {
        int p = pairs[i];
        int pos = atomicAdd(&curs[p & (BINW - 1)], 1);
        csr[pos] = p >> BINW_SHIFT;
    }
}

// ---------------------------------------------------------------------------
// xb[i] = bf16(ns[row] * x[i]) — pre-scaled bf16 copy of x for the gather.
// ---------------------------------------------------------------------------
__global__ __launch_bounds__(256) void xconv_kernel(
    const float* __restrict__ x, const float* __restrict__ ns,
    unsigned* __restrict__ xb)   // as uint (2 bf16 each)
{
    int idx = blockIdx.x * 256 + threadIdx.x;    // 8 elements per thread
    if (idx >= N_NODES * HF / 8) return;
    int row = idx >> 4;
    float c = ns[row];
    const float4* px = (const float4*)(x + (size_t)idx * 8);
    float4 v0 = px[0], v1 = px[1];
    uint4 o;
    o.x = pack2(c * v0.x, c * v0.y);
    o.y = pack2(c * v0.z, c * v0.w);
    o.z = pack2(c * v1.x, c * v1.y);
    o.w = pack2(c * v1.z, c * v1.w);
    *(uint4*)(xb + (size_t)idx * 4) = o;
}

// ---------------------------------------------------------------------------
// Aggregation: one wave per node, bf16 rows (256B). Lane-halves own even/odd
// edges; f32 accumulate; shfl_xor(.,32) combine; lanes 0-31 write f32 agg.
// Source rows pre-scaled by ns; nd applied here.
// ---------------------------------------------------------------------------
__global__ __launch_bounds__(256) void agg_kernel(
    const unsigned short* __restrict__ hb, const int* __restrict__ csr,
    const int* __restrict__ nodeOfs, const float* __restrict__ nd,
    float* __restrict__ agg)
{
    int node = blockIdx.x * 4 + (threadIdx.x >> 6);
    if (node >= N_NODES) return;
    int lane = threadIdx.x & 63;
    int half = lane >> 5;
    int flo = (lane & 31) * 4;                 // 4 features per lane
    int beg = nodeOfs[node], end = nodeOfs[node + 1];

    float a0 = 0.f, a1 = 0.f, a2 = 0.f, a3 = 0.f;
    for (int base = beg; base < end; base += 64) {
        int m = min(64, end - base);
        int sl = (lane < m) ? csr[base + lane] : 0;
        int k = 0;
        for (; k + 1 < m; k += 2) {
            int s0 = __builtin_amdgcn_readlane(sl, k);
            int s1 = __builtin_amdgcn_readlane(sl, k + 1);
            int sr = half ? s1 : s0;
            ushort4 v = *(const ushort4*)(hb + (size_t)sr * HF + flo);
            a0 += b2f(v.x); a1 += b2f(v.y); a2 += b2f(v.z); a3 += b2f(v.w);
        }
        if (k < m && half == 0) {
            int s0 = __builtin_amdgcn_readlane(sl, k);
            ushort4 v = *(const ushort4*)(hb + (size_t)s0 * HF + flo);
            a0 += b2f(v.x); a1 += b2f(v.y); a2 += b2f(v.z); a3 += b2f(v.w);
        }
    }
    a0 += __shfl_xor(a0, 32); a1 += __shfl_xor(a1, 32);
    a2 += __shfl_xor(a2, 32); a3 += __shfl_xor(a3, 32);
    if (half == 0) {
        float mm = nd[node];
        *(float4*)(agg + (size_t)node * HF + flo) =
            make_float4(a0 * mm, a1 * mm, a2 * mm, a3 * mm);
    }
}

// ---------------------------------------------------------------------------
// Fused GEMM: t = A @ W + bias [+ RES*ori], then
//   MODE 0: t(f32) -> out2 (=ori=d_out); bf16(ns*relu(LN(t))) -> hb
//   MODE 1: bf16(ns*relu(LN(t))) -> hb
//   MODE 2: t(f32) -> out2 (final output)
// ---------------------------------------------------------------------------
template <int MODE>
__global__ __launch_bounds__(GEMM_THREADS) void gemm_fused(
    const float* __restrict__ A, const float* __restrict__ Wp,
    const float* __restrict__ bias, const float* __restrict__ lng,
    const float* __restrict__ lnb, const float* __restrict__ ori,
    const float* __restrict__ ns, unsigned short* __restrict__ hb,
    float* __restrict__ out2)
{
    __shared__ float sW[HF * HF];   // 64 KiB
    const int tid = threadIdx.x;
    const int row0 = blockIdx.x * MT;

    const float4* W4 = (const float4*)Wp;
    float4* sW4 = (float4*)sW;
#pragma unroll
    for (int i = 0; i < (HF * HF / 4) / GEMM_THREADS; ++i)
        sW4[tid + i * GEMM_THREADS] = W4[tid + i * GEMM_THREADS];
    __syncthreads();

    const int cg = tid & 31;        // col group: cols cg*4 .. cg*4+3
    const int rg = tid >> 5;        // row group: rows rbase .. rbase+RPT-1
    const int rbase = row0 + rg * RPT;

    const float* Ar[RPT];
#pragma unroll
    for (int r = 0; r < RPT; ++r) {
        int row = min(rbase + r, N_NODES - 1);
        Ar[r] = A + (size_t)row * HF;
    }

    float acc[RPT][4] = {};
    for (int k = 0; k < HF; k += 4) {
        float a[RPT][4];
#pragma unroll
        for (int r = 0; r < RPT; ++r) {
            float4 t = *(const float4*)(Ar[r] + k);
            a[r][0] = t.x; a[r][1] = t.y; a[r][2] = t.z; a[r][3] = t.w;
        }
#pragma unroll
        for (int j = 0; j < 4; ++j) {
            float4 w = *(const float4*)(sW + (k + j) * HF + cg * 4);
#pragma unroll
            for (int r = 0; r < RPT; ++r) {
                acc[r][0] = fmaf(a[r][j], w.x, acc[r][0]);
                acc[r][1] = fmaf(a[r][j], w.y, acc[r][1]);
                acc[r][2] = fmaf(a[r][j], w.z, acc[r][2]);
                acc[r][3] = fmaf(a[r][j], w.w, acc[r][3]);
            }
        }
    }

    const float4 bia = *(const float4*)(bias + cg * 4);
    float4 gg, bb;
    if constexpr (MODE != 2) {
        gg = *(const float4*)(lng + cg * 4);
        bb = *(const float4*)(lnb + cg * 4);
    }

#pragma unroll
    for (int r = 0; r < RPT; ++r) {
        const int row = rbase + r;
        const bool ok = row < N_NODES;
        const int rowc = ok ? row : N_NODES - 1;
        const size_t off = (size_t)rowc * HF + cg * 4;
        float t0 = acc[r][0] + bia.x, t1 = acc[r][1] + bia.y;
        float t2 = acc[r][2] + bia.z, t3 = acc[r][3] + bia.w;
        if constexpr (MODE != 0) {
            float4 o = *(const float4*)(ori + off);
            t0 = fmaf(RESC, o.x, t0); t1 = fmaf(RESC, o.y, t1);
            t2 = fmaf(RESC, o.z, t2); t3 = fmaf(RESC, o.w, t3);
        }
        if constexpr (MODE == 2) {
            if (ok) *(float4*)(out2 + off) = make_float4(t0, t1, t2, t3);
        } else {
            if constexpr (MODE == 0)
                if (ok) *(float4*)(out2 + off) = make_float4(t0, t1, t2, t3);
            float s  = t0 + t1 + t2 + t3;
            float ss = t0 * t0 + t1 * t1 + t2 * t2 + t3 * t3;
#pragma unroll
            for (int m = 16; m >= 1; m >>= 1) {
                s  += __shfl_xor(s, m);
                ss += __shfl_xor(ss, m);
            }
            float mu   = s * (1.0f / HF);
            float var  = ss * (1.0f / HF) - mu * mu;
            float rinv = rsqrtf(var + LN_EPS);
            float nsr  = ns[rowc];   // pre-scale for next layer's aggregation
            float y0 = nsr * fmaxf(0.f, (t0 - mu) * rinv * gg.x + bb.x);
            float y1 = nsr * fmaxf(0.f, (t1 - mu) * rinv * gg.y + bb.y);
            float y2 = nsr * fmaxf(0.f, (t2 - mu) * rinv * gg.z + bb.z);
            float y3 = nsr * fmaxf(0.f, (t3 - mu) * rinv * gg.w + bb.w);
            if (ok) {
                uint2 w2;
                w2.x = pack2(y0, y1);
                w2.y = pack2(y2, y3);
                *(uint2*)(hb + off) = w2;
            }
        }
    }
}

// ---------------------------------------------------------------------------
extern "C" void kernel_launch(void* const* d_in, const int* in_sizes, int n_in,
                              void* d_out, int out_size, void* d_ws, size_t ws_size,
                              hipStream_t stream)
{
    const float* x   = (const float*)d_in[0];
    const float* W0  = (const float*)d_in[1];
    const float* Ws  = (const float*)d_in[2];
    const float* b   = (const float*)d_in[3];
    const float* lng = (const float*)d_in[4];
    const float* lnb = (const float*)d_in[5];
    const int*   src = (const int*)d_in[6];
    const int*   dst = (const int*)d_in[7];
    float* out = (float*)d_out;

    // workspace layout, total ~125.0 MB; everything written before read,
    // no memset needed.
    char* ws = (char*)d_ws;
    int*   histD     = (int*)(ws + 0);            // NBIN*NCHUNK ints (306.5 KB)
    int*   histS     = (int*)(ws + 307200);       // NBIN*NCHUNK ints
    int*   rowTotD   = (int*)(ws + 614400);       // NBIN ints
    int*   rowTotS   = (int*)(ws + 617984);
    int*   rowBaseD  = (int*)(ws + 621568);
    int*   rowBaseS  = (int*)(ws + 625152);
    int*   binOfs    = (int*)(ws + 628736);       // NBIN+1 ints
    int*   srcbinOfs = (int*)(ws + 632320);
    float* ns        = (float*)(ws + 635904);     // N f32
    float* nd        = (float*)(ws + 1036288);    // N f32
    int*   nodeOfs   = (int*)(ws + 1436672);      // N+1 ints
    unsigned short* dstrank = (unsigned short*)(ws + 1837056);  // E ushort = 3.2 MB
    unsigned short* srcrank = (unsigned short*)(ws + 5037056);  // E ushort = 3.2 MB
    int*   pairs     = (int*)(ws + 8237056);      // E ints = 6.4 MB
    unsigned char* sbytes = (unsigned char*)(ws + 14637056);    // E bytes = 1.6 MB
    int*   csr       = (int*)(ws + 16237056);     // E ints = 6.4 MB
    unsigned*       xb = (unsigned*)(ws + 22637056);        // N*128 bf16 = 25.6 MB
    unsigned short* hb = (unsigned short*)(ws + 48237056);  // N*128 bf16 = 25.6 MB
    float* agg       = (float*)(ws + 73837056);   // N*128 f32 = 51.2 MB

    histrank_kernel<<<NCHUNK, 1024, 0, stream>>>(src, dst, histD, histS, dstrank, srcrank);
    scanA_kernel<<<(2 * NBIN + 3) / 4, 256, 0, stream>>>(histD, histS, rowTotD, rowTotS);
    scanB_kernel<<<1, 1024, 0, stream>>>(rowTotD, rowTotS, rowBaseD, rowBaseS, binOfs, srcbinOfs);
    scatter_kernel<<<NCHUNK, 1024, 0, stream>>>(src, dst, dstrank, srcrank,
                                                histD, histS, rowBaseD, rowBaseS,
                                                pairs, sbytes);
    srccount_kernel<<<NBIN, 256, 0, stream>>>(sbytes, srcbinOfs, ns);
    csrbuild_kernel<<<NBIN, 256, 0, stream>>>(pairs, binOfs, nd, nodeOfs, csr);
    xconv_kernel<<<(N_NODES * HF / 8 + 255) / 256, 256, 0, stream>>>(x, ns, xb);

    const int gemm_grid = (N_NODES + MT - 1) / MT;   // 782

    // layer 0
    agg_kernel<<<(N_NODES + 3) / 4, 256, 0, stream>>>(
        (const unsigned short*)xb, csr, nodeOfs, nd, agg);
    gemm_fused<0><<<gemm_grid, GEMM_THREADS, 0, stream>>>(
        agg, W0, b, lng + HF, lnb + HF, nullptr, ns, hb, out);

    // layer 1
    agg_kernel<<<(N_NODES + 3) / 4, 256, 0, stream>>>(hb, csr, nodeOfs, nd, agg);
    gemm_fused<1><<<gemm_grid, GEMM_THREADS, 0, stream>>>(
        agg, Ws, b + HF, lng + 2 * HF, lnb + 2 * HF, out, ns, hb, nullptr);

    // layer 2
    agg_kernel<<<(N_NODES + 3) / 4, 256, 0, stream>>>(hb, csr, nodeOfs, nd, agg);
    gemm_fused<2><<<gemm_grid, GEMM_THREADS, 0, stream>>>(
        agg, Ws + HF * HF, b + 2 * HF, nullptr, nullptr, out, ns, nullptr, out);
}

// Round 8
// 367.825 us; speedup vs baseline: 3.1887x; 1.5100x over previous
//
#include <hip/hip_runtime.h>

// Problem constants (fixed by the reference)
#define N_NODES 100000
#define N_EDGES 1600000
#define HF      128
#define RESC    0.5f
#define LN_EPS  1e-5f

#define BINW_SHIFT 7
#define BINW       128
#define NBIN       ((N_NODES + BINW - 1) >> BINW_SHIFT)   // 782
#define HCHUNK     16384
#define NCHUNK     ((N_EDGES + HCHUNK - 1) / HCHUNK)      // 98

#define GEMM_THREADS 512
#define MT  128             // rows per GEMM block

typedef __attribute__((ext_vector_type(8))) short bf16x8;  // MFMA A/B frag
typedef __attribute__((ext_vector_type(4))) float f32x4;   // MFMA C/D frag

// bf16 helpers (round-to-nearest-even)
static __device__ __forceinline__ unsigned f2b(float f) {
    unsigned u = __float_as_uint(f);
    return (u + 0x7FFFu + ((u >> 16) & 1u)) >> 16;
}
static __device__ __forceinline__ unsigned pack2(float a, float b) {
    return f2b(a) | (f2b(b) << 16);
}
static __device__ __forceinline__ float b2f(unsigned short u) {
    return __uint_as_float(((unsigned)u) << 16);
}

// ---------------------------------------------------------------------------
// Counting-sort pass 1: per-chunk LDS bin histograms (dst & src). The LDS
// atomic's RETURN VALUE is the edge's intra-chunk intra-bin rank -> stored.
// ---------------------------------------------------------------------------
__global__ __launch_bounds__(1024) void histrank_kernel(
    const int* __restrict__ src, const int* __restrict__ dst,
    int* __restrict__ histD, int* __restrict__ histS,
    unsigned short* __restrict__ dstrank, unsigned short* __restrict__ srcrank)
{
    __shared__ int hd[NBIN], hs[NBIN];
    for (int i = threadIdx.x; i < NBIN; i += 1024) { hd[i] = 0; hs[i] = 0; }
    __syncthreads();
    int base = blockIdx.x * HCHUNK;
    int lim = min(base + HCHUNK, N_EDGES);
    for (int e = base + (int)threadIdx.x; e < lim; e += 1024) {
        int d = dst[e], s = src[e];
        int rd = atomicAdd(&hd[d >> BINW_SHIFT], 1);
        int rs = atomicAdd(&hs[s >> BINW_SHIFT], 1);
        dstrank[e] = (unsigned short)rd;
        srcrank[e] = (unsigned short)rs;
    }
    __syncthreads();
    for (int i = threadIdx.x; i < NBIN; i += 1024) {
        histD[i * NCHUNK + blockIdx.x] = hd[i];
        histS[i * NCHUNK + blockIdx.x] = hs[i];
    }
}

// ---------------------------------------------------------------------------
// Pass 2a: exclusive scan WITHIN each bin across its 98 chunk counts.
// ---------------------------------------------------------------------------
__global__ __launch_bounds__(256) void scanA_kernel(
    int* __restrict__ histD, int* __restrict__ histS,
    int* __restrict__ rowTotD, int* __restrict__ rowTotS)
{
    int row = blockIdx.x * 4 + ((int)threadIdx.x >> 6);
    int lane = threadIdx.x & 63;
    if (row >= 2 * NBIN) return;
    int* h = (row < NBIN) ? (histD + row * NCHUNK) : (histS + (row - NBIN) * NCHUNK);
    int v0 = h[lane];
    int v1 = (64 + lane < NCHUNK) ? h[64 + lane] : 0;
    int s0 = v0, s1 = v1;
#pragma unroll
    for (int off = 1; off < 64; off <<= 1) {
        int u0 = __shfl_up(s0, off); if (lane >= off) s0 += u0;
        int u1 = __shfl_up(s1, off); if (lane >= off) s1 += u1;
    }
    int c = __shfl(s0, 63);
    h[lane] = s0 - v0;
    if (64 + lane < NCHUNK) h[64 + lane] = c + s1 - v1;
    int tot = c + __shfl(s1, 63);
    if (lane == 0) {
        if (row < NBIN) rowTotD[row] = tot;
        else            rowTotS[row - NBIN] = tot;
    }
}

// ---------------------------------------------------------------------------
// Pass 2b: single-block exclusive scan over the 782 bin totals (both sides).
// ---------------------------------------------------------------------------
__global__ __launch_bounds__(1024) void scanB_kernel(
    const int* __restrict__ rowTotD, const int* __restrict__ rowTotS,
    int* __restrict__ rowBaseD, int* __restrict__ rowBaseS,
    int* __restrict__ binOfs, int* __restrict__ srcbinOfs)
{
    __shared__ int wsum[16];
    for (int side = 0; side < 2; ++side) {
        const int* cnt = side ? rowTotS : rowTotD;
        int* base = side ? rowBaseS : rowBaseD;
        int* ofs  = side ? srcbinOfs : binOfs;
        int b = threadIdx.x;
        int tot = (b < NBIN) ? cnt[b] : 0;
        int lane = threadIdx.x & 63, wid = threadIdx.x >> 6;
        int x = tot;
#pragma unroll
        for (int off = 1; off < 64; off <<= 1) { int u = __shfl_up(x, off); if (lane >= off) x += u; }
        if (lane == 63) wsum[wid] = x;
        __syncthreads();
        if (wid == 0) {
            int y = (lane < 16) ? wsum[lane] : 0;
#pragma unroll
            for (int off = 1; off < 16; off <<= 1) { int u = __shfl_up(y, off); if (lane >= off) y += u; }
            if (lane < 16) wsum[lane] = y;
        }
        __syncthreads();
        int incl = x + (wid > 0 ? wsum[wid - 1] : 0);
        if (b < NBIN) {
            base[b] = incl - tot;
            ofs[b + 1] = incl;
            if (b == 0) ofs[0] = 0;
        }
        __syncthreads();
    }
}

// ---------------------------------------------------------------------------
// Counting-sort pass 3: deterministic scatter, no atomics.
// ---------------------------------------------------------------------------
__global__ __launch_bounds__(1024) void scatter_kernel(
    const int* __restrict__ src, const int* __restrict__ dst,
    const unsigned short* __restrict__ dstrank, const unsigned short* __restrict__ srcrank,
    const int* __restrict__ histD, const int* __restrict__ histS,
    const int* __restrict__ rowBaseD, const int* __restrict__ rowBaseS,
    int* __restrict__ pairs, unsigned char* __restrict__ sbytes)
{
    __shared__ int baseD[NBIN], baseS[NBIN];
    for (int i = threadIdx.x; i < NBIN; i += 1024) {
        baseD[i] = rowBaseD[i] + histD[i * NCHUNK + blockIdx.x];
        baseS[i] = rowBaseS[i] + histS[i * NCHUNK + blockIdx.x];
    }
    __syncthreads();
    int base = blockIdx.x * HCHUNK;
    int lim = min(base + HCHUNK, N_EDGES);
    for (int e = base + (int)threadIdx.x; e < lim; e += 1024) {
        int d = dst[e], s = src[e];
        pairs[baseD[d >> BINW_SHIFT] + dstrank[e]] = (s << BINW_SHIFT) | (d & (BINW - 1));
        sbytes[baseS[s >> BINW_SHIFT] + srcrank[e]] = (unsigned char)(s & (BINW - 1));
    }
}

// ---------------------------------------------------------------------------
// Src side finisher: per-bin LDS histogram of sloc bytes -> ns directly.
// ---------------------------------------------------------------------------
__global__ __launch_bounds__(256) void srccount_kernel(
    const unsigned char* __restrict__ sbytes, const int* __restrict__ srcbinOfs,
    float* __restrict__ ns)
{
    __shared__ int h[BINW];
    if (threadIdx.x < BINW) h[threadIdx.x] = 0;
    __syncthreads();
    int beg = srcbinOfs[blockIdx.x], end = srcbinOfs[blockIdx.x + 1];
    for (int i = beg + (int)threadIdx.x; i < end; i += 256)
        atomicAdd(&h[sbytes[i] & (BINW - 1)], 1);
    __syncthreads();
    int node = (blockIdx.x << BINW_SHIFT) + threadIdx.x;
    if (threadIdx.x < BINW && node < N_NODES)
        ns[node] = rsqrtf((float)max(h[threadIdx.x], 1));
}

// ---------------------------------------------------------------------------
// Dst side finisher: per-bin LDS histogram -> intra-bin prefix -> nodeOfs +
// nd, then CSR scatter via LDS cursors into the bin's L2-hot window.
// ---------------------------------------------------------------------------
__global__ __launch_bounds__(256) void csrbuild_kernel(
    const int* __restrict__ pairs, const int* __restrict__ binOfs,
    float* __restrict__ nd, int* __restrict__ nodeOfs, int* __restrict__ csr)
{
    __shared__ int h[BINW];
    __shared__ int curs[BINW];
    if (threadIdx.x < BINW) h[threadIdx.x] = 0;
    __syncthreads();
    int beg = binOfs[blockIdx.x], end = binOfs[blockIdx.x + 1];
    for (int i = beg + (int)threadIdx.x; i < end; i += 256)
        atomicAdd(&h[pairs[i] & (BINW - 1)], 1);
    __syncthreads();
    if (threadIdx.x < 64) {
        int lane = threadIdx.x;
        int v0 = h[lane], v1 = h[lane + 64];
        int s0 = v0, s1 = v1;
#pragma unroll
        for (int off = 1; off < 64; off <<= 1) {
            int u0 = __shfl_up(s0, off); if (lane >= off) s0 += u0;
            int u1 = __shfl_up(s1, off); if (lane >= off) s1 += u1;
        }
        int t0 = __shfl(s0, 63);
        curs[lane]      = beg + (s0 - v0);
        curs[lane + 64] = beg + (s1 - v1) + t0;
    }
    __syncthreads();
    int node = (blockIdx.x << BINW_SHIFT) + threadIdx.x;
    if (threadIdx.x < BINW && node < N_NODES) {
        nodeOfs[node] = curs[threadIdx.x];
        nd[node] = rsqrtf((float)max(h[threadIdx.x], 1));
        if (node == N_NODES - 1) nodeOfs[N_NODES] = end;
    }
    __syncthreads();
    for (int i = beg + (int)threadIdx.x; i < end; i += 256) {
        int p = pairs[i];
        int pos = atomicAdd(&curs[p & (BINW - 1)], 1);
        csr[pos] = p >> BINW_SHIFT;
    }
}

// ---------------------------------------------------------------------------
// xb[i] = bf16(ns[row] * x[i]) — pre-scaled bf16 copy of x for the gather.
// ---------------------------------------------------------------------------
__global__ __launch_bounds__(256) void xconv_kernel(
    const float* __restrict__ x, const float* __restrict__ ns,
    unsigned* __restrict__ xb)
{
    int idx = blockIdx.x * 256 + threadIdx.x;    // 8 elements per thread
    if (idx >= N_NODES * HF / 8) return;
    int row = idx >> 4;
    float c = ns[row];
    const float4* px = (const float4*)(x + (size_t)idx * 8);
    float4 v0 = px[0], v1 = px[1];
    uint4 o;
    o.x = pack2(c * v0.x, c * v0.y);
    o.y = pack2(c * v0.z, c * v0.w);
    o.z = pack2(c * v1.x, c * v1.y);
    o.w = pack2(c * v1.z, c * v1.w);
    *(uint4*)(xb + (size_t)idx * 4) = o;
}

// ---------------------------------------------------------------------------
// wt[layer][n][k] = bf16(W[layer][k][n]) — transposed bf16 weights, the B^T
// operand layout the MFMA fragment loads want (8 contiguous k per lane).
// ---------------------------------------------------------------------------
__global__ __launch_bounds__(128) void wconv_kernel(
    const float* __restrict__ W0, const float* __restrict__ Ws,
    unsigned short* __restrict__ wt)
{
    const float* Wsrc = (blockIdx.x == 0) ? W0 : (Ws + (size_t)(blockIdx.x - 1) * HF * HF);
    unsigned short* dstp = wt + (size_t)blockIdx.x * HF * HF;
    int n = threadIdx.x;
    for (int k = 0; k < HF; k += 2) {
        float v0 = Wsrc[k * HF + n];
        float v1 = Wsrc[(k + 1) * HF + n];
        *(unsigned*)(dstp + n * HF + k) = pack2(v0, v1);
    }
}

// ---------------------------------------------------------------------------
// Aggregation: one wave per node, bf16 rows (256B); f32 accumulate; writes
// BF16 agg rows (GEMM A operand). Source rows pre-scaled by ns; nd here.
// ---------------------------------------------------------------------------
__global__ __launch_bounds__(256) void agg_kernel(
    const unsigned short* __restrict__ hb, const int* __restrict__ csr,
    const int* __restrict__ nodeOfs, const float* __restrict__ nd,
    unsigned short* __restrict__ ab)
{
    int node = blockIdx.x * 4 + (threadIdx.x >> 6);
    if (node >= N_NODES) return;
    int lane = threadIdx.x & 63;
    int half = lane >> 5;
    int flo = (lane & 31) * 4;                 // 4 features per lane
    int beg = nodeOfs[node], end = nodeOfs[node + 1];

    float a0 = 0.f, a1 = 0.f, a2 = 0.f, a3 = 0.f;
    for (int base = beg; base < end; base += 64) {
        int m = min(64, end - base);
        int sl = (lane < m) ? csr[base + lane] : 0;
        int k = 0;
        for (; k + 1 < m; k += 2) {
            int s0 = __builtin_amdgcn_readlane(sl, k);
            int s1 = __builtin_amdgcn_readlane(sl, k + 1);
            int sr = half ? s1 : s0;
            ushort4 v = *(const ushort4*)(hb + (size_t)sr * HF + flo);
            a0 += b2f(v.x); a1 += b2f(v.y); a2 += b2f(v.z); a3 += b2f(v.w);
        }
        if (k < m && half == 0) {
            int s0 = __builtin_amdgcn_readlane(sl, k);
            ushort4 v = *(const ushort4*)(hb + (size_t)s0 * HF + flo);
            a0 += b2f(v.x); a1 += b2f(v.y); a2 += b2f(v.z); a3 += b2f(v.w);
        }
    }
    a0 += __shfl_xor(a0, 32); a1 += __shfl_xor(a1, 32);
    a2 += __shfl_xor(a2, 32); a3 += __shfl_xor(a3, 32);
    if (half == 0) {
        float mm = nd[node];
        uint2 w2;
        w2.x = pack2(a0 * mm, a1 * mm);
        w2.y = pack2(a2 * mm, a3 * mm);
        *(uint2*)(ab + (size_t)node * HF + flo) = w2;
    }
}

// ---------------------------------------------------------------------------
// MFMA GEMM (m97-verified structure): A [M][K] bf16, B = W^T [N][K] bf16,
// mfma_f32_16x16x32_bf16, C/D col=lane&15 row=(lane>>4)*4+reg. 128x128 tile,
// 8 waves, wave w owns m-tile w (16 rows) x 8 n-tiles x 4 k-steps.
// LDS: sA 32KB + sB 32KB, XOR-swizzle byte^=((row&7)<<4) (G4 fix for 256B
// row stride). Fused epilogue: bias [+0.5*ori], LN+ReLU+ns-prescale -> bf16.
//   MODE 0: t(f32)->out2(=ori=d_out); bf16 -> hb
//   MODE 1: bf16 -> hb
//   MODE 2: t(f32)->out2 (final)
// ---------------------------------------------------------------------------
template <int MODE>
__global__ __launch_bounds__(GEMM_THREADS) void gemm_fused(
    const unsigned short* __restrict__ A, const unsigned short* __restrict__ Wt,
    const float* __restrict__ bias, const float* __restrict__ lng,
    const float* __restrict__ lnb, const float* __restrict__ ori,
    const float* __restrict__ ns, unsigned short* __restrict__ hb,
    float* __restrict__ out2)
{
    __shared__ char smem[65536];   // sA [0,32K), sB [32K,64K)
    const int tid = threadIdx.x;
    const int row0 = blockIdx.x * MT;

    // stage B = Wt (32KB) and A tile (32KB), swizzled on 16B granules
#pragma unroll
    for (int i = 0; i < 4; ++i) {
        int ch = tid + i * 512;            // 16B chunk id, 0..2047
        int row = ch >> 4;
        uint4 v = ((const uint4*)Wt)[ch];
        *(uint4*)(smem + 32768 + ((ch * 16) ^ ((row & 7) << 4))) = v;
    }
#pragma unroll
    for (int i = 0; i < 4; ++i) {
        int ch = tid + i * 512;
        int row = ch >> 4;
        int grow = min(row0 + row, N_NODES - 1);
        uint4 v = *(const uint4*)(A + (size_t)grow * HF + (ch & 15) * 8);
        *(uint4*)(smem + ((ch * 16) ^ ((row & 7) << 4))) = v;
    }
    __syncthreads();

    const int w  = tid >> 6;
    const int l  = tid & 63;
    const int lo = l & 15;
    const int hi = l >> 4;
    const int arow = w * 16 + lo;

    f32x4 acc[8];
#pragma unroll
    for (int nt = 0; nt < 8; ++nt) acc[nt] = (f32x4){0.f, 0.f, 0.f, 0.f};

#pragma unroll
    for (int kk = 0; kk < 4; ++kk) {
        bf16x8 af = *(const bf16x8*)(smem +
            ((arow * 256 + kk * 64 + hi * 16) ^ ((arow & 7) << 4)));
#pragma unroll
        for (int nt = 0; nt < 8; ++nt) {
            int n = nt * 16 + lo;
            bf16x8 bfr = *(const bf16x8*)(smem + 32768 +
                ((n * 256 + kk * 64 + hi * 16) ^ ((n & 7) << 4)));
            acc[nt] = __builtin_amdgcn_mfma_f32_16x16x32_bf16(af, bfr, acc[nt], 0, 0, 0);
        }
    }

    // epilogue: thread owns rows m = w*16 + hi*4 + r (r=0..3), cols n = nt*16+lo
    float bia[8], gg[8], bb[8];
#pragma unroll
    for (int nt = 0; nt < 8; ++nt) {
        bia[nt] = bias[nt * 16 + lo];
        if constexpr (MODE != 2) {
            gg[nt] = lng[nt * 16 + lo];
            bb[nt] = lnb[nt * 16 + lo];
        }
    }

#pragma unroll
    for (int r = 0; r < 4; ++r) {
        const int row = row0 + w * 16 + hi * 4 + r;
        const bool ok = row < N_NODES;
        const int rowc = ok ? row : N_NODES - 1;
        float t[8];
        float s = 0.f, ssum = 0.f;
#pragma unroll
        for (int nt = 0; nt < 8; ++nt) {
            float v = acc[nt][r] + bia[nt];
            if constexpr (MODE != 0)
                v = fmaf(RESC, ori[(size_t)rowc * HF + nt * 16 + lo], v);
            t[nt] = v;
            s += v; ssum += v * v;
        }
        if constexpr (MODE == 0) {
            if (ok) {
#pragma unroll
                for (int nt = 0; nt < 8; ++nt)
                    out2[(size_t)row * HF + nt * 16 + lo] = t[nt];
            }
        }
        if constexpr (MODE == 2) {
            if (ok) {
#pragma unroll
                for (int nt = 0; nt < 8; ++nt)
                    out2[(size_t)row * HF + nt * 16 + lo] = t[nt];
            }
        } else {
            // LayerNorm across the 16 lanes of this hi-group (x8 nt each)
#pragma unroll
            for (int m = 8; m >= 1; m >>= 1) {
                s    += __shfl_xor(s, m);
                ssum += __shfl_xor(ssum, m);
            }
            float mu   = s * (1.0f / HF);
            float var  = ssum * (1.0f / HF) - mu * mu;
            float rinv = rsqrtf(var + LN_EPS);
            float nsr  = ns[rowc];
            if (ok) {
#pragma unroll
                for (int nt = 0; nt < 8; ++nt) {
                    float y = nsr * fmaxf(0.f, (t[nt] - mu) * rinv * gg[nt] + bb[nt]);
                    hb[(size_t)row * HF + nt * 16 + lo] = (unsigned short)f2b(y);
                }
            }
        }
    }
}

// ---------------------------------------------------------------------------
extern "C" void kernel_launch(void* const* d_in, const int* in_sizes, int n_in,
                              void* d_out, int out_size, void* d_ws, size_t ws_size,
                              hipStream_t stream)
{
    const float* x   = (const float*)d_in[0];
    const float* W0  = (const float*)d_in[1];
    const float* Ws  = (const float*)d_in[2];
    const float* b   = (const float*)d_in[3];
    const float* lng = (const float*)d_in[4];
    const float* lnb = (const float*)d_in[5];
    const int*   src = (const int*)d_in[6];
    const int*   dst = (const int*)d_in[7];
    float* out = (float*)d_out;

    // workspace layout, total ~99.5 MB; everything written before read.
    char* ws = (char*)d_ws;
    int*   histD     = (int*)(ws + 0);            // NBIN*NCHUNK ints
    int*   histS     = (int*)(ws + 307200);
    int*   rowTotD   = (int*)(ws + 614400);
    int*   rowTotS   = (int*)(ws + 617984);
    int*   rowBaseD  = (int*)(ws + 621568);
    int*   rowBaseS  = (int*)(ws + 625152);
    int*   binOfs    = (int*)(ws + 628736);
    int*   srcbinOfs = (int*)(ws + 632320);
    float* ns        = (float*)(ws + 635904);
    float* nd        = (float*)(ws + 1036288);
    int*   nodeOfs   = (int*)(ws + 1436672);
    unsigned short* dstrank = (unsigned short*)(ws + 1837056);
    unsigned short* srcrank = (unsigned short*)(ws + 5037056);
    int*   pairs     = (int*)(ws + 8237056);
    unsigned char* sbytes = (unsigned char*)(ws + 14637056);
    int*   csr       = (int*)(ws + 16237056);
    unsigned*       xb = (unsigned*)(ws + 22637056);        // N*128 bf16
    unsigned short* hb = (unsigned short*)(ws + 48237056);  // N*128 bf16
    unsigned short* ab = (unsigned short*)(ws + 73837056);  // N*128 bf16 (agg)
    unsigned short* wt = (unsigned short*)(ws + 99437056);  // 3*128*128 bf16

    histrank_kernel<<<NCHUNK, 1024, 0, stream>>>(src, dst, histD, histS, dstrank, srcrank);
    scanA_kernel<<<(2 * NBIN + 3) / 4, 256, 0, stream>>>(histD, histS, rowTotD, rowTotS);
    scanB_kernel<<<1, 1024, 0, stream>>>(rowTotD, rowTotS, rowBaseD, rowBaseS, binOfs, srcbinOfs);
    scatter_kernel<<<NCHUNK, 1024, 0, stream>>>(src, dst, dstrank, srcrank,
                                                histD, histS, rowBaseD, rowBaseS,
                                                pairs, sbytes);
    srccount_kernel<<<NBIN, 256, 0, stream>>>(sbytes, srcbinOfs, ns);
    csrbuild_kernel<<<NBIN, 256, 0, stream>>>(pairs, binOfs, nd, nodeOfs, csr);
    wconv_kernel<<<3, 128, 0, stream>>>(W0, Ws, wt);
    xconv_kernel<<<(N_NODES * HF / 8 + 255) / 256, 256, 0, stream>>>(x, ns, xb);

    const int gemm_grid = (N_NODES + MT - 1) / MT;   // 782

    // layer 0
    agg_kernel<<<(N_NODES + 3) / 4, 256, 0, stream>>>(
        (const unsigned short*)xb, csr, nodeOfs, nd, ab);
    gemm_fused<0><<<gemm_grid, GEMM_THREADS, 0, stream>>>(
        ab, wt, b, lng + HF, lnb + HF, nullptr, ns, hb, out);

    // layer 1
    agg_kernel<<<(N_NODES + 3) / 4, 256, 0, stream>>>(hb, csr, nodeOfs, nd, ab);
    gemm_fused<1><<<gemm_grid, GEMM_THREADS, 0, stream>>>(
        ab, wt + HF * HF, b + HF, lng + 2 * HF, lnb + 2 * HF, out, ns, hb, nullptr);

    // layer 2
    agg_kernel<<<(N_NODES + 3) / 4, 256, 0, stream>>>(hb, csr, nodeOfs, nd, ab);
    gemm_fused<2><<<gemm_grid, GEMM_THREADS, 0, stream>>>(
        ab, wt + 2 * HF * HF, b + 2 * HF, nullptr, nullptr, out, ns, nullptr, out);
}

// Round 9
// 330.878 us; speedup vs baseline: 3.5448x; 1.1117x over previous
//
#include <hip/hip_runtime.h>

// Problem constants (fixed by the reference)
#define N_NODES 100000
#define N_EDGES 1600000
#define HF      128
#define RESC    0.5f
#define LN_EPS  1e-5f

#define BINW_SHIFT 7
#define BINW       128
#define NBIN       ((N_NODES + BINW - 1) >> BINW_SHIFT)   // 782
#define HCHUNK     16384
#define NCHUNK     ((N_EDGES + HCHUNK - 1) / HCHUNK)      // 98

#define GEMM_THREADS 512
#define MT  128             // rows per GEMM block

typedef __attribute__((ext_vector_type(8))) short bf16x8;  // MFMA A/B frag
typedef __attribute__((ext_vector_type(4))) float f32x4;   // MFMA C/D frag

// bf16 helpers (round-to-nearest-even)
static __device__ __forceinline__ unsigned f2b(float f) {
    unsigned u = __float_as_uint(f);
    return (u + 0x7FFFu + ((u >> 16) & 1u)) >> 16;
}
static __device__ __forceinline__ unsigned pack2(float a, float b) {
    return f2b(a) | (f2b(b) << 16);
}
static __device__ __forceinline__ float b2f(unsigned short u) {
    return __uint_as_float(((unsigned)u) << 16);
}
static __device__ __forceinline__ float blo(unsigned u) {
    return __uint_as_float(u << 16);
}
static __device__ __forceinline__ float bhi(unsigned u) {
    return __uint_as_float(u & 0xFFFF0000u);
}

// ---------------------------------------------------------------------------
// Counting-sort pass 1: per-chunk LDS bin histograms (dst & src). The LDS
// atomic's RETURN VALUE is the edge's intra-chunk intra-bin rank -> stored.
// ---------------------------------------------------------------------------
__global__ __launch_bounds__(1024) void histrank_kernel(
    const int* __restrict__ src, const int* __restrict__ dst,
    int* __restrict__ histD, int* __restrict__ histS,
    unsigned short* __restrict__ dstrank, unsigned short* __restrict__ srcrank)
{
    __shared__ int hd[NBIN], hs[NBIN];
    for (int i = threadIdx.x; i < NBIN; i += 1024) { hd[i] = 0; hs[i] = 0; }
    __syncthreads();
    int base = blockIdx.x * HCHUNK;
    int lim = min(base + HCHUNK, N_EDGES);
    for (int e = base + (int)threadIdx.x; e < lim; e += 1024) {
        int d = dst[e], s = src[e];
        int rd = atomicAdd(&hd[d >> BINW_SHIFT], 1);
        int rs = atomicAdd(&hs[s >> BINW_SHIFT], 1);
        dstrank[e] = (unsigned short)rd;
        srcrank[e] = (unsigned short)rs;
    }
    __syncthreads();
    for (int i = threadIdx.x; i < NBIN; i += 1024) {
        histD[i * NCHUNK + blockIdx.x] = hd[i];
        histS[i * NCHUNK + blockIdx.x] = hs[i];
    }
}

// ---------------------------------------------------------------------------
// Pass 2a: exclusive scan WITHIN each bin across its 98 chunk counts.
// ---------------------------------------------------------------------------
__global__ __launch_bounds__(256) void scanA_kernel(
    int* __restrict__ histD, int* __restrict__ histS,
    int* __restrict__ rowTotD, int* __restrict__ rowTotS)
{
    int row = blockIdx.x * 4 + ((int)threadIdx.x >> 6);
    int lane = threadIdx.x & 63;
    if (row >= 2 * NBIN) return;
    int* h = (row < NBIN) ? (histD + row * NCHUNK) : (histS + (row - NBIN) * NCHUNK);
    int v0 = h[lane];
    int v1 = (64 + lane < NCHUNK) ? h[64 + lane] : 0;
    int s0 = v0, s1 = v1;
#pragma unroll
    for (int off = 1; off < 64; off <<= 1) {
        int u0 = __shfl_up(s0, off); if (lane >= off) s0 += u0;
        int u1 = __shfl_up(s1, off); if (lane >= off) s1 += u1;
    }
    int c = __shfl(s0, 63);
    h[lane] = s0 - v0;
    if (64 + lane < NCHUNK) h[64 + lane] = c + s1 - v1;
    int tot = c + __shfl(s1, 63);
    if (lane == 0) {
        if (row < NBIN) rowTotD[row] = tot;
        else            rowTotS[row - NBIN] = tot;
    }
}

// ---------------------------------------------------------------------------
// Pass 2b: single-block exclusive scan over the 782 bin totals (both sides).
// ---------------------------------------------------------------------------
__global__ __launch_bounds__(1024) void scanB_kernel(
    const int* __restrict__ rowTotD, const int* __restrict__ rowTotS,
    int* __restrict__ rowBaseD, int* __restrict__ rowBaseS,
    int* __restrict__ binOfs, int* __restrict__ srcbinOfs)
{
    __shared__ int wsum[16];
    for (int side = 0; side < 2; ++side) {
        const int* cnt = side ? rowTotS : rowTotD;
        int* base = side ? rowBaseS : rowBaseD;
        int* ofs  = side ? srcbinOfs : binOfs;
        int b = threadIdx.x;
        int tot = (b < NBIN) ? cnt[b] : 0;
        int lane = threadIdx.x & 63, wid = threadIdx.x >> 6;
        int x = tot;
#pragma unroll
        for (int off = 1; off < 64; off <<= 1) { int u = __shfl_up(x, off); if (lane >= off) x += u; }
        if (lane == 63) wsum[wid] = x;
        __syncthreads();
        if (wid == 0) {
            int y = (lane < 16) ? wsum[lane] : 0;
#pragma unroll
            for (int off = 1; off < 16; off <<= 1) { int u = __shfl_up(y, off); if (lane >= off) y += u; }
            if (lane < 16) wsum[lane] = y;
        }
        __syncthreads();
        int incl = x + (wid > 0 ? wsum[wid - 1] : 0);
        if (b < NBIN) {
            base[b] = incl - tot;
            ofs[b + 1] = incl;
            if (b == 0) ofs[0] = 0;
        }
        __syncthreads();
    }
}

// ---------------------------------------------------------------------------
// Counting-sort pass 3: deterministic scatter, no atomics.
// ---------------------------------------------------------------------------
__global__ __launch_bounds__(1024) void scatter_kernel(
    const int* __restrict__ src, const int* __restrict__ dst,
    const unsigned short* __restrict__ dstrank, const unsigned short* __restrict__ srcrank,
    const int* __restrict__ histD, const int* __restrict__ histS,
    const int* __restrict__ rowBaseD, const int* __restrict__ rowBaseS,
    int* __restrict__ pairs, unsigned char* __restrict__ sbytes)
{
    __shared__ int baseD[NBIN], baseS[NBIN];
    for (int i = threadIdx.x; i < NBIN; i += 1024) {
        baseD[i] = rowBaseD[i] + histD[i * NCHUNK + blockIdx.x];
        baseS[i] = rowBaseS[i] + histS[i * NCHUNK + blockIdx.x];
    }
    __syncthreads();
    int base = blockIdx.x * HCHUNK;
    int lim = min(base + HCHUNK, N_EDGES);
    for (int e = base + (int)threadIdx.x; e < lim; e += 1024) {
        int d = dst[e], s = src[e];
        pairs[baseD[d >> BINW_SHIFT] + dstrank[e]] = (s << BINW_SHIFT) | (d & (BINW - 1));
        sbytes[baseS[s >> BINW_SHIFT] + srcrank[e]] = (unsigned char)(s & (BINW - 1));
    }
}

// ---------------------------------------------------------------------------
// Src side finisher: per-bin LDS histogram of sloc bytes -> ns directly.
// ---------------------------------------------------------------------------
__global__ __launch_bounds__(256) void srccount_kernel(
    const unsigned char* __restrict__ sbytes, const int* __restrict__ srcbinOfs,
    float* __restrict__ ns)
{
    __shared__ int h[BINW];
    if (threadIdx.x < BINW) h[threadIdx.x] = 0;
    __syncthreads();
    int beg = srcbinOfs[blockIdx.x], end = srcbinOfs[blockIdx.x + 1];
    for (int i = beg + (int)threadIdx.x; i < end; i += 256)
        atomicAdd(&h[sbytes[i] & (BINW - 1)], 1);
    __syncthreads();
    int node = (blockIdx.x << BINW_SHIFT) + threadIdx.x;
    if (threadIdx.x < BINW && node < N_NODES)
        ns[node] = rsqrtf((float)max(h[threadIdx.x], 1));
}

// ---------------------------------------------------------------------------
// Dst side finisher: per-bin LDS histogram -> intra-bin prefix -> nodeOfs +
// nd, then CSR scatter via LDS cursors into the bin's L2-hot window.
// ---------------------------------------------------------------------------
__global__ __launch_bounds__(256) void csrbuild_kernel(
    const int* __restrict__ pairs, const int* __restrict__ binOfs,
    float* __restrict__ nd, int* __restrict__ nodeOfs, int* __restrict__ csr)
{
    __shared__ int h[BINW];
    __shared__ int curs[BINW];
    if (threadIdx.x < BINW) h[threadIdx.x] = 0;
    __syncthreads();
    int beg = binOfs[blockIdx.x], end = binOfs[blockIdx.x + 1];
    for (int i = beg + (int)threadIdx.x; i < end; i += 256)
        atomicAdd(&h[pairs[i] & (BINW - 1)], 1);
    __syncthreads();
    if (threadIdx.x < 64) {
        int lane = threadIdx.x;
        int v0 = h[lane], v1 = h[lane + 64];
        int s0 = v0, s1 = v1;
#pragma unroll
        for (int off = 1; off < 64; off <<= 1) {
            int u0 = __shfl_up(s0, off); if (lane >= off) s0 += u0;
            int u1 = __shfl_up(s1, off); if (lane >= off) s1 += u1;
        }
        int t0 = __shfl(s0, 63);
        curs[lane]      = beg + (s0 - v0);
        curs[lane + 64] = beg + (s1 - v1) + t0;
    }
    __syncthreads();
    int node = (blockIdx.x << BINW_SHIFT) + threadIdx.x;
    if (threadIdx.x < BINW && node < N_NODES) {
        nodeOfs[node] = curs[threadIdx.x];
        nd[node] = rsqrtf((float)max(h[threadIdx.x], 1));
        if (node == N_NODES - 1) nodeOfs[N_NODES] = end;
    }
    __syncthreads();
    for (int i = beg + (int)threadIdx.x; i < end; i += 256) {
        int p = pairs[i];
        int pos = atomicAdd(&curs[p & (BINW - 1)], 1);
        csr[pos] = p >> BINW_SHIFT;
    }
}

// ---------------------------------------------------------------------------
// xb[i] = bf16(ns[row] * x[i]) — pre-scaled bf16 copy of x for the gather.
// ---------------------------------------------------------------------------
__global__ __launch_bounds__(256) void xconv_kernel(
    const float* __restrict__ x, const float* __restrict__ ns,
    unsigned* __restrict__ xb)
{
    int idx = blockIdx.x * 256 + threadIdx.x;    // 8 elements per thread
    if (idx >= N_NODES * HF / 8) return;
    int row = idx >> 4;
    float c = ns[row];
    const float4* px = (const float4*)(x + (size_t)idx * 8);
    float4 v0 = px[0], v1 = px[1];
    uint4 o;
    o.x = pack2(c * v0.x, c * v0.y);
    o.y = pack2(c * v0.z, c * v0.w);
    o.z = pack2(c * v1.x, c * v1.y);
    o.w = pack2(c * v1.z, c * v1.w);
    *(uint4*)(xb + (size_t)idx * 4) = o;
}

// ---------------------------------------------------------------------------
// wt[layer][n][k] = bf16(W[layer][k][n]) — transposed bf16 weights (B^T).
// ---------------------------------------------------------------------------
__global__ __launch_bounds__(128) void wconv_kernel(
    const float* __restrict__ W0, const float* __restrict__ Ws,
    unsigned short* __restrict__ wt)
{
    const float* Wsrc = (blockIdx.x == 0) ? W0 : (Ws + (size_t)(blockIdx.x - 1) * HF * HF);
    unsigned short* dstp = wt + (size_t)blockIdx.x * HF * HF;
    int n = threadIdx.x;
    for (int k = 0; k < HF; k += 2) {
        float v0 = Wsrc[k * HF + n];
        float v1 = Wsrc[(k + 1) * HF + n];
        *(unsigned*)(dstp + n * HF + k) = pack2(v0, v1);
    }
}

// ---------------------------------------------------------------------------
// Aggregation: one wave per node. 4 lane-groups of 16; each group owns one
// edge per round, each lane loads uint4 = 8 bf16 feats (full 256B row per
// group in ONE instruction). 4 edges in flight/round -> 2x the MLP, ~half
// the VALU of the 2-edge version. Group combine via shfl_xor(16|32); lanes
// 0-15 write the bf16 agg row as one coalesced uint4 each.
// ---------------------------------------------------------------------------
__global__ __launch_bounds__(256) void agg_kernel(
    const unsigned short* __restrict__ hb, const int* __restrict__ csr,
    const int* __restrict__ nodeOfs, const float* __restrict__ nd,
    unsigned short* __restrict__ ab)
{
    int node = blockIdx.x * 4 + (threadIdx.x >> 6);
    if (node >= N_NODES) return;
    int lane = threadIdx.x & 63;
    int g   = lane >> 4;           // edge group 0..3
    int fl  = (lane & 15) * 8;     // 8 features per lane
    int beg = nodeOfs[node], end = nodeOfs[node + 1];

    float a0 = 0.f, a1 = 0.f, a2 = 0.f, a3 = 0.f;
    float a4 = 0.f, a5 = 0.f, a6 = 0.f, a7 = 0.f;
    for (int base = beg; base < end; base += 64) {
        int m = min(64, end - base);
        int sl = (lane < m) ? csr[base + lane] : 0;
#pragma unroll 2
        for (int k = 0; k < m; k += 4) {
            int sidx = __shfl(sl, k + g);          // group g's edge id
            uint4 v = make_uint4(0u, 0u, 0u, 0u);
            if (k + g < m)
                v = *(const uint4*)(hb + (size_t)sidx * HF + fl);
            a0 += blo(v.x); a1 += bhi(v.x);
            a2 += blo(v.y); a3 += bhi(v.y);
            a4 += blo(v.z); a5 += bhi(v.z);
            a6 += blo(v.w); a7 += bhi(v.w);
        }
    }
#pragma unroll
    for (int off = 16; off <= 32; off <<= 1) {
        a0 += __shfl_xor(a0, off); a1 += __shfl_xor(a1, off);
        a2 += __shfl_xor(a2, off); a3 += __shfl_xor(a3, off);
        a4 += __shfl_xor(a4, off); a5 += __shfl_xor(a5, off);
        a6 += __shfl_xor(a6, off); a7 += __shfl_xor(a7, off);
    }
    if (lane < 16) {
        float mm = nd[node];
        uint4 o;
        o.x = pack2(a0 * mm, a1 * mm);
        o.y = pack2(a2 * mm, a3 * mm);
        o.z = pack2(a4 * mm, a5 * mm);
        o.w = pack2(a6 * mm, a7 * mm);
        *(uint4*)(ab + (size_t)node * HF + fl) = o;
    }
}

// ---------------------------------------------------------------------------
// MFMA GEMM (m97-verified structure): A [M][K] bf16, B = W^T [N][K] bf16,
// mfma_f32_16x16x32_bf16, C/D col=lane&15 row=(lane>>4)*4+reg. 128x128 tile,
// 8 waves. LDS XOR-swizzle byte^=((row&7)<<4). Fused epilogue.
//   MODE 0: t(f32)->out2(=ori=d_out); bf16 -> hb
//   MODE 1: bf16 -> hb
//   MODE 2: t(f32)->out2 (final)
// ---------------------------------------------------------------------------
template <int MODE>
__global__ __launch_bounds__(GEMM_THREADS) void gemm_fused(
    const unsigned short* __restrict__ A, const unsigned short* __restrict__ Wt,
    const float* __restrict__ bias, const float* __restrict__ lng,
    const float* __restrict__ lnb, const float* __restrict__ ori,
    const float* __restrict__ ns, unsigned short* __restrict__ hb,
    float* __restrict__ out2)
{
    __shared__ char smem[65536];   // sA [0,32K), sB [32K,64K)
    const int tid = threadIdx.x;
    const int row0 = blockIdx.x * MT;

#pragma unroll
    for (int i = 0; i < 4; ++i) {
        int ch = tid + i * 512;            // 16B chunk id, 0..2047
        int row = ch >> 4;
        uint4 v = ((const uint4*)Wt)[ch];
        *(uint4*)(smem + 32768 + ((ch * 16) ^ ((row & 7) << 4))) = v;
    }
#pragma unroll
    for (int i = 0; i < 4; ++i) {
        int ch = tid + i * 512;
        int row = ch >> 4;
        int grow = min(row0 + row, N_NODES - 1);
        uint4 v = *(const uint4*)(A + (size_t)grow * HF + (ch & 15) * 8);
        *(uint4*)(smem + ((ch * 16) ^ ((row & 7) << 4))) = v;
    }
    __syncthreads();

    const int w  = tid >> 6;
    const int l  = tid & 63;
    const int lo = l & 15;
    const int hi = l >> 4;
    const int arow = w * 16 + lo;

    f32x4 acc[8];
#pragma unroll
    for (int nt = 0; nt < 8; ++nt) acc[nt] = (f32x4){0.f, 0.f, 0.f, 0.f};

#pragma unroll
    for (int kk = 0; kk < 4; ++kk) {
        bf16x8 af = *(const bf16x8*)(smem +
            ((arow * 256 + kk * 64 + hi * 16) ^ ((arow & 7) << 4)));
#pragma unroll
        for (int nt = 0; nt < 8; ++nt) {
            int n = nt * 16 + lo;
            bf16x8 bfr = *(const bf16x8*)(smem + 32768 +
                ((n * 256 + kk * 64 + hi * 16) ^ ((n & 7) << 4)));
            acc[nt] = __builtin_amdgcn_mfma_f32_16x16x32_bf16(af, bfr, acc[nt], 0, 0, 0);
        }
    }

    float bia[8], gg[8], bb[8];
#pragma unroll
    for (int nt = 0; nt < 8; ++nt) {
        bia[nt] = bias[nt * 16 + lo];
        if constexpr (MODE != 2) {
            gg[nt] = lng[nt * 16 + lo];
            bb[nt] = lnb[nt * 16 + lo];
        }
    }

#pragma unroll
    for (int r = 0; r < 4; ++r) {
        const int row = row0 + w * 16 + hi * 4 + r;
        const bool ok = row < N_NODES;
        const int rowc = ok ? row : N_NODES - 1;
        float t[8];
        float s = 0.f, ssum = 0.f;
#pragma unroll
        for (int nt = 0; nt < 8; ++nt) {
            float v = acc[nt][r] + bia[nt];
            if constexpr (MODE != 0)
                v = fmaf(RESC, ori[(size_t)rowc * HF + nt * 16 + lo], v);
            t[nt] = v;
            s += v; ssum += v * v;
        }
        if constexpr (MODE == 0) {
            if (ok) {
#pragma unroll
                for (int nt = 0; nt < 8; ++nt)
                    out2[(size_t)row * HF + nt * 16 + lo] = t[nt];
            }
        }
        if constexpr (MODE == 2) {
            if (ok) {
#pragma unroll
                for (int nt = 0; nt < 8; ++nt)
                    out2[(size_t)row * HF + nt * 16 + lo] = t[nt];
            }
        } else {
#pragma unroll
            for (int m = 8; m >= 1; m >>= 1) {
                s    += __shfl_xor(s, m);
                ssum += __shfl_xor(ssum, m);
            }
            float mu   = s * (1.0f / HF);
            float var  = ssum * (1.0f / HF) - mu * mu;
            float rinv = rsqrtf(var + LN_EPS);
            float nsr  = ns[rowc];
            if (ok) {
#pragma unroll
                for (int nt = 0; nt < 8; ++nt) {
                    float y = nsr * fmaxf(0.f, (t[nt] - mu) * rinv * gg[nt] + bb[nt]);
                    hb[(size_t)row * HF + nt * 16 + lo] = (unsigned short)f2b(y);
                }
            }
        }
    }
}

// ---------------------------------------------------------------------------
extern "C" void kernel_launch(void* const* d_in, const int* in_sizes, int n_in,
                              void* d_out, int out_size, void* d_ws, size_t ws_size,
                              hipStream_t stream)
{
    const float* x   = (const float*)d_in[0];
    const float* W0  = (const float*)d_in[1];
    const float* Ws  = (const float*)d_in[2];
    const float* b   = (const float*)d_in[3];
    const float* lng = (const float*)d_in[4];
    const float* lnb = (const float*)d_in[5];
    const int*   src = (const int*)d_in[6];
    const int*   dst = (const int*)d_in[7];
    float* out = (float*)d_out;

    // workspace layout, total ~99.5 MB; everything written before read.
    char* ws = (char*)d_ws;
    int*   histD     = (int*)(ws + 0);            // NBIN*NCHUNK ints
    int*   histS     = (int*)(ws + 307200);
    int*   rowTotD   = (int*)(ws + 614400);
    int*   rowTotS   = (int*)(ws + 617984);
    int*   rowBaseD  = (int*)(ws + 621568);
    int*   rowBaseS  = (int*)(ws + 625152);
    int*   binOfs    = (int*)(ws + 628736);
    int*   srcbinOfs = (int*)(ws + 632320);
    float* ns        = (float*)(ws + 635904);
    float* nd        = (float*)(ws + 1036288);
    int*   nodeOfs   = (int*)(ws + 1436672);
    unsigned short* dstrank = (unsigned short*)(ws + 1837056);
    unsigned short* srcrank = (unsigned short*)(ws + 5037056);
    int*   pairs     = (int*)(ws + 8237056);
    unsigned char* sbytes = (unsigned char*)(ws + 14637056);
    int*   csr       = (int*)(ws + 16237056);
    unsigned*       xb = (unsigned*)(ws + 22637056);        // N*128 bf16
    unsigned short* hb = (unsigned short*)(ws + 48237056);  // N*128 bf16
    unsigned short* ab = (unsigned short*)(ws + 73837056);  // N*128 bf16 (agg)
    unsigned short* wt = (unsigned short*)(ws + 99437056);  // 3*128*128 bf16

    histrank_kernel<<<NCHUNK, 1024, 0, stream>>>(src, dst, histD, histS, dstrank, srcrank);
    scanA_kernel<<<(2 * NBIN + 3) / 4, 256, 0, stream>>>(histD, histS, rowTotD, rowTotS);
    scanB_kernel<<<1, 1024, 0, stream>>>(rowTotD, rowTotS, rowBaseD, rowBaseS, binOfs, srcbinOfs);
    scatter_kernel<<<NCHUNK, 1024, 0, stream>>>(src, dst, dstrank, srcrank,
                                                histD, histS, rowBaseD, rowBaseS,
                                                pairs, sbytes);
    srccount_kernel<<<NBIN, 256, 0, stream>>>(sbytes, srcbinOfs, ns);
    csrbuild_kernel<<<NBIN, 256, 0, stream>>>(pairs, binOfs, nd, nodeOfs, csr);
    wconv_kernel<<<3, 128, 0, stream>>>(W0, Ws, wt);
    xconv_kernel<<<(N_NODES * HF / 8 + 255) / 256, 256, 0, stream>>>(x, ns, xb);

    const int gemm_grid = (N_NODES + MT - 1) / MT;   // 782

    // layer 0
    agg_kernel<<<(N_NODES + 3) / 4, 256, 0, stream>>>(
        (const unsigned short*)xb, csr, nodeOfs, nd, ab);
    gemm_fused<0><<<gemm_grid, GEMM_THREADS, 0, stream>>>(
        ab, wt, b, lng + HF, lnb + HF, nullptr, ns, hb, out);

    // layer 1
    agg_kernel<<<(N_NODES + 3) / 4, 256, 0, stream>>>(hb, csr, nodeOfs, nd, ab);
    gemm_fused<1><<<gemm_grid, GEMM_THREADS, 0, stream>>>(
        ab, wt + HF * HF, b + HF, lng + 2 * HF, lnb + 2 * HF, out, ns, hb, nullptr);

    // layer 2
    agg_kernel<<<(N_NODES + 3) / 4, 256, 0, stream>>>(hb, csr, nodeOfs, nd, ab);
    gemm_fused<2><<<gemm_grid, GEMM_THREADS, 0, stream>>>(
        ab, wt + 2 * HF * HF, b + 2 * HF, nullptr, nullptr, out, ns, nullptr, out);
}

// Round 10
// 320.541 us; speedup vs baseline: 3.6591x; 1.0322x over previous
//
#include <hip/hip_runtime.h>

// Problem constants (fixed by the reference)
#define N_NODES 100000
#define N_EDGES 1600000
#define HF      128
#define RESC    0.5f
#define LN_EPS  1e-5f

#define BINW_SHIFT 7
#define BINW       128
#define NBIN       ((N_NODES + BINW - 1) >> BINW_SHIFT)   // 782
#define HCHUNK     16384
#define NCHUNK     ((N_EDGES + HCHUNK - 1) / HCHUNK)      // 98

#define GEMM_THREADS 512
#define MT  128             // rows per GEMM block

typedef __attribute__((ext_vector_type(8))) short bf16x8;  // MFMA A/B frag
typedef __attribute__((ext_vector_type(4))) float f32x4;   // MFMA C/D frag

// bf16 helpers (round-to-nearest-even)
static __device__ __forceinline__ unsigned f2b(float f) {
    unsigned u = __float_as_uint(f);
    return (u + 0x7FFFu + ((u >> 16) & 1u)) >> 16;
}
static __device__ __forceinline__ unsigned pack2(float a, float b) {
    return f2b(a) | (f2b(b) << 16);
}
static __device__ __forceinline__ float b2f(unsigned short u) {
    return __uint_as_float(((unsigned)u) << 16);
}
static __device__ __forceinline__ float blo(unsigned u) {
    return __uint_as_float(u << 16);
}
static __device__ __forceinline__ float bhi(unsigned u) {
    return __uint_as_float(u & 0xFFFF0000u);
}

// ---------------------------------------------------------------------------
// Counting-sort pass 1: per-chunk LDS bin histograms (dst & src). The LDS
// atomic's RETURN VALUE is the edge's intra-chunk intra-bin rank -> stored.
// ---------------------------------------------------------------------------
__global__ __launch_bounds__(1024) void histrank_kernel(
    const int* __restrict__ src, const int* __restrict__ dst,
    int* __restrict__ histD, int* __restrict__ histS,
    unsigned short* __restrict__ dstrank, unsigned short* __restrict__ srcrank)
{
    __shared__ int hd[NBIN], hs[NBIN];
    for (int i = threadIdx.x; i < NBIN; i += 1024) { hd[i] = 0; hs[i] = 0; }
    __syncthreads();
    int base = blockIdx.x * HCHUNK;
    int lim = min(base + HCHUNK, N_EDGES);
    for (int e = base + (int)threadIdx.x; e < lim; e += 1024) {
        int d = dst[e], s = src[e];
        int rd = atomicAdd(&hd[d >> BINW_SHIFT], 1);
        int rs = atomicAdd(&hs[s >> BINW_SHIFT], 1);
        dstrank[e] = (unsigned short)rd;
        srcrank[e] = (unsigned short)rs;
    }
    __syncthreads();
    for (int i = threadIdx.x; i < NBIN; i += 1024) {
        histD[i * NCHUNK + blockIdx.x] = hd[i];
        histS[i * NCHUNK + blockIdx.x] = hs[i];
    }
}

// ---------------------------------------------------------------------------
// Pass 2a: exclusive scan WITHIN each bin across its 98 chunk counts.
// ---------------------------------------------------------------------------
__global__ __launch_bounds__(256) void scanA_kernel(
    int* __restrict__ histD, int* __restrict__ histS,
    int* __restrict__ rowTotD, int* __restrict__ rowTotS)
{
    int row = blockIdx.x * 4 + ((int)threadIdx.x >> 6);
    int lane = threadIdx.x & 63;
    if (row >= 2 * NBIN) return;
    int* h = (row < NBIN) ? (histD + row * NCHUNK) : (histS + (row - NBIN) * NCHUNK);
    int v0 = h[lane];
    int v1 = (64 + lane < NCHUNK) ? h[64 + lane] : 0;
    int s0 = v0, s1 = v1;
#pragma unroll
    for (int off = 1; off < 64; off <<= 1) {
        int u0 = __shfl_up(s0, off); if (lane >= off) s0 += u0;
        int u1 = __shfl_up(s1, off); if (lane >= off) s1 += u1;
    }
    int c = __shfl(s0, 63);
    h[lane] = s0 - v0;
    if (64 + lane < NCHUNK) h[64 + lane] = c + s1 - v1;
    int tot = c + __shfl(s1, 63);
    if (lane == 0) {
        if (row < NBIN) rowTotD[row] = tot;
        else            rowTotS[row - NBIN] = tot;
    }
}

// ---------------------------------------------------------------------------
// Pass 2b: single-block exclusive scan over the 782 bin totals (both sides).
// ---------------------------------------------------------------------------
__global__ __launch_bounds__(1024) void scanB_kernel(
    const int* __restrict__ rowTotD, const int* __restrict__ rowTotS,
    int* __restrict__ rowBaseD, int* __restrict__ rowBaseS,
    int* __restrict__ binOfs, int* __restrict__ srcbinOfs)
{
    __shared__ int wsum[16];
    for (int side = 0; side < 2; ++side) {
        const int* cnt = side ? rowTotS : rowTotD;
        int* base = side ? rowBaseS : rowBaseD;
        int* ofs  = side ? srcbinOfs : binOfs;
        int b = threadIdx.x;
        int tot = (b < NBIN) ? cnt[b] : 0;
        int lane = threadIdx.x & 63, wid = threadIdx.x >> 6;
        int x = tot;
#pragma unroll
        for (int off = 1; off < 64; off <<= 1) { int u = __shfl_up(x, off); if (lane >= off) x += u; }
        if (lane == 63) wsum[wid] = x;
        __syncthreads();
        if (wid == 0) {
            int y = (lane < 16) ? wsum[lane] : 0;
#pragma unroll
            for (int off = 1; off < 16; off <<= 1) { int u = __shfl_up(y, off); if (lane >= off) y += u; }
            if (lane < 16) wsum[lane] = y;
        }
        __syncthreads();
        int incl = x + (wid > 0 ? wsum[wid - 1] : 0);
        if (b < NBIN) {
            base[b] = incl - tot;
            ofs[b + 1] = incl;
            if (b == 0) ofs[0] = 0;
        }
        __syncthreads();
    }
}

// ---------------------------------------------------------------------------
// Counting-sort pass 3: deterministic scatter, no atomics.
// ---------------------------------------------------------------------------
__global__ __launch_bounds__(1024) void scatter_kernel(
    const int* __restrict__ src, const int* __restrict__ dst,
    const unsigned short* __restrict__ dstrank, const unsigned short* __restrict__ srcrank,
    const int* __restrict__ histD, const int* __restrict__ histS,
    const int* __restrict__ rowBaseD, const int* __restrict__ rowBaseS,
    int* __restrict__ pairs, unsigned char* __restrict__ sbytes)
{
    __shared__ int baseD[NBIN], baseS[NBIN];
    for (int i = threadIdx.x; i < NBIN; i += 1024) {
        baseD[i] = rowBaseD[i] + histD[i * NCHUNK + blockIdx.x];
        baseS[i] = rowBaseS[i] + histS[i * NCHUNK + blockIdx.x];
    }
    __syncthreads();
    int base = blockIdx.x * HCHUNK;
    int lim = min(base + HCHUNK, N_EDGES);
    for (int e = base + (int)threadIdx.x; e < lim; e += 1024) {
        int d = dst[e], s = src[e];
        pairs[baseD[d >> BINW_SHIFT] + dstrank[e]] = (s << BINW_SHIFT) | (d & (BINW - 1));
        sbytes[baseS[s >> BINW_SHIFT] + srcrank[e]] = (unsigned char)(s & (BINW - 1));
    }
}

// ---------------------------------------------------------------------------
// Src side finisher: per-bin LDS histogram of sloc bytes -> ns directly.
// ---------------------------------------------------------------------------
__global__ __launch_bounds__(256) void srccount_kernel(
    const unsigned char* __restrict__ sbytes, const int* __restrict__ srcbinOfs,
    float* __restrict__ ns)
{
    __shared__ int h[BINW];
    if (threadIdx.x < BINW) h[threadIdx.x] = 0;
    __syncthreads();
    int beg = srcbinOfs[blockIdx.x], end = srcbinOfs[blockIdx.x + 1];
    for (int i = beg + (int)threadIdx.x; i < end; i += 256)
        atomicAdd(&h[sbytes[i] & (BINW - 1)], 1);
    __syncthreads();
    int node = (blockIdx.x << BINW_SHIFT) + threadIdx.x;
    if (threadIdx.x < BINW && node < N_NODES)
        ns[node] = rsqrtf((float)max(h[threadIdx.x], 1));
}

// ---------------------------------------------------------------------------
// Dst side finisher: per-bin LDS histogram -> intra-bin prefix -> nodeOfs +
// nd, then CSR scatter via LDS cursors into the bin's L2-hot window.
// ---------------------------------------------------------------------------
__global__ __launch_bounds__(256) void csrbuild_kernel(
    const int* __restrict__ pairs, const int* __restrict__ binOfs,
    float* __restrict__ nd, int* __restrict__ nodeOfs, int* __restrict__ csr)
{
    __shared__ int h[BINW];
    __shared__ int curs[BINW];
    if (threadIdx.x < BINW) h[threadIdx.x] = 0;
    __syncthreads();
    int beg = binOfs[blockIdx.x], end = binOfs[blockIdx.x + 1];
    for (int i = beg + (int)threadIdx.x; i < end; i += 256)
        atomicAdd(&h[pairs[i] & (BINW - 1)], 1);
    __syncthreads();
    if (threadIdx.x < 64) {
        int lane = threadIdx.x;
        int v0 = h[lane], v1 = h[lane + 64];
        int s0 = v0, s1 = v1;
#pragma unroll
        for (int off = 1; off < 64; off <<= 1) {
            int u0 = __shfl_up(s0, off); if (lane >= off) s0 += u0;
            int u1 = __shfl_up(s1, off); if (lane >= off) s1 += u1;
        }
        int t0 = __shfl(s0, 63);
        curs[lane]      = beg + (s0 - v0);
        curs[lane + 64] = beg + (s1 - v1) + t0;
    }
    __syncthreads();
    int node = (blockIdx.x << BINW_SHIFT) + threadIdx.x;
    if (threadIdx.x < BINW && node < N_NODES) {
        nodeOfs[node] = curs[threadIdx.x];
        nd[node] = rsqrtf((float)max(h[threadIdx.x], 1));
        if (node == N_NODES - 1) nodeOfs[N_NODES] = end;
    }
    __syncthreads();
    for (int i = beg + (int)threadIdx.x; i < end; i += 256) {
        int p = pairs[i];
        int pos = atomicAdd(&curs[p & (BINW - 1)], 1);
        csr[pos] = p >> BINW_SHIFT;
    }
}

// ---------------------------------------------------------------------------
// xb[i] = bf16(ns[row] * x[i]) — pre-scaled bf16 copy of x for the gather.
// ---------------------------------------------------------------------------
__global__ __launch_bounds__(256) void xconv_kernel(
    const float* __restrict__ x, const float* __restrict__ ns,
    unsigned* __restrict__ xb)
{
    int idx = blockIdx.x * 256 + threadIdx.x;    // 8 elements per thread
    if (idx >= N_NODES * HF / 8) return;
    int row = idx >> 4;
    float c = ns[row];
    const float4* px = (const float4*)(x + (size_t)idx * 8);
    float4 v0 = px[0], v1 = px[1];
    uint4 o;
    o.x = pack2(c * v0.x, c * v0.y);
    o.y = pack2(c * v0.z, c * v0.w);
    o.z = pack2(c * v1.x, c * v1.y);
    o.w = pack2(c * v1.z, c * v1.w);
    *(uint4*)(xb + (size_t)idx * 4) = o;
}

// ---------------------------------------------------------------------------
// wt[layer][n][k] = bf16(W[layer][k][n]) — transposed bf16 weights (B^T).
// ---------------------------------------------------------------------------
__global__ __launch_bounds__(128) void wconv_kernel(
    const float* __restrict__ W0, const float* __restrict__ Ws,
    unsigned short* __restrict__ wt)
{
    const float* Wsrc = (blockIdx.x == 0) ? W0 : (Ws + (size_t)(blockIdx.x - 1) * HF * HF);
    unsigned short* dstp = wt + (size_t)blockIdx.x * HF * HF;
    int n = threadIdx.x;
    for (int k = 0; k < HF; k += 2) {
        float v0 = Wsrc[k * HF + n];
        float v1 = Wsrc[(k + 1) * HF + n];
        *(unsigned*)(dstp + n * HF + k) = pack2(v0, v1);
    }
}

// ---------------------------------------------------------------------------
// Aggregation: one wave per node. 4 lane-groups of 16; group g owns edge
// k+4*r+g; each lane loads uint4 = 8 bf16 feats (full 256B row per group in
// ONE instruction). 16-edge super-rounds: 4 independent predicated loads
// issued back-to-back (explicit staging array -> ~4-5 row fetches in flight
// per wave; avg degree 16 means one super-round covers a typical node).
// Group combine via shfl_xor(16|32); lanes 0-15 write one uint4 each.
// ---------------------------------------------------------------------------
__global__ __launch_bounds__(256) void agg_kernel(
    const unsigned short* __restrict__ hb, const int* __restrict__ csr,
    const int* __restrict__ nodeOfs, const float* __restrict__ nd,
    unsigned short* __restrict__ ab)
{
    int node = blockIdx.x * 4 + (threadIdx.x >> 6);
    if (node >= N_NODES) return;
    int lane = threadIdx.x & 63;
    int g   = lane >> 4;           // edge group 0..3
    int fl  = (lane & 15) * 8;     // 8 features per lane
    int beg = nodeOfs[node], end = nodeOfs[node + 1];

    float a0 = 0.f, a1 = 0.f, a2 = 0.f, a3 = 0.f;
    float a4 = 0.f, a5 = 0.f, a6 = 0.f, a7 = 0.f;
    for (int base = beg; base < end; base += 64) {
        int m = min(64, end - base);
        int sl = (lane < m) ? csr[base + lane] : 0;
#pragma unroll 1
        for (int k = 0; k < m; k += 16) {
            uint4 v[4];
#pragma unroll
            for (int r = 0; r < 4; ++r) {
                int kk = k + r * 4 + g;
                int sidx = __shfl(sl, kk);
                v[r] = make_uint4(0u, 0u, 0u, 0u);
                if (kk < m)
                    v[r] = *(const uint4*)(hb + (size_t)sidx * HF + fl);
            }
#pragma unroll
            for (int r = 0; r < 4; ++r) {
                a0 += blo(v[r].x); a1 += bhi(v[r].x);
                a2 += blo(v[r].y); a3 += bhi(v[r].y);
                a4 += blo(v[r].z); a5 += bhi(v[r].z);
                a6 += blo(v[r].w); a7 += bhi(v[r].w);
            }
        }
    }
#pragma unroll
    for (int off = 16; off <= 32; off <<= 1) {
        a0 += __shfl_xor(a0, off); a1 += __shfl_xor(a1, off);
        a2 += __shfl_xor(a2, off); a3 += __shfl_xor(a3, off);
        a4 += __shfl_xor(a4, off); a5 += __shfl_xor(a5, off);
        a6 += __shfl_xor(a6, off); a7 += __shfl_xor(a7, off);
    }
    if (lane < 16) {
        float mm = nd[node];
        uint4 o;
        o.x = pack2(a0 * mm, a1 * mm);
        o.y = pack2(a2 * mm, a3 * mm);
        o.z = pack2(a4 * mm, a5 * mm);
        o.w = pack2(a6 * mm, a7 * mm);
        *(uint4*)(ab + (size_t)node * HF + fl) = o;
    }
}

// ---------------------------------------------------------------------------
// MFMA GEMM (m97-verified structure): A [M][K] bf16, B = W^T [N][K] bf16,
// mfma_f32_16x16x32_bf16, C/D col=lane&15 row=(lane>>4)*4+reg. 128x128 tile,
// 8 waves. LDS XOR-swizzle byte^=((row&7)<<4). Fused epilogue.
//   MODE 0: t(f32)->out2(=ori=d_out); bf16 -> hb
//   MODE 1: bf16 -> hb
//   MODE 2: t(f32)->out2 (final)
// ---------------------------------------------------------------------------
template <int MODE>
__global__ __launch_bounds__(GEMM_THREADS) void gemm_fused(
    const unsigned short* __restrict__ A, const unsigned short* __restrict__ Wt,
    const float* __restrict__ bias, const float* __restrict__ lng,
    const float* __restrict__ lnb, const float* __restrict__ ori,
    const float* __restrict__ ns, unsigned short* __restrict__ hb,
    float* __restrict__ out2)
{
    __shared__ char smem[65536];   // sA [0,32K), sB [32K,64K)
    const int tid = threadIdx.x;
    const int row0 = blockIdx.x * MT;

#pragma unroll
    for (int i = 0; i < 4; ++i) {
        int ch = tid + i * 512;            // 16B chunk id, 0..2047
        int row = ch >> 4;
        uint4 v = ((const uint4*)Wt)[ch];
        *(uint4*)(smem + 32768 + ((ch * 16) ^ ((row & 7) << 4))) = v;
    }
#pragma unroll
    for (int i = 0; i < 4; ++i) {
        int ch = tid + i * 512;
        int row = ch >> 4;
        int grow = min(row0 + row, N_NODES - 1);
        uint4 v = *(const uint4*)(A + (size_t)grow * HF + (ch & 15) * 8);
        *(uint4*)(smem + ((ch * 16) ^ ((row & 7) << 4))) = v;
    }
    __syncthreads();

    const int w  = tid >> 6;
    const int l  = tid & 63;
    const int lo = l & 15;
    const int hi = l >> 4;
    const int arow = w * 16 + lo;

    f32x4 acc[8];
#pragma unroll
    for (int nt = 0; nt < 8; ++nt) acc[nt] = (f32x4){0.f, 0.f, 0.f, 0.f};

#pragma unroll
    for (int kk = 0; kk < 4; ++kk) {
        bf16x8 af = *(const bf16x8*)(smem +
            ((arow * 256 + kk * 64 + hi * 16) ^ ((arow & 7) << 4)));
#pragma unroll
        for (int nt = 0; nt < 8; ++nt) {
            int n = nt * 16 + lo;
            bf16x8 bfr = *(const bf16x8*)(smem + 32768 +
                ((n * 256 + kk * 64 + hi * 16) ^ ((n & 7) << 4)));
            acc[nt] = __builtin_amdgcn_mfma_f32_16x16x32_bf16(af, bfr, acc[nt], 0, 0, 0);
        }
    }

    float bia[8], gg[8], bb[8];
#pragma unroll
    for (int nt = 0; nt < 8; ++nt) {
        bia[nt] = bias[nt * 16 + lo];
        if constexpr (MODE != 2) {
            gg[nt] = lng[nt * 16 + lo];
            bb[nt] = lnb[nt * 16 + lo];
        }
    }

#pragma unroll
    for (int r = 0; r < 4; ++r) {
        const int row = row0 + w * 16 + hi * 4 + r;
        const bool ok = row < N_NODES;
        const int rowc = ok ? row : N_NODES - 1;
        float t[8];
        float s = 0.f, ssum = 0.f;
#pragma unroll
        for (int nt = 0; nt < 8; ++nt) {
            float v = acc[nt][r] + bia[nt];
            if constexpr (MODE != 0)
                v = fmaf(RESC, ori[(size_t)rowc * HF + nt * 16 + lo], v);
            t[nt] = v;
            s += v; ssum += v * v;
        }
        if constexpr (MODE == 0) {
            if (ok) {
#pragma unroll
                for (int nt = 0; nt < 8; ++nt)
                    out2[(size_t)row * HF + nt * 16 + lo] = t[nt];
            }
        }
        if constexpr (MODE == 2) {
            if (ok) {
#pragma unroll
                for (int nt = 0; nt < 8; ++nt)
                    out2[(size_t)row * HF + nt * 16 + lo] = t[nt];
            }
        } else {
#pragma unroll
            for (int m = 8; m >= 1; m >>= 1) {
                s    += __shfl_xor(s, m);
                ssum += __shfl_xor(ssum, m);
            }
            float mu   = s * (1.0f / HF);
            float var  = ssum * (1.0f / HF) - mu * mu;
            float rinv = rsqrtf(var + LN_EPS);
            float nsr  = ns[rowc];
            if (ok) {
#pragma unroll
                for (int nt = 0; nt < 8; ++nt) {
                    float y = nsr * fmaxf(0.f, (t[nt] - mu) * rinv * gg[nt] + bb[nt]);
                    hb[(size_t)row * HF + nt * 16 + lo] = (unsigned short)f2b(y);
                }
            }
        }
    }
}

// ---------------------------------------------------------------------------
extern "C" void kernel_launch(void* const* d_in, const int* in_sizes, int n_in,
                              void* d_out, int out_size, void* d_ws, size_t ws_size,
                              hipStream_t stream)
{
    const float* x   = (const float*)d_in[0];
    const float* W0  = (const float*)d_in[1];
    const float* Ws  = (const float*)d_in[2];
    const float* b   = (const float*)d_in[3];
    const float* lng = (const float*)d_in[4];
    const float* lnb = (const float*)d_in[5];
    const int*   src = (const int*)d_in[6];
    const int*   dst = (const int*)d_in[7];
    float* out = (float*)d_out;

    // workspace layout, total ~99.5 MB; everything written before read.
    char* ws = (char*)d_ws;
    int*   histD     = (int*)(ws + 0);            // NBIN*NCHUNK ints
    int*   histS     = (int*)(ws + 307200);
    int*   rowTotD   = (int*)(ws + 614400);
    int*   rowTotS   = (int*)(ws + 617984);
    int*   rowBaseD  = (int*)(ws + 621568);
    int*   rowBaseS  = (int*)(ws + 625152);
    int*   binOfs    = (int*)(ws + 628736);
    int*   srcbinOfs = (int*)(ws + 632320);
    float* ns        = (float*)(ws + 635904);
    float* nd        = (float*)(ws + 1036288);
    int*   nodeOfs   = (int*)(ws + 1436672);
    unsigned short* dstrank = (unsigned short*)(ws + 1837056);
    unsigned short* srcrank = (unsigned short*)(ws + 5037056);
    int*   pairs     = (int*)(ws + 8237056);
    unsigned char* sbytes = (unsigned char*)(ws + 14637056);
    int*   csr       = (int*)(ws + 16237056);
    unsigned*       xb = (unsigned*)(ws + 22637056);        // N*128 bf16
    unsigned short* hb = (unsigned short*)(ws + 48237056);  // N*128 bf16
    unsigned short* ab = (unsigned short*)(ws + 73837056);  // N*128 bf16 (agg)
    unsigned short* wt = (unsigned short*)(ws + 99437056);  // 3*128*128 bf16

    histrank_kernel<<<NCHUNK, 1024, 0, stream>>>(src, dst, histD, histS, dstrank, srcrank);
    scanA_kernel<<<(2 * NBIN + 3) / 4, 256, 0, stream>>>(histD, histS, rowTotD, rowTotS);
    scanB_kernel<<<1, 1024, 0, stream>>>(rowTotD, rowTotS, rowBaseD, rowBaseS, binOfs, srcbinOfs);
    scatter_kernel<<<NCHUNK, 1024, 0, stream>>>(src, dst, dstrank, srcrank,
                                                histD, histS, rowBaseD, rowBaseS,
                                                pairs, sbytes);
    srccount_kernel<<<NBIN, 256, 0, stream>>>(sbytes, srcbinOfs, ns);
    csrbuild_kernel<<<NBIN, 256, 0, stream>>>(pairs, binOfs, nd, nodeOfs, csr);
    wconv_kernel<<<3, 128, 0, stream>>>(W0, Ws, wt);
    xconv_kernel<<<(N_NODES * HF / 8 + 255) / 256, 256, 0, stream>>>(x, ns, xb);

    const int gemm_grid = (N_NODES + MT - 1) / MT;   // 782

    // layer 0
    agg_kernel<<<(N_NODES + 3) / 4, 256, 0, stream>>>(
        (const unsigned short*)xb, csr, nodeOfs, nd, ab);
    gemm_fused<0><<<gemm_grid, GEMM_THREADS, 0, stream>>>(
        ab, wt, b, lng + HF, lnb + HF, nullptr, ns, hb, out);

    // layer 1
    agg_kernel<<<(N_NODES + 3) / 4, 256, 0, stream>>>(hb, csr, nodeOfs, nd, ab);
    gemm_fused<1><<<gemm_grid, GEMM_THREADS, 0, stream>>>(
        ab, wt + HF * HF, b + HF, lng + 2 * HF, lnb + 2 * HF, out, ns, hb, nullptr);

    // layer 2
    agg_kernel<<<(N_NODES + 3) / 4, 256, 0, stream>>>(hb, csr, nodeOfs, nd, ab);
    gemm_fused<2><<<gemm_grid, GEMM_THREADS, 0, stream>>>(
        ab, wt + 2 * HF * HF, b + 2 * HF, nullptr, nullptr, out, ns, nullptr, out);
}

// Round 11
// 315.986 us; speedup vs baseline: 3.7118x; 1.0144x over previous
//
#include <hip/hip_runtime.h>

// Problem constants (fixed by the reference)
#define N_NODES 100000
#define N_EDGES 1600000
#define HF      128
#define RESC    0.5f
#define LN_EPS  1e-5f

#define BINW_SHIFT 7
#define BINW       128
#define NBIN       ((N_NODES + BINW - 1) >> BINW_SHIFT)   // 782
#define HCHUNK     16384
#define NCHUNK     ((N_EDGES + HCHUNK - 1) / HCHUNK)      // 98

#define GEMM_THREADS 512
#define MT  128             // rows per GEMM block

typedef __attribute__((ext_vector_type(8))) short bf16x8;  // MFMA A/B frag
typedef __attribute__((ext_vector_type(4))) float f32x4;   // MFMA C/D frag

// bf16 helpers (round-to-nearest-even)
static __device__ __forceinline__ unsigned f2b(float f) {
    unsigned u = __float_as_uint(f);
    return (u + 0x7FFFu + ((u >> 16) & 1u)) >> 16;
}
static __device__ __forceinline__ unsigned pack2(float a, float b) {
    return f2b(a) | (f2b(b) << 16);
}
static __device__ __forceinline__ float b2f(unsigned short u) {
    return __uint_as_float(((unsigned)u) << 16);
}
static __device__ __forceinline__ float blo(unsigned u) {
    return __uint_as_float(u << 16);
}
static __device__ __forceinline__ float bhi(unsigned u) {
    return __uint_as_float(u & 0xFFFF0000u);
}

// ---------------------------------------------------------------------------
// Counting-sort pass 1: per-chunk LDS bin histograms (dst & src). The LDS
// atomic's RETURN VALUE is the edge's intra-chunk intra-bin rank -> stored.
// ---------------------------------------------------------------------------
__global__ __launch_bounds__(1024) void histrank_kernel(
    const int* __restrict__ src, const int* __restrict__ dst,
    int* __restrict__ histD, int* __restrict__ histS,
    unsigned short* __restrict__ dstrank, unsigned short* __restrict__ srcrank)
{
    __shared__ int hd[NBIN], hs[NBIN];
    for (int i = threadIdx.x; i < NBIN; i += 1024) { hd[i] = 0; hs[i] = 0; }
    __syncthreads();
    int base = blockIdx.x * HCHUNK;
    int lim = min(base + HCHUNK, N_EDGES);
    for (int e = base + (int)threadIdx.x; e < lim; e += 1024) {
        int d = dst[e], s = src[e];
        int rd = atomicAdd(&hd[d >> BINW_SHIFT], 1);
        int rs = atomicAdd(&hs[s >> BINW_SHIFT], 1);
        dstrank[e] = (unsigned short)rd;
        srcrank[e] = (unsigned short)rs;
    }
    __syncthreads();
    for (int i = threadIdx.x; i < NBIN; i += 1024) {
        histD[i * NCHUNK + blockIdx.x] = hd[i];
        histS[i * NCHUNK + blockIdx.x] = hs[i];
    }
}

// ---------------------------------------------------------------------------
// Pass 2a: exclusive scan WITHIN each bin across its 98 chunk counts.
// ---------------------------------------------------------------------------
__global__ __launch_bounds__(256) void scanA_kernel(
    int* __restrict__ histD, int* __restrict__ histS,
    int* __restrict__ rowTotD, int* __restrict__ rowTotS)
{
    int row = blockIdx.x * 4 + ((int)threadIdx.x >> 6);
    int lane = threadIdx.x & 63;
    if (row >= 2 * NBIN) return;
    int* h = (row < NBIN) ? (histD + row * NCHUNK) : (histS + (row - NBIN) * NCHUNK);
    int v0 = h[lane];
    int v1 = (64 + lane < NCHUNK) ? h[64 + lane] : 0;
    int s0 = v0, s1 = v1;
#pragma unroll
    for (int off = 1; off < 64; off <<= 1) {
        int u0 = __shfl_up(s0, off); if (lane >= off) s0 += u0;
        int u1 = __shfl_up(s1, off); if (lane >= off) s1 += u1;
    }
    int c = __shfl(s0, 63);
    h[lane] = s0 - v0;
    if (64 + lane < NCHUNK) h[64 + lane] = c + s1 - v1;
    int tot = c + __shfl(s1, 63);
    if (lane == 0) {
        if (row < NBIN) rowTotD[row] = tot;
        else            rowTotS[row - NBIN] = tot;
    }
}

// ---------------------------------------------------------------------------
// Pass 2b: single-block exclusive scan over the 782 bin totals (both sides).
// ---------------------------------------------------------------------------
__global__ __launch_bounds__(1024) void scanB_kernel(
    const int* __restrict__ rowTotD, const int* __restrict__ rowTotS,
    int* __restrict__ rowBaseD, int* __restrict__ rowBaseS,
    int* __restrict__ binOfs, int* __restrict__ srcbinOfs)
{
    __shared__ int wsum[16];
    for (int side = 0; side < 2; ++side) {
        const int* cnt = side ? rowTotS : rowTotD;
        int* base = side ? rowBaseS : rowBaseD;
        int* ofs  = side ? srcbinOfs : binOfs;
        int b = threadIdx.x;
        int tot = (b < NBIN) ? cnt[b] : 0;
        int lane = threadIdx.x & 63, wid = threadIdx.x >> 6;
        int x = tot;
#pragma unroll
        for (int off = 1; off < 64; off <<= 1) { int u = __shfl_up(x, off); if (lane >= off) x += u; }
        if (lane == 63) wsum[wid] = x;
        __syncthreads();
        if (wid == 0) {
            int y = (lane < 16) ? wsum[lane] : 0;
#pragma unroll
            for (int off = 1; off < 16; off <<= 1) { int u = __shfl_up(y, off); if (lane >= off) y += u; }
            if (lane < 16) wsum[lane] = y;
        }
        __syncthreads();
        int incl = x + (wid > 0 ? wsum[wid - 1] : 0);
        if (b < NBIN) {
            base[b] = incl - tot;
            ofs[b + 1] = incl;
            if (b == 0) ofs[0] = 0;
        }
        __syncthreads();
    }
}

// ---------------------------------------------------------------------------
// Counting-sort pass 3: deterministic scatter, no atomics.
// ---------------------------------------------------------------------------
__global__ __launch_bounds__(1024) void scatter_kernel(
    const int* __restrict__ src, const int* __restrict__ dst,
    const unsigned short* __restrict__ dstrank, const unsigned short* __restrict__ srcrank,
    const int* __restrict__ histD, const int* __restrict__ histS,
    const int* __restrict__ rowBaseD, const int* __restrict__ rowBaseS,
    int* __restrict__ pairs, unsigned char* __restrict__ sbytes)
{
    __shared__ int baseD[NBIN], baseS[NBIN];
    for (int i = threadIdx.x; i < NBIN; i += 1024) {
        baseD[i] = rowBaseD[i] + histD[i * NCHUNK + blockIdx.x];
        baseS[i] = rowBaseS[i] + histS[i * NCHUNK + blockIdx.x];
    }
    __syncthreads();
    int base = blockIdx.x * HCHUNK;
    int lim = min(base + HCHUNK, N_EDGES);
    for (int e = base + (int)threadIdx.x; e < lim; e += 1024) {
        int d = dst[e], s = src[e];
        pairs[baseD[d >> BINW_SHIFT] + dstrank[e]] = (s << BINW_SHIFT) | (d & (BINW - 1));
        sbytes[baseS[s >> BINW_SHIFT] + srcrank[e]] = (unsigned char)(s & (BINW - 1));
    }
}

// ---------------------------------------------------------------------------
// Src side finisher: per-bin LDS histogram of sloc bytes -> ns directly.
// ---------------------------------------------------------------------------
__global__ __launch_bounds__(256) void srccount_kernel(
    const unsigned char* __restrict__ sbytes, const int* __restrict__ srcbinOfs,
    float* __restrict__ ns)
{
    __shared__ int h[BINW];
    if (threadIdx.x < BINW) h[threadIdx.x] = 0;
    __syncthreads();
    int beg = srcbinOfs[blockIdx.x], end = srcbinOfs[blockIdx.x + 1];
    for (int i = beg + (int)threadIdx.x; i < end; i += 256)
        atomicAdd(&h[sbytes[i] & (BINW - 1)], 1);
    __syncthreads();
    int node = (blockIdx.x << BINW_SHIFT) + threadIdx.x;
    if (threadIdx.x < BINW && node < N_NODES)
        ns[node] = rsqrtf((float)max(h[threadIdx.x], 1));
}

// ---------------------------------------------------------------------------
// Dst side finisher: per-bin LDS histogram -> intra-bin prefix -> nodeOfs +
// nd, then CSR scatter via LDS cursors into the bin's L2-hot window.
// ---------------------------------------------------------------------------
__global__ __launch_bounds__(256) void csrbuild_kernel(
    const int* __restrict__ pairs, const int* __restrict__ binOfs,
    float* __restrict__ nd, int* __restrict__ nodeOfs, int* __restrict__ csr)
{
    __shared__ int h[BINW];
    __shared__ int curs[BINW];
    if (threadIdx.x < BINW) h[threadIdx.x] = 0;
    __syncthreads();
    int beg = binOfs[blockIdx.x], end = binOfs[blockIdx.x + 1];
    for (int i = beg + (int)threadIdx.x; i < end; i += 256)
        atomicAdd(&h[pairs[i] & (BINW - 1)], 1);
    __syncthreads();
    if (threadIdx.x < 64) {
        int lane = threadIdx.x;
        int v0 = h[lane], v1 = h[lane + 64];
        int s0 = v0, s1 = v1;
#pragma unroll
        for (int off = 1; off < 64; off <<= 1) {
            int u0 = __shfl_up(s0, off); if (lane >= off) s0 += u0;
            int u1 = __shfl_up(s1, off); if (lane >= off) s1 += u1;
        }
        int t0 = __shfl(s0, 63);
        curs[lane]      = beg + (s0 - v0);
        curs[lane + 64] = beg + (s1 - v1) + t0;
    }
    __syncthreads();
    int node = (blockIdx.x << BINW_SHIFT) + threadIdx.x;
    if (threadIdx.x < BINW && node < N_NODES) {
        nodeOfs[node] = curs[threadIdx.x];
        nd[node] = rsqrtf((float)max(h[threadIdx.x], 1));
        if (node == N_NODES - 1) nodeOfs[N_NODES] = end;
    }
    __syncthreads();
    for (int i = beg + (int)threadIdx.x; i < end; i += 256) {
        int p = pairs[i];
        int pos = atomicAdd(&curs[p & (BINW - 1)], 1);
        csr[pos] = p >> BINW_SHIFT;
    }
}

// ---------------------------------------------------------------------------
// xb[i] = bf16(ns[row] * x[i]) — pre-scaled bf16 copy of x for the gather.
// ---------------------------------------------------------------------------
__global__ __launch_bounds__(256) void xconv_kernel(
    const float* __restrict__ x, const float* __restrict__ ns,
    unsigned* __restrict__ xb)
{
    int idx = blockIdx.x * 256 + threadIdx.x;    // 8 elements per thread
    if (idx >= N_NODES * HF / 8) return;
    int row = idx >> 4;
    float c = ns[row];
    const float4* px = (const float4*)(x + (size_t)idx * 8);
    float4 v0 = px[0], v1 = px[1];
    uint4 o;
    o.x = pack2(c * v0.x, c * v0.y);
    o.y = pack2(c * v0.z, c * v0.w);
    o.z = pack2(c * v1.x, c * v1.y);
    o.w = pack2(c * v1.z, c * v1.w);
    *(uint4*)(xb + (size_t)idx * 4) = o;
}

// ---------------------------------------------------------------------------
// wt[layer][n][k] = bf16(W[layer][k][n]) — transposed bf16 weights (B^T).
// ---------------------------------------------------------------------------
__global__ __launch_bounds__(128) void wconv_kernel(
    const float* __restrict__ W0, const float* __restrict__ Ws,
    unsigned short* __restrict__ wt)
{
    const float* Wsrc = (blockIdx.x == 0) ? W0 : (Ws + (size_t)(blockIdx.x - 1) * HF * HF);
    unsigned short* dstp = wt + (size_t)blockIdx.x * HF * HF;
    int n = threadIdx.x;
    for (int k = 0; k < HF; k += 2) {
        float v0 = Wsrc[k * HF + n];
        float v1 = Wsrc[(k + 1) * HF + n];
        *(unsigned*)(dstp + n * HF + k) = pack2(v0, v1);
    }
}

// ---------------------------------------------------------------------------
// Aggregation: one wave per node. 4 lane-groups of 16; group g owns edge
// k+4*r+g; each lane loads uint4 = 8 bf16 feats (full 256B row per group in
// ONE instruction). 32-edge super-rounds: 8 independent predicated loads
// issued back-to-back (explicit staging array -> ~8 row fetches in flight
// per wave; avg degree 16 -> one super-round covers a typical node 2x over).
// Group combine via shfl_xor(16|32); lanes 0-15 write one uint4 each.
// ---------------------------------------------------------------------------
__global__ __launch_bounds__(256) void agg_kernel(
    const unsigned short* __restrict__ hb, const int* __restrict__ csr,
    const int* __restrict__ nodeOfs, const float* __restrict__ nd,
    unsigned short* __restrict__ ab)
{
    int node = blockIdx.x * 4 + (threadIdx.x >> 6);
    if (node >= N_NODES) return;
    int lane = threadIdx.x & 63;
    int g   = lane >> 4;           // edge group 0..3
    int fl  = (lane & 15) * 8;     // 8 features per lane
    int beg = nodeOfs[node], end = nodeOfs[node + 1];

    float a0 = 0.f, a1 = 0.f, a2 = 0.f, a3 = 0.f;
    float a4 = 0.f, a5 = 0.f, a6 = 0.f, a7 = 0.f;
    for (int base = beg; base < end; base += 64) {
        int m = min(64, end - base);
        int sl = (lane < m) ? csr[base + lane] : 0;
#pragma unroll 1
        for (int k = 0; k < m; k += 32) {
            uint4 v[8];
#pragma unroll
            for (int r = 0; r < 8; ++r) {
                int kk = k + r * 4 + g;
                int sidx = __shfl(sl, kk);
                v[r] = make_uint4(0u, 0u, 0u, 0u);
                if (kk < m)
                    v[r] = *(const uint4*)(hb + (size_t)sidx * HF + fl);
            }
#pragma unroll
            for (int r = 0; r < 8; ++r) {
                a0 += blo(v[r].x); a1 += bhi(v[r].x);
                a2 += blo(v[r].y); a3 += bhi(v[r].y);
                a4 += blo(v[r].z); a5 += bhi(v[r].z);
                a6 += blo(v[r].w); a7 += bhi(v[r].w);
            }
        }
    }
#pragma unroll
    for (int off = 16; off <= 32; off <<= 1) {
        a0 += __shfl_xor(a0, off); a1 += __shfl_xor(a1, off);
        a2 += __shfl_xor(a2, off); a3 += __shfl_xor(a3, off);
        a4 += __shfl_xor(a4, off); a5 += __shfl_xor(a5, off);
        a6 += __shfl_xor(a6, off); a7 += __shfl_xor(a7, off);
    }
    if (lane < 16) {
        float mm = nd[node];
        uint4 o;
        o.x = pack2(a0 * mm, a1 * mm);
        o.y = pack2(a2 * mm, a3 * mm);
        o.z = pack2(a4 * mm, a5 * mm);
        o.w = pack2(a6 * mm, a7 * mm);
        *(uint4*)(ab + (size_t)node * HF + fl) = o;
    }
}

// ---------------------------------------------------------------------------
// MFMA GEMM (m97-verified structure): A [M][K] bf16, B = W^T [N][K] bf16,
// mfma_f32_16x16x32_bf16, C/D col=lane&15 row=(lane>>4)*4+reg. 128x128 tile,
// 8 waves. LDS XOR-swizzle byte^=((row&7)<<4). Fused epilogue.
// ori ("obf") is stored/read as BF16 to halve residual traffic.
//   MODE 0: bf16(t) -> obf; LN/ReLU/ns -> hb
//   MODE 1: t += 0.5*obf; LN/ReLU/ns -> hb
//   MODE 2: t += 0.5*obf; t(f32) -> out2 (final d_out)
// ---------------------------------------------------------------------------
template <int MODE>
__global__ __launch_bounds__(GEMM_THREADS) void gemm_fused(
    const unsigned short* __restrict__ A, const unsigned short* __restrict__ Wt,
    const float* __restrict__ bias, const float* __restrict__ lng,
    const float* __restrict__ lnb, unsigned short* __restrict__ obf,
    const float* __restrict__ ns, unsigned short* __restrict__ hb,
    float* __restrict__ out2)
{
    __shared__ char smem[65536];   // sA [0,32K), sB [32K,64K)
    const int tid = threadIdx.x;
    const int row0 = blockIdx.x * MT;

#pragma unroll
    for (int i = 0; i < 4; ++i) {
        int ch = tid + i * 512;            // 16B chunk id, 0..2047
        int row = ch >> 4;
        uint4 v = ((const uint4*)Wt)[ch];
        *(uint4*)(smem + 32768 + ((ch * 16) ^ ((row & 7) << 4))) = v;
    }
#pragma unroll
    for (int i = 0; i < 4; ++i) {
        int ch = tid + i * 512;
        int row = ch >> 4;
        int grow = min(row0 + row, N_NODES - 1);
        uint4 v = *(const uint4*)(A + (size_t)grow * HF + (ch & 15) * 8);
        *(uint4*)(smem + ((ch * 16) ^ ((row & 7) << 4))) = v;
    }
    __syncthreads();

    const int w  = tid >> 6;
    const int l  = tid & 63;
    const int lo = l & 15;
    const int hi = l >> 4;
    const int arow = w * 16 + lo;

    f32x4 acc[8];
#pragma unroll
    for (int nt = 0; nt < 8; ++nt) acc[nt] = (f32x4){0.f, 0.f, 0.f, 0.f};

#pragma unroll
    for (int kk = 0; kk < 4; ++kk) {
        bf16x8 af = *(const bf16x8*)(smem +
            ((arow * 256 + kk * 64 + hi * 16) ^ ((arow & 7) << 4)));
#pragma unroll
        for (int nt = 0; nt < 8; ++nt) {
            int n = nt * 16 + lo;
            bf16x8 bfr = *(const bf16x8*)(smem + 32768 +
                ((n * 256 + kk * 64 + hi * 16) ^ ((n & 7) << 4)));
            acc[nt] = __builtin_amdgcn_mfma_f32_16x16x32_bf16(af, bfr, acc[nt], 0, 0, 0);
        }
    }

    float bia[8], gg[8], bb[8];
#pragma unroll
    for (int nt = 0; nt < 8; ++nt) {
        bia[nt] = bias[nt * 16 + lo];
        if constexpr (MODE != 2) {
            gg[nt] = lng[nt * 16 + lo];
            bb[nt] = lnb[nt * 16 + lo];
        }
    }

#pragma unroll
    for (int r = 0; r < 4; ++r) {
        const int row = row0 + w * 16 + hi * 4 + r;
        const bool ok = row < N_NODES;
        const int rowc = ok ? row : N_NODES - 1;
        float t[8];
        float s = 0.f, ssum = 0.f;
#pragma unroll
        for (int nt = 0; nt < 8; ++nt) {
            float v = acc[nt][r] + bia[nt];
            if constexpr (MODE != 0)
                v = fmaf(RESC, b2f(obf[(size_t)rowc * HF + nt * 16 + lo]), v);
            t[nt] = v;
            s += v; ssum += v * v;
        }
        if constexpr (MODE == 0) {
            if (ok) {
#pragma unroll
                for (int nt = 0; nt < 8; ++nt)
                    obf[(size_t)row * HF + nt * 16 + lo] = (unsigned short)f2b(t[nt]);
            }
        }
        if constexpr (MODE == 2) {
            if (ok) {
#pragma unroll
                for (int nt = 0; nt < 8; ++nt)
                    out2[(size_t)row * HF + nt * 16 + lo] = t[nt];
            }
        } else {
#pragma unroll
            for (int m = 8; m >= 1; m >>= 1) {
                s    += __shfl_xor(s, m);
                ssum += __shfl_xor(ssum, m);
            }
            float mu   = s * (1.0f / HF);
            float var  = ssum * (1.0f / HF) - mu * mu;
            float rinv = rsqrtf(var + LN_EPS);
            float nsr  = ns[rowc];
            if (ok) {
#pragma unroll
                for (int nt = 0; nt < 8; ++nt) {
                    float y = nsr * fmaxf(0.f, (t[nt] - mu) * rinv * gg[nt] + bb[nt]);
                    hb[(size_t)row * HF + nt * 16 + lo] = (unsigned short)f2b(y);
                }
            }
        }
    }
}

// ---------------------------------------------------------------------------
extern "C" void kernel_launch(void* const* d_in, const int* in_sizes, int n_in,
                              void* d_out, int out_size, void* d_ws, size_t ws_size,
                              hipStream_t stream)
{
    const float* x   = (const float*)d_in[0];
    const float* W0  = (const float*)d_in[1];
    const float* Ws  = (const float*)d_in[2];
    const float* b   = (const float*)d_in[3];
    const float* lng = (const float*)d_in[4];
    const float* lnb = (const float*)d_in[5];
    const int*   src = (const int*)d_in[6];
    const int*   dst = (const int*)d_in[7];
    float* out = (float*)d_out;

    // workspace layout, total ~125.1 MB; everything written before read.
    char* ws = (char*)d_ws;
    int*   histD     = (int*)(ws + 0);            // NBIN*NCHUNK ints
    int*   histS     = (int*)(ws + 307200);
    int*   rowTotD   = (int*)(ws + 614400);
    int*   rowTotS   = (int*)(ws + 617984);
    int*   rowBaseD  = (int*)(ws + 621568);
    int*   rowBaseS  = (int*)(ws + 625152);
    int*   binOfs    = (int*)(ws + 628736);
    int*   srcbinOfs = (int*)(ws + 632320);
    float* ns        = (float*)(ws + 635904);
    float* nd        = (float*)(ws + 1036288);
    int*   nodeOfs   = (int*)(ws + 1436672);
    unsigned short* dstrank = (unsigned short*)(ws + 1837056);
    unsigned short* srcrank = (unsigned short*)(ws + 5037056);
    int*   pairs     = (int*)(ws + 8237056);
    unsigned char* sbytes = (unsigned char*)(ws + 14637056);
    int*   csr       = (int*)(ws + 16237056);
    unsigned*       xb  = (unsigned*)(ws + 22637056);        // N*128 bf16
    unsigned short* hb  = (unsigned short*)(ws + 48237056);  // N*128 bf16
    unsigned short* ab  = (unsigned short*)(ws + 73837056);  // N*128 bf16 (agg)
    unsigned short* wt  = (unsigned short*)(ws + 99437056);  // 3*128*128 bf16
    unsigned short* obf = (unsigned short*)(ws + 99535360);  // N*128 bf16 (ori)

    histrank_kernel<<<NCHUNK, 1024, 0, stream>>>(src, dst, histD, histS, dstrank, srcrank);
    scanA_kernel<<<(2 * NBIN + 3) / 4, 256, 0, stream>>>(histD, histS, rowTotD, rowTotS);
    scanB_kernel<<<1, 1024, 0, stream>>>(rowTotD, rowTotS, rowBaseD, rowBaseS, binOfs, srcbinOfs);
    scatter_kernel<<<NCHUNK, 1024, 0, stream>>>(src, dst, dstrank, srcrank,
                                                histD, histS, rowBaseD, rowBaseS,
                                                pairs, sbytes);
    srccount_kernel<<<NBIN, 256, 0, stream>>>(sbytes, srcbinOfs, ns);
    csrbuild_kernel<<<NBIN, 256, 0, stream>>>(pairs, binOfs, nd, nodeOfs, csr);
    wconv_kernel<<<3, 128, 0, stream>>>(W0, Ws, wt);
    xconv_kernel<<<(N_NODES * HF / 8 + 255) / 256, 256, 0, stream>>>(x, ns, xb);

    const int gemm_grid = (N_NODES + MT - 1) / MT;   // 782

    // layer 0
    agg_kernel<<<(N_NODES + 3) / 4, 256, 0, stream>>>(
        (const unsigned short*)xb, csr, nodeOfs, nd, ab);
    gemm_fused<0><<<gemm_grid, GEMM_THREADS, 0, stream>>>(
        ab, wt, b, lng + HF, lnb + HF, obf, ns, hb, nullptr);

    // layer 1
    agg_kernel<<<(N_NODES + 3) / 4, 256, 0, stream>>>(hb, csr, nodeOfs, nd, ab);
    gemm_fused<1><<<gemm_grid, GEMM_THREADS, 0, stream>>>(
        ab, wt + HF * HF, b + HF, lng + 2 * HF, lnb + 2 * HF, obf, ns, hb, nullptr);

    // layer 2
    agg_kernel<<<(N_NODES + 3) / 4, 256, 0, stream>>>(hb, csr, nodeOfs, nd, ab);
    gemm_fused<2><<<gemm_grid, GEMM_THREADS, 0, stream>>>(
        ab, wt + 2 * HF * HF, b + 2 * HF, nullptr, nullptr, obf, ns, nullptr, out);
}

// Round 13
// 315.545 us; speedup vs baseline: 3.7170x; 1.0014x over previous
//
#include <hip/hip_runtime.h>

// Problem constants (fixed by the reference)
#define N_NODES 100000
#define N_EDGES 1600000
#define HF      128
#define RESC    0.5f
#define LN_EPS  1e-5f

#define BINW_SHIFT 7
#define BINW       128
#define NBIN       ((N_NODES + BINW - 1) >> BINW_SHIFT)   // 782
#define HCHUNK     16384
#define NCHUNK     ((N_EDGES + HCHUNK - 1) / HCHUNK)      // 98

#define GEMM_THREADS 512
#define MT  128             // rows per GEMM block

typedef __attribute__((ext_vector_type(8))) short bf16x8;  // MFMA A/B frag
typedef __attribute__((ext_vector_type(4))) float f32x4;   // MFMA C/D frag

// bf16 helpers (round-to-nearest-even)
static __device__ __forceinline__ unsigned f2b(float f) {
    unsigned u = __float_as_uint(f);
    return (u + 0x7FFFu + ((u >> 16) & 1u)) >> 16;
}
static __device__ __forceinline__ unsigned pack2(float a, float b) {
    return f2b(a) | (f2b(b) << 16);
}
static __device__ __forceinline__ float b2f(unsigned short u) {
    return __uint_as_float(((unsigned)u) << 16);
}
static __device__ __forceinline__ float blo(unsigned u) {
    return __uint_as_float(u << 16);
}
static __device__ __forceinline__ float bhi(unsigned u) {
    return __uint_as_float(u & 0xFFFF0000u);
}

// ---------------------------------------------------------------------------
// Counting-sort pass 1: per-chunk LDS bin histograms (dst & src). The LDS
// atomic's RETURN VALUE is the edge's intra-chunk intra-bin rank -> stored.
// ---------------------------------------------------------------------------
__global__ __launch_bounds__(1024) void histrank_kernel(
    const int* __restrict__ src, const int* __restrict__ dst,
    int* __restrict__ histD, int* __restrict__ histS,
    unsigned short* __restrict__ dstrank, unsigned short* __restrict__ srcrank)
{
    __shared__ int hd[NBIN], hs[NBIN];
    for (int i = threadIdx.x; i < NBIN; i += 1024) { hd[i] = 0; hs[i] = 0; }
    __syncthreads();
    int base = blockIdx.x * HCHUNK;
    int lim = min(base + HCHUNK, N_EDGES);
    for (int e = base + (int)threadIdx.x; e < lim; e += 1024) {
        int d = dst[e], s = src[e];
        int rd = atomicAdd(&hd[d >> BINW_SHIFT], 1);
        int rs = atomicAdd(&hs[s >> BINW_SHIFT], 1);
        dstrank[e] = (unsigned short)rd;
        srcrank[e] = (unsigned short)rs;
    }
    __syncthreads();
    for (int i = threadIdx.x; i < NBIN; i += 1024) {
        histD[i * NCHUNK + blockIdx.x] = hd[i];
        histS[i * NCHUNK + blockIdx.x] = hs[i];
    }
}

// ---------------------------------------------------------------------------
// Pass 2a: exclusive scan WITHIN each bin across its 98 chunk counts.
// ---------------------------------------------------------------------------
__global__ __launch_bounds__(256) void scanA_kernel(
    int* __restrict__ histD, int* __restrict__ histS,
    int* __restrict__ rowTotD, int* __restrict__ rowTotS)
{
    int row = blockIdx.x * 4 + ((int)threadIdx.x >> 6);
    int lane = threadIdx.x & 63;
    if (row >= 2 * NBIN) return;
    int* h = (row < NBIN) ? (histD + row * NCHUNK) : (histS + (row - NBIN) * NCHUNK);
    int v0 = h[lane];
    int v1 = (64 + lane < NCHUNK) ? h[64 + lane] : 0;
    int s0 = v0, s1 = v1;
#pragma unroll
    for (int off = 1; off < 64; off <<= 1) {
        int u0 = __shfl_up(s0, off); if (lane >= off) s0 += u0;
        int u1 = __shfl_up(s1, off); if (lane >= off) s1 += u1;
    }
    int c = __shfl(s0, 63);
    h[lane] = s0 - v0;
    if (64 + lane < NCHUNK) h[64 + lane] = c + s1 - v1;
    int tot = c + __shfl(s1, 63);
    if (lane == 0) {
        if (row < NBIN) rowTotD[row] = tot;
        else            rowTotS[row - NBIN] = tot;
    }
}

// ---------------------------------------------------------------------------
// Pass 2b: single-block exclusive scan over the 782 bin totals (both sides).
// ---------------------------------------------------------------------------
__global__ __launch_bounds__(1024) void scanB_kernel(
    const int* __restrict__ rowTotD, const int* __restrict__ rowTotS,
    int* __restrict__ rowBaseD, int* __restrict__ rowBaseS,
    int* __restrict__ binOfs, int* __restrict__ srcbinOfs)
{
    __shared__ int wsum[16];
    for (int side = 0; side < 2; ++side) {
        const int* cnt = side ? rowTotS : rowTotD;
        int* base = side ? rowBaseS : rowBaseD;
        int* ofs  = side ? srcbinOfs : binOfs;
        int b = threadIdx.x;
        int tot = (b < NBIN) ? cnt[b] : 0;
        int lane = threadIdx.x & 63, wid = threadIdx.x >> 6;
        int x = tot;
#pragma unroll
        for (int off = 1; off < 64; off <<= 1) { int u = __shfl_up(x, off); if (lane >= off) x += u; }
        if (lane == 63) wsum[wid] = x;
        __syncthreads();
        if (wid == 0) {
            int y = (lane < 16) ? wsum[lane] : 0;
#pragma unroll
            for (int off = 1; off < 16; off <<= 1) { int u = __shfl_up(y, off); if (lane >= off) y += u; }
            if (lane < 16) wsum[lane] = y;
        }
        __syncthreads();
        int incl = x + (wid > 0 ? wsum[wid - 1] : 0);
        if (b < NBIN) {
            base[b] = incl - tot;
            ofs[b + 1] = incl;
            if (b == 0) ofs[0] = 0;
        }
        __syncthreads();
    }
}

// ---------------------------------------------------------------------------
// Counting-sort pass 3: deterministic scatter, no atomics.
// ---------------------------------------------------------------------------
__global__ __launch_bounds__(1024) void scatter_kernel(
    const int* __restrict__ src, const int* __restrict__ dst,
    const unsigned short* __restrict__ dstrank, const unsigned short* __restrict__ srcrank,
    const int* __restrict__ histD, const int* __restrict__ histS,
    const int* __restrict__ rowBaseD, const int* __restrict__ rowBaseS,
    int* __restrict__ pairs, unsigned char* __restrict__ sbytes)
{
    __shared__ int baseD[NBIN], baseS[NBIN];
    for (int i = threadIdx.x; i < NBIN; i += 1024) {
        baseD[i] = rowBaseD[i] + histD[i * NCHUNK + blockIdx.x];
        baseS[i] = rowBaseS[i] + histS[i * NCHUNK + blockIdx.x];
    }
    __syncthreads();
    int base = blockIdx.x * HCHUNK;
    int lim = min(base + HCHUNK, N_EDGES);
    for (int e = base + (int)threadIdx.x; e < lim; e += 1024) {
        int d = dst[e], s = src[e];
        pairs[baseD[d >> BINW_SHIFT] + dstrank[e]] = (s << BINW_SHIFT) | (d & (BINW - 1));
        sbytes[baseS[s >> BINW_SHIFT] + srcrank[e]] = (unsigned char)(s & (BINW - 1));
    }
}

// ---------------------------------------------------------------------------
// Src side finisher: per-bin LDS histogram of sloc bytes -> ns directly.
// ---------------------------------------------------------------------------
__global__ __launch_bounds__(256) void srccount_kernel(
    const unsigned char* __restrict__ sbytes, const int* __restrict__ srcbinOfs,
    float* __restrict__ ns)
{
    __shared__ int h[BINW];
    if (threadIdx.x < BINW) h[threadIdx.x] = 0;
    __syncthreads();
    int beg = srcbinOfs[blockIdx.x], end = srcbinOfs[blockIdx.x + 1];
    for (int i = beg + (int)threadIdx.x; i < end; i += 256)
        atomicAdd(&h[sbytes[i] & (BINW - 1)], 1);
    __syncthreads();
    int node = (blockIdx.x << BINW_SHIFT) + threadIdx.x;
    if (threadIdx.x < BINW && node < N_NODES)
        ns[node] = rsqrtf((float)max(h[threadIdx.x], 1));
}

// ---------------------------------------------------------------------------
// Dst side finisher: per-bin LDS histogram -> intra-bin prefix -> nodeOfs +
// nd, then CSR scatter via LDS cursors into the bin's L2-hot window.
// ---------------------------------------------------------------------------
__global__ __launch_bounds__(256) void csrbuild_kernel(
    const int* __restrict__ pairs, const int* __restrict__ binOfs,
    float* __restrict__ nd, int* __restrict__ nodeOfs, int* __restrict__ csr)
{
    __shared__ int h[BINW];
    __shared__ int curs[BINW];
    if (threadIdx.x < BINW) h[threadIdx.x] = 0;
    __syncthreads();
    int beg = binOfs[blockIdx.x], end = binOfs[blockIdx.x + 1];
    for (int i = beg + (int)threadIdx.x; i < end; i += 256)
        atomicAdd(&h[pairs[i] & (BINW - 1)], 1);
    __syncthreads();
    if (threadIdx.x < 64) {
        int lane = threadIdx.x;
        int v0 = h[lane], v1 = h[lane + 64];
        int s0 = v0, s1 = v1;
#pragma unroll
        for (int off = 1; off < 64; off <<= 1) {
            int u0 = __shfl_up(s0, off); if (lane >= off) s0 += u0;
            int u1 = __shfl_up(s1, off); if (lane >= off) s1 += u1;
        }
        int t0 = __shfl(s0, 63);
        curs[lane]      = beg + (s0 - v0);
        curs[lane + 64] = beg + (s1 - v1) + t0;
    }
    __syncthreads();
    int node = (blockIdx.x << BINW_SHIFT) + threadIdx.x;
    if (threadIdx.x < BINW && node < N_NODES) {
        nodeOfs[node] = curs[threadIdx.x];
        nd[node] = rsqrtf((float)max(h[threadIdx.x], 1));
        if (node == N_NODES - 1) nodeOfs[N_NODES] = end;
    }
    __syncthreads();
    for (int i = beg + (int)threadIdx.x; i < end; i += 256) {
        int p = pairs[i];
        int pos = atomicAdd(&curs[p & (BINW - 1)], 1);
        csr[pos] = p >> BINW_SHIFT;
    }
}

// ---------------------------------------------------------------------------
// xb[i] = bf16(ns[row] * x[i]) — pre-scaled bf16 copy of x for the gather.
// ---------------------------------------------------------------------------
__global__ __launch_bounds__(256) void xconv_kernel(
    const float* __restrict__ x, const float* __restrict__ ns,
    unsigned* __restrict__ xb)
{
    int idx = blockIdx.x * 256 + threadIdx.x;    // 8 elements per thread
    if (idx >= N_NODES * HF / 8) return;
    int row = idx >> 4;
    float c = ns[row];
    const float4* px = (const float4*)(x + (size_t)idx * 8);
    float4 v0 = px[0], v1 = px[1];
    uint4 o;
    o.x = pack2(c * v0.x, c * v0.y);
    o.y = pack2(c * v0.z, c * v0.w);
    o.z = pack2(c * v1.x, c * v1.y);
    o.w = pack2(c * v1.z, c * v1.w);
    *(uint4*)(xb + (size_t)idx * 4) = o;
}

// ---------------------------------------------------------------------------
// wt[layer][n][k] = bf16(W[layer][k][n]) — transposed bf16 weights (B^T).
// ---------------------------------------------------------------------------
__global__ __launch_bounds__(128) void wconv_kernel(
    const float* __restrict__ W0, const float* __restrict__ Ws,
    unsigned short* __restrict__ wt)
{
    const float* Wsrc = (blockIdx.x == 0) ? W0 : (Ws + (size_t)(blockIdx.x - 1) * HF * HF);
    unsigned short* dstp = wt + (size_t)blockIdx.x * HF * HF;
    int n = threadIdx.x;
    for (int k = 0; k < HF; k += 2) {
        float v0 = Wsrc[k * HF + n];
        float v1 = Wsrc[(k + 1) * HF + n];
        *(unsigned*)(dstp + n * HF + k) = pack2(v0, v1);
    }
}

// ---------------------------------------------------------------------------
// Aggregation (at its random-gather service floor per R10/R11 null result):
// one wave per node, 4 lane-groups of 16, 32-edge super-rounds with 8
// predicated uint4 row-loads in flight. FETCH = compulsory floor.
// ---------------------------------------------------------------------------
__global__ __launch_bounds__(256) void agg_kernel(
    const unsigned short* __restrict__ hb, const int* __restrict__ csr,
    const int* __restrict__ nodeOfs, const float* __restrict__ nd,
    unsigned short* __restrict__ ab)
{
    int node = blockIdx.x * 4 + (threadIdx.x >> 6);
    if (node >= N_NODES) return;
    int lane = threadIdx.x & 63;
    int g   = lane >> 4;           // edge group 0..3
    int fl  = (lane & 15) * 8;     // 8 features per lane
    int beg = nodeOfs[node], end = nodeOfs[node + 1];

    float a0 = 0.f, a1 = 0.f, a2 = 0.f, a3 = 0.f;
    float a4 = 0.f, a5 = 0.f, a6 = 0.f, a7 = 0.f;
    for (int base = beg; base < end; base += 64) {
        int m = min(64, end - base);
        int sl = (lane < m) ? csr[base + lane] : 0;
#pragma unroll 1
        for (int k = 0; k < m; k += 32) {
            uint4 v[8];
#pragma unroll
            for (int r = 0; r < 8; ++r) {
                int kk = k + r * 4 + g;
                int sidx = __shfl(sl, kk);
                v[r] = make_uint4(0u, 0u, 0u, 0u);
                if (kk < m)
                    v[r] = *(const uint4*)(hb + (size_t)sidx * HF + fl);
            }
#pragma unroll
            for (int r = 0; r < 8; ++r) {
                a0 += blo(v[r].x); a1 += bhi(v[r].x);
                a2 += blo(v[r].y); a3 += bhi(v[r].y);
                a4 += blo(v[r].z); a5 += bhi(v[r].z);
                a6 += blo(v[r].w); a7 += bhi(v[r].w);
            }
        }
    }
#pragma unroll
    for (int off = 16; off <= 32; off <<= 1) {
        a0 += __shfl_xor(a0, off); a1 += __shfl_xor(a1, off);
        a2 += __shfl_xor(a2, off); a3 += __shfl_xor(a3, off);
        a4 += __shfl_xor(a4, off); a5 += __shfl_xor(a5, off);
        a6 += __shfl_xor(a6, off); a7 += __shfl_xor(a7, off);
    }
    if (lane < 16) {
        float mm = nd[node];
        uint4 o;
        o.x = pack2(a0 * mm, a1 * mm);
        o.y = pack2(a2 * mm, a3 * mm);
        o.z = pack2(a4 * mm, a5 * mm);
        o.w = pack2(a6 * mm, a7 * mm);
        *(uint4*)(ab + (size_t)node * HF + fl) = o;
    }
}

// ---------------------------------------------------------------------------
// MFMA GEMM: A [M][K] bf16, B = W^T [N][K] bf16, mfma_f32_16x16x32_bf16.
// W-only LDS (32 KiB, XOR-swizzled) -> 4 blocks/CU; A fragments are per-lane
// DIRECT global loads (each A element feeds exactly one lane's fragment).
// NOTE (R12 bug fix): A offsets are in ELEMENTS: fragment kk = elements
// [kk*32 + hi*8, +8) of the row (the smem version's kk*64+hi*16 was BYTES).
//   MODE 0: bf16(t) -> obf; LN/ReLU/ns -> hb
//   MODE 1: t += 0.5*obf; LN/ReLU/ns -> hb
//   MODE 2: t += 0.5*obf; t(f32) -> out2 (final d_out)
// ---------------------------------------------------------------------------
template <int MODE>
__global__ __launch_bounds__(GEMM_THREADS) void gemm_fused(
    const unsigned short* __restrict__ A, const unsigned short* __restrict__ Wt,
    const float* __restrict__ bias, const float* __restrict__ lng,
    const float* __restrict__ lnb, unsigned short* __restrict__ obf,
    const float* __restrict__ ns, unsigned short* __restrict__ hb,
    float* __restrict__ out2)
{
    __shared__ char smem[32768];   // sB (W^T) only
    const int tid = threadIdx.x;
    const int row0 = blockIdx.x * MT;

    const int w  = tid >> 6;
    const int l  = tid & 63;
    const int lo = l & 15;
    const int hi = l >> 4;

    // A fragments: per-lane direct global loads (element offsets!),
    // issued before W staging so they overlap the LDS writes + barrier.
    const int arow_g = min(row0 + w * 16 + lo, N_NODES - 1);
    bf16x8 af[4];
#pragma unroll
    for (int kk = 0; kk < 4; ++kk)
        af[kk] = *(const bf16x8*)(A + (size_t)arow_g * HF + kk * 32 + hi * 8);

    // stage B = Wt (32KB), swizzled on 16B granules
#pragma unroll
    for (int i = 0; i < 4; ++i) {
        int ch = tid + i * 512;            // 16B chunk id, 0..2047
        int row = ch >> 4;
        uint4 v = ((const uint4*)Wt)[ch];
        *(uint4*)(smem + ((ch * 16) ^ ((row & 7) << 4))) = v;
    }
    __syncthreads();

    f32x4 acc[8];
#pragma unroll
    for (int nt = 0; nt < 8; ++nt) acc[nt] = (f32x4){0.f, 0.f, 0.f, 0.f};

#pragma unroll
    for (int kk = 0; kk < 4; ++kk) {
#pragma unroll
        for (int nt = 0; nt < 8; ++nt) {
            int n = nt * 16 + lo;
            bf16x8 bfr = *(const bf16x8*)(smem +
                ((n * 256 + kk * 64 + hi * 16) ^ ((n & 7) << 4)));
            acc[nt] = __builtin_amdgcn_mfma_f32_16x16x32_bf16(af[kk], bfr, acc[nt], 0, 0, 0);
        }
    }

    float bia[8], gg[8], bb[8];
#pragma unroll
    for (int nt = 0; nt < 8; ++nt) {
        bia[nt] = bias[nt * 16 + lo];
        if constexpr (MODE != 2) {
            gg[nt] = lng[nt * 16 + lo];
            bb[nt] = lnb[nt * 16 + lo];
        }
    }

#pragma unroll
    for (int r = 0; r < 4; ++r) {
        const int row = row0 + w * 16 + hi * 4 + r;
        const bool ok = row < N_NODES;
        const int rowc = ok ? row : N_NODES - 1;
        float t[8];
        float s = 0.f, ssum = 0.f;
#pragma unroll
        for (int nt = 0; nt < 8; ++nt) {
            float v = acc[nt][r] + bia[nt];
            if constexpr (MODE != 0)
                v = fmaf(RESC, b2f(obf[(size_t)rowc * HF + nt * 16 + lo]), v);
            t[nt] = v;
            s += v; ssum += v * v;
        }
        if constexpr (MODE == 0) {
            if (ok) {
#pragma unroll
                for (int nt = 0; nt < 8; ++nt)
                    obf[(size_t)row * HF + nt * 16 + lo] = (unsigned short)f2b(t[nt]);
            }
        }
        if constexpr (MODE == 2) {
            if (ok) {
#pragma unroll
                for (int nt = 0; nt < 8; ++nt)
                    out2[(size_t)row * HF + nt * 16 + lo] = t[nt];
            }
        } else {
#pragma unroll
            for (int m = 8; m >= 1; m >>= 1) {
                s    += __shfl_xor(s, m);
                ssum += __shfl_xor(ssum, m);
            }
            float mu   = s * (1.0f / HF);
            float var  = ssum * (1.0f / HF) - mu * mu;
            float rinv = rsqrtf(var + LN_EPS);
            float nsr  = ns[rowc];
            if (ok) {
#pragma unroll
                for (int nt = 0; nt < 8; ++nt) {
                    float y = nsr * fmaxf(0.f, (t[nt] - mu) * rinv * gg[nt] + bb[nt]);
                    hb[(size_t)row * HF + nt * 16 + lo] = (unsigned short)f2b(y);
                }
            }
        }
    }
}

// ---------------------------------------------------------------------------
extern "C" void kernel_launch(void* const* d_in, const int* in_sizes, int n_in,
                              void* d_out, int out_size, void* d_ws, size_t ws_size,
                              hipStream_t stream)
{
    const float* x   = (const float*)d_in[0];
    const float* W0  = (const float*)d_in[1];
    const float* Ws  = (const float*)d_in[2];
    const float* b   = (const float*)d_in[3];
    const float* lng = (const float*)d_in[4];
    const float* lnb = (const float*)d_in[5];
    const int*   src = (const int*)d_in[6];
    const int*   dst = (const int*)d_in[7];
    float* out = (float*)d_out;

    // workspace layout, total ~125.1 MB; everything written before read.
    char* ws = (char*)d_ws;
    int*   histD     = (int*)(ws + 0);            // NBIN*NCHUNK ints
    int*   histS     = (int*)(ws + 307200);
    int*   rowTotD   = (int*)(ws + 614400);
    int*   rowTotS   = (int*)(ws + 617984);
    int*   rowBaseD  = (int*)(ws + 621568);
    int*   rowBaseS  = (int*)(ws + 625152);
    int*   binOfs    = (int*)(ws + 628736);
    int*   srcbinOfs = (int*)(ws + 632320);
    float* ns        = (float*)(ws + 635904);
    float* nd        = (float*)(ws + 1036288);
    int*   nodeOfs   = (int*)(ws + 1436672);
    unsigned short* dstrank = (unsigned short*)(ws + 1837056);
    unsigned short* srcrank = (unsigned short*)(ws + 5037056);
    int*   pairs     = (int*)(ws + 8237056);
    unsigned char* sbytes = (unsigned char*)(ws + 14637056);
    int*   csr       = (int*)(ws + 16237056);
    unsigned*       xb  = (unsigned*)(ws + 22637056);        // N*128 bf16
    unsigned short* hb  = (unsigned short*)(ws + 48237056);  // N*128 bf16
    unsigned short* ab  = (unsigned short*)(ws + 73837056);  // N*128 bf16 (agg)
    unsigned short* wt  = (unsigned short*)(ws + 99437056);  // 3*128*128 bf16
    unsigned short* obf = (unsigned short*)(ws + 99535360);  // N*128 bf16 (ori)

    histrank_kernel<<<NCHUNK, 1024, 0, stream>>>(src, dst, histD, histS, dstrank, srcrank);
    scanA_kernel<<<(2 * NBIN + 3) / 4, 256, 0, stream>>>(histD, histS, rowTotD, rowTotS);
    scanB_kernel<<<1, 1024, 0, stream>>>(rowTotD, rowTotS, rowBaseD, rowBaseS, binOfs, srcbinOfs);
    scatter_kernel<<<NCHUNK, 1024, 0, stream>>>(src, dst, dstrank, srcrank,
                                                histD, histS, rowBaseD, rowBaseS,
                                                pairs, sbytes);
    srccount_kernel<<<NBIN, 256, 0, stream>>>(sbytes, srcbinOfs, ns);
    csrbuild_kernel<<<NBIN, 256, 0, stream>>>(pairs, binOfs, nd, nodeOfs, csr);
    wconv_kernel<<<3, 128, 0, stream>>>(W0, Ws, wt);
    xconv_kernel<<<(N_NODES * HF / 8 + 255) / 256, 256, 0, stream>>>(x, ns, xb);

    const int gemm_grid = (N_NODES + MT - 1) / MT;   // 782

    // layer 0
    agg_kernel<<<(N_NODES + 3) / 4, 256, 0, stream>>>(
        (const unsigned short*)xb, csr, nodeOfs, nd, ab);
    gemm_fused<0><<<gemm_grid, GEMM_THREADS, 0, stream>>>(
        ab, wt, b, lng + HF, lnb + HF, obf, ns, hb, nullptr);

    // layer 1
    agg_kernel<<<(N_NODES + 3) / 4, 256, 0, stream>>>(hb, csr, nodeOfs, nd, ab);
    gemm_fused<1><<<gemm_grid, GEMM_THREADS, 0, stream>>>(
        ab, wt + HF * HF, b + HF, lng + 2 * HF, lnb + 2 * HF, obf, ns, hb, nullptr);

    // layer 2
    agg_kernel<<<(N_NODES + 3) / 4, 256, 0, stream>>>(hb, csr, nodeOfs, nd, ab);
    gemm_fused<2><<<gemm_grid, GEMM_THREADS, 0, stream>>>(
        ab, wt + 2 * HF * HF, b + 2 * HF, nullptr, nullptr, obf, ns, nullptr, out);
}